// Round 1
// baseline (2979.836 us; speedup 1.0000x reference)
//
#include <hip/hip_runtime.h>

#define TT 4
#define NN 20000
#define EE 320000
#define NZ 340000
// H = 64 everywhere

// swizzled LDS index for a [64][64] f32 tile: row k, col e.
// Granule (4-float) XOR swizzle keeps b128 row-reads AND column-writes low-conflict.
__device__ __forceinline__ int swz(int k, int e) {
    return (k << 6) + ((((e >> 2) ^ (k & 15)) << 2) | (e & 3));
}

// ---------------- CSR build ----------------
__global__ void k_count(const int* __restrict__ r, const int* __restrict__ s,
                        const int* __restrict__ Li,
                        int* cnt_r, int* cnt_s, int* cnt_L) {
    int i = blockIdx.x * 256 + threadIdx.x;
    if (i < EE) { atomicAdd(&cnt_r[r[i]], 1); atomicAdd(&cnt_s[s[i]], 1); }
    if (i < NZ) { atomicAdd(&cnt_L[Li[i]], 1); }
}

__global__ __launch_bounds__(1024) void k_scan(int* cnt, int* rowp, int* wp) {
    int which = blockIdx.x;
    int* c = cnt + which * NN;
    int* row = rowp + which * (NN + 1);
    int* w = wp + which * NN;
    __shared__ int ssum[1024];
    int tid = threadIdx.x;
    const int CH = (NN + 1023) / 1024; // 20
    int base = tid * CH;
    int s = 0;
    for (int i = 0; i < CH; ++i) { int idx = base + i; s += (idx < NN) ? c[idx] : 0; }
    ssum[tid] = s;
    __syncthreads();
    for (int o = 1; o < 1024; o <<= 1) {
        int v = (tid >= o) ? ssum[tid - o] : 0;
        __syncthreads();
        ssum[tid] += v;
        __syncthreads();
    }
    int run = (tid > 0) ? ssum[tid - 1] : 0;
    for (int i = 0; i < CH; ++i) {
        int idx = base + i;
        if (idx < NN) { row[idx] = run; w[idx] = run; run += c[idx]; }
    }
    if (tid == 1023) row[NN] = ssum[1023];
}

__global__ void k_scatter(const int* __restrict__ r, const int* __restrict__ s,
                          const int* __restrict__ Li,
                          int* wp_r, int* wp_s, int* wp_L,
                          int* col_r, int* col_s, int* col_L) {
    int i = blockIdx.x * 256 + threadIdx.x;
    if (i < EE) {
        col_r[atomicAdd(&wp_r[r[i]], 1)] = i;
        col_s[atomicAdd(&wp_s[s[i]], 1)] = i;
    }
    if (i < NZ) { col_L[atomicAdd(&wp_L[Li[i]], 1)] = i; }
}

// ---------------- node encoder ----------------
__global__ __launch_bounds__(256) void k_xenc(const float* __restrict__ na,
                                              const float* __restrict__ W_ne,
                                              const float* __restrict__ b_ne,
                                              float* __restrict__ xenc) {
    int row = blockIdx.x * 4 + (threadIdx.x >> 6); // 0..T*N-1
    int j = threadIdx.x & 63;
    float4 a = *(const float4*)&na[(size_t)row * 4];
    float v = b_ne[j] + a.x * W_ne[j] + a.y * W_ne[64 + j] + a.z * W_ne[128 + j] + a.w * W_ne[192 + j];
    xenc[(size_t)row * 64 + j] = fmaxf(v, 0.f);
}

// ---------------- global block + g-bias fold ----------------
__global__ void k_gbias(int do_update, const float* __restrict__ W_gb,
                        const float* __restrict__ b_gb, const float* __restrict__ W_eb,
                        const float* __restrict__ b_eb, const float* __restrict__ W_nb,
                        const float* __restrict__ b_nb, float* __restrict__ g_cur,
                        float* __restrict__ e_sum, float* __restrict__ x_sum,
                        float* __restrict__ gb_eb, float* __restrict__ gb_nb) {
    int j = threadIdx.x; // 64 threads
    float a = 0.f;
    if (do_update) {
        a = b_gb[j];
        for (int k = 0; k < 64; ++k) a += (e_sum[k] / (float)EE) * W_gb[k * 64 + j];
        for (int k = 0; k < 64; ++k) a += (x_sum[k] / (float)NN) * W_gb[(64 + k) * 64 + j];
        for (int k = 0; k < 64; ++k) a += g_cur[k] * W_gb[(128 + k) * 64 + j];
    }
    __syncthreads();
    if (do_update) {
        g_cur[j] = fmaxf(a, 0.f);
        e_sum[j] = 0.f;
        x_sum[j] = 0.f;
    }
    __syncthreads();
    float a1 = b_eb[j], a2 = b_nb[j];
    for (int k = 0; k < 64; ++k) {
        float gk = g_cur[k];
        a1 = fmaf(gk, W_eb[(384 + k) * 64 + j], a1);
        a2 = fmaf(gk, W_nb[(256 + k) * 64 + j], a2);
    }
    gb_eb[j] = a1;
    gb_nb[j] = a2;
}

// ---------------- edge block: the big GEMM ----------------
// 64 edges x 64 outs per block, K = 6 gathered chunks of 64 (g-chunk folded into gbias)
__global__ __launch_bounds__(256) void k_edge(
    const float* __restrict__ xenc_t, float* __restrict__ h_e,
    const float* __restrict__ h_x, const float* __restrict__ emb,
    const int* __restrict__ eattr_t, const int* __restrict__ sidx,
    const int* __restrict__ ridx, const float* __restrict__ W_eb,
    const float* __restrict__ gbias, float* __restrict__ e_sum) {
    __shared__ float sIn[64 * 64];
    __shared__ float sW[64 * 64];
    __shared__ float sRed[4][64];
    const int tid = threadIdx.x;
    const int e0 = blockIdx.x * 64;
    const int je = tid & 15, jj = tid >> 4;
    const int wv = tid >> 6, ln = tid & 63;
    float acc[4][4] = {};
    for (int c = 0; c < 6; ++c) {
        #pragma unroll
        for (int i = 0; i < 16; ++i) {
            int idx = tid + 256 * i;
            sW[idx] = W_eb[c * 4096 + idx];
        }
        #pragma unroll
        for (int i = 0; i < 16; ++i) {
            int esub = i * 4 + wv;
            int e = e0 + esub;
            const float* src;
            switch (c) {
                case 0: src = emb + (size_t)64 * eattr_t[e]; break;
                case 1: src = h_e + (size_t)64 * e; break;
                case 2: src = xenc_t + (size_t)64 * sidx[e]; break;
                case 3: src = h_x + (size_t)64 * sidx[e]; break;
                case 4: src = xenc_t + (size_t)64 * ridx[e]; break;
                default: src = h_x + (size_t)64 * ridx[e]; break;
            }
            sIn[swz(ln, esub)] = src[ln];
        }
        __syncthreads();
        #pragma unroll 4
        for (int k = 0; k < 64; ++k) {
            float4 iv = *(const float4*)&sIn[(k << 6) + (((je ^ (k & 15))) << 2)];
            float4 w4 = *(const float4*)&sW[(k << 6) + (jj << 2)];
            const float* ip = (const float*)&iv;
            #pragma unroll
            for (int p = 0; p < 4; ++p) {
                acc[p][0] = fmaf(ip[p], w4.x, acc[p][0]);
                acc[p][1] = fmaf(ip[p], w4.y, acc[p][1]);
                acc[p][2] = fmaf(ip[p], w4.z, acc[p][2]);
                acc[p][3] = fmaf(ip[p], w4.w, acc[p][3]);
            }
        }
        __syncthreads();
    }
    // epilogue: + gbias, relu, transpose through LDS, coalesced store, column sums
    float4 gb = *(const float4*)&gbias[jj << 2];
    #pragma unroll
    for (int p = 0; p < 4; ++p) {
        int e = 4 * je + p;
        float4 v;
        v.x = fmaxf(acc[p][0] + gb.x, 0.f);
        v.y = fmaxf(acc[p][1] + gb.y, 0.f);
        v.z = fmaxf(acc[p][2] + gb.z, 0.f);
        v.w = fmaxf(acc[p][3] + gb.w, 0.f);
        *(float4*)&sIn[swz(e, jj << 2)] = v;
    }
    __syncthreads();
    float colsum = 0.f;
    #pragma unroll
    for (int i = 0; i < 16; ++i) {
        int e = i * 4 + wv;
        float v = sIn[swz(e, ln)];
        h_e[(size_t)64 * (e0 + e) + ln] = v;
        colsum += v;
    }
    sRed[wv][ln] = colsum;
    __syncthreads();
    if (wv == 0)
        atomicAdd(&e_sum[ln], sRed[0][ln] + sRed[1][ln] + sRed[2][ln] + sRed[3][ln]);
}

// ---------------- recv/sent gather (segment sums via CSR) ----------------
__global__ __launch_bounds__(256) void k_gather(
    const float* __restrict__ h_e, const int* __restrict__ row_r,
    const int* __restrict__ col_r, const int* __restrict__ row_s,
    const int* __restrict__ col_s, float* __restrict__ recv, float* __restrict__ sentb) {
    int n = blockIdx.x * 4 + (threadIdx.x >> 6);
    int j = threadIdx.x & 63;
    if (n >= NN) return;
    float a = 0.f;
    int b0 = row_r[n], b1 = row_r[n + 1];
    for (int p = b0; p < b1; ++p) a += h_e[(size_t)64 * col_r[p] + j];
    recv[(size_t)64 * n + j] = a;
    a = 0.f;
    b0 = row_s[n]; b1 = row_s[n + 1];
    for (int p = b0; p < b1; ++p) a += h_e[(size_t)64 * col_s[p] + j];
    sentb[(size_t)64 * n + j] = a;
}

// ---------------- node block GEMM ----------------
__global__ __launch_bounds__(256) void k_node(
    const float* __restrict__ recv, const float* __restrict__ sentb,
    const float* __restrict__ xenc_t, float* __restrict__ h_x,
    const float* __restrict__ W_nb, const float* __restrict__ gbias,
    float* __restrict__ x_sum, float* __restrict__ hid_t, float* __restrict__ timed_t) {
    __shared__ float sIn[64 * 64];
    __shared__ float sW[64 * 64];
    __shared__ float sRed[4][64];
    const int tid = threadIdx.x;
    const int n0 = blockIdx.x * 64;
    const int je = tid & 15, jj = tid >> 4;
    const int wv = tid >> 6, ln = tid & 63;
    float acc[4][4] = {};
    for (int c = 0; c < 4; ++c) {
        #pragma unroll
        for (int i = 0; i < 16; ++i) {
            int idx = tid + 256 * i;
            sW[idx] = W_nb[c * 4096 + idx];
        }
        #pragma unroll
        for (int i = 0; i < 16; ++i) {
            int nsub = i * 4 + wv;
            int n = n0 + nsub;
            float v = 0.f;
            if (n < NN) {
                const float* src;
                switch (c) {
                    case 0: src = recv + (size_t)64 * n; break;
                    case 1: src = sentb + (size_t)64 * n; break;
                    case 2: src = xenc_t + (size_t)64 * n; break;
                    default: src = h_x + (size_t)64 * n; break;
                }
                v = src[ln];
            }
            sIn[swz(ln, nsub)] = v;
        }
        __syncthreads();
        #pragma unroll 4
        for (int k = 0; k < 64; ++k) {
            float4 iv = *(const float4*)&sIn[(k << 6) + (((je ^ (k & 15))) << 2)];
            float4 w4 = *(const float4*)&sW[(k << 6) + (jj << 2)];
            const float* ip = (const float*)&iv;
            #pragma unroll
            for (int p = 0; p < 4; ++p) {
                acc[p][0] = fmaf(ip[p], w4.x, acc[p][0]);
                acc[p][1] = fmaf(ip[p], w4.y, acc[p][1]);
                acc[p][2] = fmaf(ip[p], w4.z, acc[p][2]);
                acc[p][3] = fmaf(ip[p], w4.w, acc[p][3]);
            }
        }
        __syncthreads();
    }
    float4 gb = *(const float4*)&gbias[jj << 2];
    #pragma unroll
    for (int p = 0; p < 4; ++p) {
        int nsub = 4 * je + p;
        bool valid = (n0 + nsub) < NN;
        float4 v;
        v.x = valid ? fmaxf(acc[p][0] + gb.x, 0.f) : 0.f;
        v.y = valid ? fmaxf(acc[p][1] + gb.y, 0.f) : 0.f;
        v.z = valid ? fmaxf(acc[p][2] + gb.z, 0.f) : 0.f;
        v.w = valid ? fmaxf(acc[p][3] + gb.w, 0.f) : 0.f;
        *(float4*)&sIn[swz(nsub, jj << 2)] = v;
    }
    __syncthreads();
    float colsum = 0.f;
    #pragma unroll
    for (int i = 0; i < 16; ++i) {
        int nsub = i * 4 + wv;
        int n = n0 + nsub;
        float xn = sIn[swz(nsub, ln)];
        colsum += xn;
        if (n < NN) {
            float hx = h_x[(size_t)64 * n + ln] + xn;
            h_x[(size_t)64 * n + ln] = hx;
            hid_t[(size_t)64 * n + ln] = hx;
            timed_t[(size_t)64 * n + ln] = xn;
        }
    }
    sRed[wv][ln] = colsum;
    __syncthreads();
    if (wv == 0)
        atomicAdd(&x_sum[ln], sRed[0][ln] + sRed[1][ln] + sRed[2][ln] + sRed[3][ln]);
}

// ---------------- Laplacian ----------------
__global__ __launch_bounds__(256) void k_lap(
    const float* __restrict__ h_x, const float* __restrict__ Lv,
    const int* __restrict__ Lj, const int* __restrict__ row_L,
    const int* __restrict__ col_L, const float* __restrict__ coeff,
    float* __restrict__ spat_t) {
    int n = blockIdx.x * 4 + (threadIdx.x >> 6);
    int j = threadIdx.x & 63;
    if (n >= NN) return;
    float a = 0.f;
    int b0 = row_L[n], b1 = row_L[n + 1];
    for (int p = b0; p < b1; ++p) {
        int idx = col_L[p];
        a = fmaf(Lv[idx], h_x[(size_t)64 * Lj[idx] + j], a);
    }
    spat_t[(size_t)64 * n + j] = coeff[0] * a;
}

// ---------------- decoders ----------------
__global__ __launch_bounds__(256) void k_dec(
    const float* __restrict__ hid, const float* __restrict__ W_d1,
    const float* __restrict__ b_d1, const float* __restrict__ W_d2,
    const float* __restrict__ b_d2, const float* __restrict__ W_i1,
    const float* __restrict__ b_i1, const float* __restrict__ W_i2,
    const float* __restrict__ b_i2, float* __restrict__ out_nodes,
    float* __restrict__ pred_in) {
    __shared__ float sh[4][64];
    int wv = threadIdx.x >> 6, j = threadIdx.x & 63;
    int row = blockIdx.x * 4 + wv; // 0..T*N-1
    float hv = hid[(size_t)64 * row + j];
    sh[wv][j] = hv;
    __syncthreads();
    float a1 = b_d1[j], a2 = b_i1[j];
    for (int k = 0; k < 64; ++k) {
        float h = sh[wv][k];
        a1 = fmaf(h, W_d1[k * 64 + j], a1);
        a2 = fmaf(h, W_i1[k * 64 + j], a2);
    }
    a1 = fmaxf(a1, 0.f);
    a2 = fmaxf(a2, 0.f);
    float r0 = a1 * W_d2[j];
    float4 wi = *(const float4*)&W_i2[4 * j];
    float p0 = a2 * wi.x, p1 = a2 * wi.y, p2 = a2 * wi.z, p3 = a2 * wi.w;
    for (int o = 32; o > 0; o >>= 1) {
        r0 += __shfl_down(r0, o, 64);
        p0 += __shfl_down(p0, o, 64);
        p1 += __shfl_down(p1, o, 64);
        p2 += __shfl_down(p2, o, 64);
        p3 += __shfl_down(p3, o, 64);
    }
    if (j == 0) {
        out_nodes[row] = r0 + b_d2[0];
        float4 pv;
        pv.x = p0 + b_i2[0];
        pv.y = p1 + b_i2[1];
        pv.z = p2 + b_i2[2];
        pv.w = p3 + b_i2[3];
        *(float4*)&pred_in[(size_t)4 * row] = pv;
    }
}

extern "C" void kernel_launch(void* const* d_in, const int* in_sizes, int n_in,
                              void* d_out, int out_size, void* d_ws, size_t ws_size,
                              hipStream_t stream) {
    (void)in_sizes; (void)n_in; (void)out_size; (void)ws_size;
    const float* node_attr   = (const float*)d_in[0];
    const float* global_attr = (const float*)d_in[1];
    const float* L_values    = (const float*)d_in[2];
    const float* coeff       = (const float*)d_in[3];
    const int*   edge_attr   = (const int*)d_in[4];
    const int*   edge_index  = (const int*)d_in[5];
    const int*   L_index     = (const int*)d_in[6];
    // d_in[7] = num_processing_steps (scan length is T=4 regardless)
    const float* emb  = (const float*)d_in[8];
    const float* W_ne = (const float*)d_in[9];
    const float* b_ne = (const float*)d_in[10];
    const float* W_eb = (const float*)d_in[11];
    const float* b_eb = (const float*)d_in[12];
    const float* W_nb = (const float*)d_in[13];
    const float* b_nb = (const float*)d_in[14];
    const float* W_gb = (const float*)d_in[15];
    const float* b_gb = (const float*)d_in[16];
    const float* W_d1 = (const float*)d_in[17];
    const float* b_d1 = (const float*)d_in[18];
    const float* W_d2 = (const float*)d_in[19];
    const float* b_d2 = (const float*)d_in[20];
    const float* W_i1 = (const float*)d_in[21];
    const float* b_i1 = (const float*)d_in[22];
    const float* W_i2 = (const float*)d_in[23];
    const float* b_i2 = (const float*)d_in[24];

    const int* s_idx = edge_index;       // senders
    const int* r_idx = edge_index + EE;  // receivers
    const int* Li = L_index;
    const int* Lj = L_index + NZ;

    char* ws = (char*)d_ws;
    size_t off = 0;
    auto alloc = [&](size_t bytes) -> void* {
        void* p = ws + off;
        off = (off + bytes + 255) & ~(size_t)255;
        return p;
    };
    float* xenc  = (float*)alloc((size_t)TT * NN * 64 * 4);
    float* hid   = (float*)alloc((size_t)TT * NN * 64 * 4);
    float* h_x   = (float*)alloc((size_t)NN * 64 * 4);
    float* h_e   = (float*)alloc((size_t)EE * 64 * 4);
    float* recv  = (float*)alloc((size_t)NN * 64 * 4);
    float* sentb = (float*)alloc((size_t)NN * 64 * 4);
    float* smalls = (float*)alloc(2048);
    int* cnt   = (int*)alloc((size_t)3 * NN * 4);
    int* rowp  = (int*)alloc((size_t)3 * (NN + 1) * 4);
    int* wp    = (int*)alloc((size_t)3 * NN * 4);
    int* col_r = (int*)alloc((size_t)EE * 4);
    int* col_s = (int*)alloc((size_t)EE * 4);
    int* col_L = (int*)alloc((size_t)NZ * 4);

    float* g_cur = smalls;
    float* e_sum = smalls + 64;
    float* x_sum = smalls + 128;
    float* gb_eb = smalls + 192;
    float* gb_nb = smalls + 256;
    int* cnt_r = cnt, *cnt_s = cnt + NN, *cnt_L = cnt + 2 * NN;
    int* row_r = rowp, *row_s = rowp + (NN + 1), *row_L = rowp + 2 * (NN + 1);
    int* wp_r = wp, *wp_s = wp + NN, *wp_L = wp + 2 * NN;

    float* out_nodes = (float*)d_out;                    // [T,N,1]
    float* time_d = out_nodes + (size_t)TT * NN;         // [T,N,64]
    float* spat_d = time_d + (size_t)TT * NN * 64;       // [T,N,64]
    float* pred_in = spat_d + (size_t)TT * NN * 64;      // [T,N,4]

    hipMemsetAsync(h_x, 0, (size_t)NN * 64 * 4, stream);
    hipMemsetAsync(h_e, 0, (size_t)EE * 64 * 4, stream);
    hipMemsetAsync(smalls, 0, 2048, stream);
    hipMemsetAsync(cnt, 0, (size_t)3 * NN * 4, stream);
    hipMemcpyAsync(g_cur, global_attr, 64 * 4, hipMemcpyDeviceToDevice, stream);

    k_count<<<(NZ + 255) / 256, 256, 0, stream>>>(r_idx, s_idx, Li, cnt_r, cnt_s, cnt_L);
    k_scan<<<3, 1024, 0, stream>>>(cnt, rowp, wp);
    k_scatter<<<(NZ + 255) / 256, 256, 0, stream>>>(r_idx, s_idx, Li, wp_r, wp_s, wp_L,
                                                    col_r, col_s, col_L);
    k_xenc<<<TT * NN / 4, 256, 0, stream>>>(node_attr, W_ne, b_ne, xenc);
    k_gbias<<<1, 64, 0, stream>>>(0, W_gb, b_gb, W_eb, b_eb, W_nb, b_nb,
                                  g_cur, e_sum, x_sum, gb_eb, gb_nb);

    for (int t = 0; t < TT; ++t) {
        const float* xenc_t = xenc + (size_t)t * NN * 64;
        k_edge<<<EE / 64, 256, 0, stream>>>(xenc_t, h_e, h_x, emb,
                                            edge_attr + (size_t)t * EE, s_idx, r_idx,
                                            W_eb, gb_eb, e_sum);
        k_gather<<<(NN + 3) / 4, 256, 0, stream>>>(h_e, row_r, col_r, row_s, col_s,
                                                   recv, sentb);
        k_node<<<(NN + 63) / 64, 256, 0, stream>>>(recv, sentb, xenc_t, h_x, W_nb, gb_nb,
                                                   x_sum, hid + (size_t)t * NN * 64,
                                                   time_d + (size_t)t * NN * 64);
        k_lap<<<(NN + 3) / 4, 256, 0, stream>>>(h_x, L_values, Lj, row_L, col_L, coeff,
                                                spat_d + (size_t)t * NN * 64);
        k_gbias<<<1, 64, 0, stream>>>(1, W_gb, b_gb, W_eb, b_eb, W_nb, b_nb,
                                      g_cur, e_sum, x_sum, gb_eb, gb_nb);
    }
    k_dec<<<TT * NN / 4, 256, 0, stream>>>(hid, W_d1, b_d1, W_d2, b_d2,
                                           W_i1, b_i1, W_i2, b_i2, out_nodes, pred_in);
}

// Round 2
// 1875.939 us; speedup vs baseline: 1.5885x; 1.5885x over previous
//
#include <hip/hip_runtime.h>

#define TT 4
#define NN 20000
#define EE 320000
#define NZ 340000

typedef __attribute__((ext_vector_type(8))) __bf16 bf16x8;
typedef __attribute__((ext_vector_type(16))) float f32x16;

__device__ __forceinline__ unsigned short f2bf(float f) {
    unsigned int u = __float_as_uint(f);
    u = (u + 0x7FFFu + ((u >> 16) & 1u)) >> 16;
    return (unsigned short)u;
}
__device__ __forceinline__ float bf2f(unsigned short h) {
    return __uint_as_float(((unsigned int)h) << 16);
}

#define GLL16(src, dst) __builtin_amdgcn_global_load_lds( \
    (const __attribute__((address_space(1))) unsigned int*)(src), \
    (__attribute__((address_space(3))) unsigned int*)(dst), 16, 0, 0)

// ---------------- CSR build ----------------
__global__ void k_count(const int* __restrict__ r, const int* __restrict__ s,
                        const int* __restrict__ Li,
                        int* cnt_r, int* cnt_s, int* cnt_L) {
    int i = blockIdx.x * 256 + threadIdx.x;
    if (i < EE) { atomicAdd(&cnt_r[r[i]], 1); atomicAdd(&cnt_s[s[i]], 1); }
    if (i < NZ) { atomicAdd(&cnt_L[Li[i]], 1); }
}

__global__ __launch_bounds__(1024) void k_scan(int* cnt, int* rowp, int* wp) {
    int which = blockIdx.x;
    int* c = cnt + which * NN;
    int* row = rowp + which * (NN + 1);
    int* w = wp + which * NN;
    __shared__ int ssum[1024];
    int tid = threadIdx.x;
    const int CH = (NN + 1023) / 1024;
    int base = tid * CH;
    int s = 0;
    for (int i = 0; i < CH; ++i) { int idx = base + i; s += (idx < NN) ? c[idx] : 0; }
    ssum[tid] = s;
    __syncthreads();
    for (int o = 1; o < 1024; o <<= 1) {
        int v = (tid >= o) ? ssum[tid - o] : 0;
        __syncthreads();
        ssum[tid] += v;
        __syncthreads();
    }
    int run = (tid > 0) ? ssum[tid - 1] : 0;
    for (int i = 0; i < CH; ++i) {
        int idx = base + i;
        if (idx < NN) { row[idx] = run; w[idx] = run; run += c[idx]; }
    }
    if (tid == 1023) row[NN] = ssum[1023];
}

__global__ void k_scatter(const int* __restrict__ r, const int* __restrict__ s,
                          const int* __restrict__ Li,
                          int* wp_r, int* wp_s, int* wp_L,
                          int* col_r, int* col_s, int* col_L) {
    int i = blockIdx.x * 256 + threadIdx.x;
    if (i < EE) {
        col_r[atomicAdd(&wp_r[r[i]], 1)] = i;
        col_s[atomicAdd(&wp_s[s[i]], 1)] = i;
    }
    if (i < NZ) { col_L[atomicAdd(&wp_L[Li[i]], 1)] = i; }
}

// ---------------- weight packing to bf16 MFMA fragment order ----------------
// Bp layout: [colhalf(2)][kb][lane(64)][8] ; col = ch*32 + (l&31), k = kb*16 + (l>>5)*8 + i
__global__ __launch_bounds__(256) void k_pack(
    const float* __restrict__ W_eb, const float* __restrict__ W_nb,
    const float* __restrict__ emb, unsigned short* __restrict__ Bpe,
    unsigned short* __restrict__ Bpn, unsigned short* __restrict__ emb_bf) {
    int t = blockIdx.x * 256 + threadIdx.x;
    if (t < 2 * 24 * 512) {
        int i = t & 7, l = (t >> 3) & 63, kb = (t >> 9) % 24, ch = t / (24 * 512);
        int colv = ch * 32 + (l & 31);
        int k = kb * 16 + (l >> 5) * 8 + i;
        Bpe[t] = f2bf(W_eb[k * 64 + colv]);
    }
    if (t < 2 * 16 * 512) {
        int i = t & 7, l = (t >> 3) & 63, kb = (t >> 9) % 16, ch = t / (16 * 512);
        int colv = ch * 32 + (l & 31);
        int k = kb * 16 + (l >> 5) * 8 + i;
        Bpn[t] = f2bf(W_nb[k * 64 + colv]);
    }
    if (t < 100 * 64) emb_bf[t] = f2bf(emb[t]);
}

// ---------------- node encoder (bf16 out) ----------------
__global__ __launch_bounds__(256) void k_xenc(const float* __restrict__ na,
                                              const float* __restrict__ W_ne,
                                              const float* __restrict__ b_ne,
                                              unsigned short* __restrict__ xenc) {
    int row = blockIdx.x * 4 + (threadIdx.x >> 6);
    int j = threadIdx.x & 63;
    float4 a = *(const float4*)&na[(size_t)row * 4];
    float v = b_ne[j] + a.x * W_ne[j] + a.y * W_ne[64 + j] + a.z * W_ne[128 + j] + a.w * W_ne[192 + j];
    xenc[(size_t)row * 64 + j] = f2bf(fmaxf(v, 0.f));
}

// ---------------- global block + g-bias fold ----------------
__global__ void k_gbias(int do_update, const float* __restrict__ W_gb,
                        const float* __restrict__ b_gb, const float* __restrict__ W_eb,
                        const float* __restrict__ b_eb, const float* __restrict__ W_nb,
                        const float* __restrict__ b_nb, float* __restrict__ g_cur,
                        float* __restrict__ e_sum, float* __restrict__ x_sum,
                        float* __restrict__ gb_eb, float* __restrict__ gb_nb) {
    int j = threadIdx.x; // 64 threads
    float a = 0.f;
    if (do_update) {
        a = b_gb[j];
        for (int k = 0; k < 64; ++k) a += (e_sum[k] / (float)EE) * W_gb[k * 64 + j];
        for (int k = 0; k < 64; ++k) a += (x_sum[k] / (float)NN) * W_gb[(64 + k) * 64 + j];
        for (int k = 0; k < 64; ++k) a += g_cur[k] * W_gb[(128 + k) * 64 + j];
    }
    __syncthreads();
    if (do_update) {
        g_cur[j] = fmaxf(a, 0.f);
        e_sum[j] = 0.f;
        x_sum[j] = 0.f;
    }
    __syncthreads();
    float a1 = b_eb[j], a2 = b_nb[j];
    for (int k = 0; k < 64; ++k) {
        float gk = g_cur[k];
        a1 = fmaf(gk, W_eb[(384 + k) * 64 + j], a1);
        a2 = fmaf(gk, W_nb[(256 + k) * 64 + j], a2);
    }
    gb_eb[j] = a1;
    gb_nb[j] = a2;
}

// ---------------- edge block: bf16 MFMA GEMM ----------------
// 64 edges x 64 outs per block; 4 waves, each a 32x32 quadrant via mfma_f32_32x32x16_bf16.
// A staged via global_load_lds w/ pre-swizzled source granules (rule #21).
__global__ __launch_bounds__(256) void k_edge(
    const unsigned short* __restrict__ xenc_t, unsigned short* __restrict__ h_e,
    const unsigned short* __restrict__ hx_bf, const unsigned short* __restrict__ emb_bf,
    const int* __restrict__ eattr_t, const int* __restrict__ sidx,
    const int* __restrict__ ridx, const unsigned short* __restrict__ Bp,
    const float* __restrict__ gbias, float* __restrict__ e_sum) {
    __shared__ unsigned short sA[64 * 64];
    const int tid = threadIdx.x;
    const int w = tid >> 6, ln = tid & 63;
    const int e0 = blockIdx.x * 64;
    const int g = ln & 7;
    const int rA = w * 16 + (ln >> 3);
    const int rB = rA + 8;
    const int swzA = (g ^ (rA & 7)) << 3; // shorts
    const int swzB = (g ^ (rB & 7)) << 3;
    const int eA = e0 + rA, eB = e0 + rB;
    const int siA = sidx[eA], siB = sidx[eB];
    const int riA = ridx[eA], riB = ridx[eB];
    const int aiA = eattr_t[eA], aiB = eattr_t[eB];
    unsigned short* dst0 = &sA[w * 1024];
    unsigned short* dst1 = &sA[w * 1024 + 512];

    const int erow0 = (w & 1) * 32;
    const int colhalf = w >> 1;
    const int lrow = erow0 + (ln & 31);
    const int ahi = ln >> 5;
    const unsigned short* BpW = Bp + (size_t)colhalf * 24 * 512;

    f32x16 acc;
    #pragma unroll
    for (int i = 0; i < 16; ++i) acc[i] = 0.f;

    #pragma unroll
    for (int c = 0; c < 6; ++c) {
        const unsigned short *pA, *pB;
        switch (c) {
            case 0: pA = emb_bf + (size_t)64 * aiA; pB = emb_bf + (size_t)64 * aiB; break;
            case 1: pA = h_e + (size_t)64 * eA;     pB = h_e + (size_t)64 * eB;     break;
            case 2: pA = xenc_t + (size_t)64 * siA; pB = xenc_t + (size_t)64 * siB; break;
            case 3: pA = hx_bf + (size_t)64 * siA;  pB = hx_bf + (size_t)64 * siB;  break;
            case 4: pA = xenc_t + (size_t)64 * riA; pB = xenc_t + (size_t)64 * riB; break;
            default:pA = hx_bf + (size_t)64 * riA;  pB = hx_bf + (size_t)64 * riB;  break;
        }
        GLL16(pA + swzA, dst0);
        GLL16(pB + swzB, dst1);
        __syncthreads();
        #pragma unroll
        for (int kb = 0; kb < 4; ++kb) {
            int gp = (kb * 2 + ahi) ^ (lrow & 7);
            bf16x8 a = *(const bf16x8*)&sA[lrow * 64 + gp * 8];
            bf16x8 b = *(const bf16x8*)&BpW[((c * 4 + kb) * 64 + ln) * 8];
            acc = __builtin_amdgcn_mfma_f32_32x32x16_bf16(a, b, acc, 0, 0, 0);
        }
        __syncthreads();
    }

    const int col = colhalf * 32 + (ln & 31);
    const float gb = gbias[col];
    float csum = 0.f;
    #pragma unroll
    for (int r = 0; r < 16; ++r) {
        int row = (r & 3) + 8 * (r >> 2) + 4 * ahi;
        float v = fmaxf(acc[r] + gb, 0.f);
        csum += v;
        h_e[(size_t)(e0 + erow0 + row) * 64 + col] = f2bf(v);
    }
    csum += __shfl_xor(csum, 32, 64);
    if (ln < 32) atomicAdd(&e_sum[col], csum);
}

// ---------------- recv/sent gather (bf16) ----------------
__global__ __launch_bounds__(256) void k_gather(
    const unsigned short* __restrict__ h_e, const int* __restrict__ row_r,
    const int* __restrict__ col_r, const int* __restrict__ row_s,
    const int* __restrict__ col_s, unsigned short* __restrict__ recv,
    unsigned short* __restrict__ sentb) {
    int n = blockIdx.x * 4 + (threadIdx.x >> 6);
    int j = threadIdx.x & 63;
    if (n >= NN) return;
    float a = 0.f;
    int b0 = row_r[n], b1 = row_r[n + 1];
    for (int p = b0; p < b1; ++p) a += bf2f(h_e[(size_t)64 * col_r[p] + j]);
    recv[(size_t)64 * n + j] = f2bf(a);
    a = 0.f;
    b0 = row_s[n]; b1 = row_s[n + 1];
    for (int p = b0; p < b1; ++p) a += bf2f(h_e[(size_t)64 * col_s[p] + j]);
    sentb[(size_t)64 * n + j] = f2bf(a);
}

// ---------------- node block: bf16 MFMA GEMM ----------------
__global__ __launch_bounds__(256) void k_node(
    const unsigned short* __restrict__ recv, const unsigned short* __restrict__ sentb,
    const unsigned short* __restrict__ xenc_t, float* __restrict__ h_x,
    unsigned short* __restrict__ hx_bf, const unsigned short* __restrict__ Bp,
    const float* __restrict__ gbias, float* __restrict__ x_sum,
    float* __restrict__ hid_t, float* __restrict__ timed_t) {
    __shared__ unsigned short sA[64 * 64];
    const int tid = threadIdx.x;
    const int w = tid >> 6, ln = tid & 63;
    const int n0 = blockIdx.x * 64;
    const int g = ln & 7;
    const int rA = w * 16 + (ln >> 3);
    const int rB = rA + 8;
    const int swzA = (g ^ (rA & 7)) << 3;
    const int swzB = (g ^ (rB & 7)) << 3;
    int nA = n0 + rA; if (nA > NN - 1) nA = NN - 1;
    int nB = n0 + rB; if (nB > NN - 1) nB = NN - 1;
    unsigned short* dst0 = &sA[w * 1024];
    unsigned short* dst1 = &sA[w * 1024 + 512];

    const int nrow0 = (w & 1) * 32;
    const int colhalf = w >> 1;
    const int lrow = nrow0 + (ln & 31);
    const int ahi = ln >> 5;
    const unsigned short* BpW = Bp + (size_t)colhalf * 16 * 512;

    f32x16 acc;
    #pragma unroll
    for (int i = 0; i < 16; ++i) acc[i] = 0.f;

    #pragma unroll
    for (int c = 0; c < 4; ++c) {
        const unsigned short *pA, *pB;
        switch (c) {
            case 0: pA = recv + (size_t)64 * nA;   pB = recv + (size_t)64 * nB;   break;
            case 1: pA = sentb + (size_t)64 * nA;  pB = sentb + (size_t)64 * nB;  break;
            case 2: pA = xenc_t + (size_t)64 * nA; pB = xenc_t + (size_t)64 * nB; break;
            default:pA = hx_bf + (size_t)64 * nA;  pB = hx_bf + (size_t)64 * nB;  break;
        }
        GLL16(pA + swzA, dst0);
        GLL16(pB + swzB, dst1);
        __syncthreads();
        #pragma unroll
        for (int kb = 0; kb < 4; ++kb) {
            int gp = (kb * 2 + ahi) ^ (lrow & 7);
            bf16x8 a = *(const bf16x8*)&sA[lrow * 64 + gp * 8];
            bf16x8 b = *(const bf16x8*)&BpW[((c * 4 + kb) * 64 + ln) * 8];
            acc = __builtin_amdgcn_mfma_f32_32x32x16_bf16(a, b, acc, 0, 0, 0);
        }
        __syncthreads();
    }

    const int col = colhalf * 32 + (ln & 31);
    const float gb = gbias[col];
    float csum = 0.f;
    #pragma unroll
    for (int r = 0; r < 16; ++r) {
        int row = nrow0 + (r & 3) + 8 * (r >> 2) + 4 * ahi;
        int n = n0 + row;
        if (n < NN) {
            float xn = fmaxf(acc[r] + gb, 0.f);
            csum += xn;
            size_t o = (size_t)n * 64 + col;
            float hx = h_x[o] + xn;
            h_x[o] = hx;
            hx_bf[o] = f2bf(hx);
            hid_t[o] = hx;
            timed_t[o] = xn;
        }
    }
    csum += __shfl_xor(csum, 32, 64);
    if (ln < 32) atomicAdd(&x_sum[col], csum);
}

// ---------------- Laplacian (f32 h_x) ----------------
__global__ __launch_bounds__(256) void k_lap(
    const float* __restrict__ h_x, const float* __restrict__ Lv,
    const int* __restrict__ Lj, const int* __restrict__ row_L,
    const int* __restrict__ col_L, const float* __restrict__ coeff,
    float* __restrict__ spat_t) {
    int n = blockIdx.x * 4 + (threadIdx.x >> 6);
    int j = threadIdx.x & 63;
    if (n >= NN) return;
    float a = 0.f;
    int b0 = row_L[n], b1 = row_L[n + 1];
    for (int p = b0; p < b1; ++p) {
        int idx = col_L[p];
        a = fmaf(Lv[idx], h_x[(size_t)64 * Lj[idx] + j], a);
    }
    spat_t[(size_t)64 * n + j] = coeff[0] * a;
}

// ---------------- decoders ----------------
__global__ __launch_bounds__(256) void k_dec(
    const float* __restrict__ hid, const float* __restrict__ W_d1,
    const float* __restrict__ b_d1, const float* __restrict__ W_d2,
    const float* __restrict__ b_d2, const float* __restrict__ W_i1,
    const float* __restrict__ b_i1, const float* __restrict__ W_i2,
    const float* __restrict__ b_i2, float* __restrict__ out_nodes,
    float* __restrict__ pred_in) {
    __shared__ float sh[4][64];
    int wv = threadIdx.x >> 6, j = threadIdx.x & 63;
    int row = blockIdx.x * 4 + wv;
    float hv = hid[(size_t)64 * row + j];
    sh[wv][j] = hv;
    __syncthreads();
    float a1 = b_d1[j], a2 = b_i1[j];
    for (int k = 0; k < 64; ++k) {
        float h = sh[wv][k];
        a1 = fmaf(h, W_d1[k * 64 + j], a1);
        a2 = fmaf(h, W_i1[k * 64 + j], a2);
    }
    a1 = fmaxf(a1, 0.f);
    a2 = fmaxf(a2, 0.f);
    float r0 = a1 * W_d2[j];
    float4 wi = *(const float4*)&W_i2[4 * j];
    float p0 = a2 * wi.x, p1 = a2 * wi.y, p2 = a2 * wi.z, p3 = a2 * wi.w;
    for (int o = 32; o > 0; o >>= 1) {
        r0 += __shfl_down(r0, o, 64);
        p0 += __shfl_down(p0, o, 64);
        p1 += __shfl_down(p1, o, 64);
        p2 += __shfl_down(p2, o, 64);
        p3 += __shfl_down(p3, o, 64);
    }
    if (j == 0) {
        out_nodes[row] = r0 + b_d2[0];
        float4 pv;
        pv.x = p0 + b_i2[0];
        pv.y = p1 + b_i2[1];
        pv.z = p2 + b_i2[2];
        pv.w = p3 + b_i2[3];
        *(float4*)&pred_in[(size_t)4 * row] = pv;
    }
}

extern "C" void kernel_launch(void* const* d_in, const int* in_sizes, int n_in,
                              void* d_out, int out_size, void* d_ws, size_t ws_size,
                              hipStream_t stream) {
    (void)in_sizes; (void)n_in; (void)out_size; (void)ws_size;
    const float* node_attr   = (const float*)d_in[0];
    const float* global_attr = (const float*)d_in[1];
    const float* L_values    = (const float*)d_in[2];
    const float* coeff       = (const float*)d_in[3];
    const int*   edge_attr   = (const int*)d_in[4];
    const int*   edge_index  = (const int*)d_in[5];
    const int*   L_index     = (const int*)d_in[6];
    const float* emb  = (const float*)d_in[8];
    const float* W_ne = (const float*)d_in[9];
    const float* b_ne = (const float*)d_in[10];
    const float* W_eb = (const float*)d_in[11];
    const float* b_eb = (const float*)d_in[12];
    const float* W_nb = (const float*)d_in[13];
    const float* b_nb = (const float*)d_in[14];
    const float* W_gb = (const float*)d_in[15];
    const float* b_gb = (const float*)d_in[16];
    const float* W_d1 = (const float*)d_in[17];
    const float* b_d1 = (const float*)d_in[18];
    const float* W_d2 = (const float*)d_in[19];
    const float* b_d2 = (const float*)d_in[20];
    const float* W_i1 = (const float*)d_in[21];
    const float* b_i1 = (const float*)d_in[22];
    const float* W_i2 = (const float*)d_in[23];
    const float* b_i2 = (const float*)d_in[24];

    const int* s_idx = edge_index;
    const int* r_idx = edge_index + EE;
    const int* Li = L_index;
    const int* Lj = L_index + NZ;

    char* ws = (char*)d_ws;
    size_t off = 0;
    auto alloc = [&](size_t bytes) -> void* {
        void* p = ws + off;
        off = (off + bytes + 255) & ~(size_t)255;
        return p;
    };
    unsigned short* xenc   = (unsigned short*)alloc((size_t)TT * NN * 64 * 2);
    float*          hid    = (float*)alloc((size_t)TT * NN * 64 * 4);
    float*          h_x    = (float*)alloc((size_t)NN * 64 * 4);
    unsigned short* hx_bf  = (unsigned short*)alloc((size_t)NN * 64 * 2);
    unsigned short* h_e    = (unsigned short*)alloc((size_t)EE * 64 * 2);
    unsigned short* recv   = (unsigned short*)alloc((size_t)NN * 64 * 2);
    unsigned short* sentb  = (unsigned short*)alloc((size_t)NN * 64 * 2);
    float* smalls          = (float*)alloc(2048);
    unsigned short* Bpe    = (unsigned short*)alloc((size_t)2 * 24 * 512 * 2);
    unsigned short* Bpn    = (unsigned short*)alloc((size_t)2 * 16 * 512 * 2);
    unsigned short* emb_bf = (unsigned short*)alloc((size_t)100 * 64 * 2);
    int* cnt   = (int*)alloc((size_t)3 * NN * 4);
    int* rowp  = (int*)alloc((size_t)3 * (NN + 1) * 4);
    int* wp    = (int*)alloc((size_t)3 * NN * 4);
    int* col_r = (int*)alloc((size_t)EE * 4);
    int* col_s = (int*)alloc((size_t)EE * 4);
    int* col_L = (int*)alloc((size_t)NZ * 4);

    float* g_cur = smalls;
    float* e_sum = smalls + 64;
    float* x_sum = smalls + 128;
    float* gb_eb = smalls + 192;
    float* gb_nb = smalls + 256;
    int* cnt_r = cnt, *cnt_s = cnt + NN, *cnt_L = cnt + 2 * NN;
    int* row_r = rowp, *row_s = rowp + (NN + 1), *row_L = rowp + 2 * (NN + 1);
    int* wp_r = wp, *wp_s = wp + NN, *wp_L = wp + 2 * NN;

    float* out_nodes = (float*)d_out;                    // [T,N,1]
    float* time_d = out_nodes + (size_t)TT * NN;         // [T,N,64]
    float* spat_d = time_d + (size_t)TT * NN * 64;       // [T,N,64]
    float* pred_in = spat_d + (size_t)TT * NN * 64;      // [T,N,4]

    hipMemsetAsync(h_x, 0, (size_t)NN * 64 * 4, stream);
    hipMemsetAsync(hx_bf, 0, (size_t)NN * 64 * 2, stream);
    hipMemsetAsync(h_e, 0, (size_t)EE * 64 * 2, stream);
    hipMemsetAsync(smalls, 0, 2048, stream);
    hipMemsetAsync(cnt, 0, (size_t)3 * NN * 4, stream);
    hipMemcpyAsync(g_cur, global_attr, 64 * 4, hipMemcpyDeviceToDevice, stream);

    k_count<<<(NZ + 255) / 256, 256, 0, stream>>>(r_idx, s_idx, Li, cnt_r, cnt_s, cnt_L);
    k_scan<<<3, 1024, 0, stream>>>(cnt, rowp, wp);
    k_scatter<<<(NZ + 255) / 256, 256, 0, stream>>>(r_idx, s_idx, Li, wp_r, wp_s, wp_L,
                                                    col_r, col_s, col_L);
    k_pack<<<96, 256, 0, stream>>>(W_eb, W_nb, emb, Bpe, Bpn, emb_bf);
    k_xenc<<<TT * NN / 4, 256, 0, stream>>>(node_attr, W_ne, b_ne, xenc);
    k_gbias<<<1, 64, 0, stream>>>(0, W_gb, b_gb, W_eb, b_eb, W_nb, b_nb,
                                  g_cur, e_sum, x_sum, gb_eb, gb_nb);

    for (int t = 0; t < TT; ++t) {
        const unsigned short* xenc_t = xenc + (size_t)t * NN * 64;
        k_edge<<<EE / 64, 256, 0, stream>>>(xenc_t, h_e, hx_bf, emb_bf,
                                            edge_attr + (size_t)t * EE, s_idx, r_idx,
                                            Bpe, gb_eb, e_sum);
        k_gather<<<(NN + 3) / 4, 256, 0, stream>>>(h_e, row_r, col_r, row_s, col_s,
                                                   recv, sentb);
        k_node<<<(NN + 63) / 64, 256, 0, stream>>>(recv, sentb, xenc_t, h_x, hx_bf,
                                                   Bpn, gb_nb, x_sum,
                                                   hid + (size_t)t * NN * 64,
                                                   time_d + (size_t)t * NN * 64);
        k_lap<<<(NN + 3) / 4, 256, 0, stream>>>(h_x, L_values, Lj, row_L, col_L, coeff,
                                                spat_d + (size_t)t * NN * 64);
        k_gbias<<<1, 64, 0, stream>>>(1, W_gb, b_gb, W_eb, b_eb, W_nb, b_nb,
                                      g_cur, e_sum, x_sum, gb_eb, gb_nb);
    }
    k_dec<<<TT * NN / 4, 256, 0, stream>>>(hid, W_d1, b_d1, W_d2, b_d2,
                                           W_i1, b_i1, W_i2, b_i2, out_nodes, pred_in);
}

// Round 3
// 938.915 us; speedup vs baseline: 3.1737x; 1.9980x over previous
//
#include <hip/hip_runtime.h>

#define TT 4
#define NN 20000
#define EE 320000
#define NZ 340000

typedef __attribute__((ext_vector_type(8))) __bf16 bf16x8;
typedef __attribute__((ext_vector_type(16))) float f32x16;

__device__ __forceinline__ unsigned short f2bf(float f) {
    unsigned int u = __float_as_uint(f);
    u = (u + 0x7FFFu + ((u >> 16) & 1u)) >> 16;
    return (unsigned short)u;
}
__device__ __forceinline__ float bf2f(unsigned short h) {
    return __uint_as_float(((unsigned int)h) << 16);
}

// ---------------- CSR build ----------------
__global__ void k_count(const int* __restrict__ r, const int* __restrict__ s,
                        const int* __restrict__ Li,
                        int* cnt_r, int* cnt_s, int* cnt_L) {
    int i = blockIdx.x * 256 + threadIdx.x;
    if (i < EE) { atomicAdd(&cnt_r[r[i]], 1); atomicAdd(&cnt_s[s[i]], 1); }
    if (i < NZ) { atomicAdd(&cnt_L[Li[i]], 1); }
}

__global__ __launch_bounds__(1024) void k_scan(int* cnt, int* rowp, int* wp) {
    int which = blockIdx.x;
    int* c = cnt + which * NN;
    int* row = rowp + which * (NN + 1);
    int* w = wp + which * NN;
    __shared__ int ssum[1024];
    int tid = threadIdx.x;
    const int CH = (NN + 1023) / 1024;
    int base = tid * CH;
    int s = 0;
    for (int i = 0; i < CH; ++i) { int idx = base + i; s += (idx < NN) ? c[idx] : 0; }
    ssum[tid] = s;
    __syncthreads();
    for (int o = 1; o < 1024; o <<= 1) {
        int v = (tid >= o) ? ssum[tid - o] : 0;
        __syncthreads();
        ssum[tid] += v;
        __syncthreads();
    }
    int run = (tid > 0) ? ssum[tid - 1] : 0;
    for (int i = 0; i < CH; ++i) {
        int idx = base + i;
        if (idx < NN) { row[idx] = run; w[idx] = run; run += c[idx]; }
    }
    if (tid == 1023) row[NN] = ssum[1023];
}

__global__ void k_scatter(const int* __restrict__ r, const int* __restrict__ s,
                          const int* __restrict__ Li, const int* __restrict__ Lj,
                          const float* __restrict__ Lv,
                          int* wp_r, int* wp_s, int* wp_L,
                          int* col_r, int* col_s, int* col_Lj, float* col_Lv) {
    int i = blockIdx.x * 256 + threadIdx.x;
    if (i < EE) {
        col_r[atomicAdd(&wp_r[r[i]], 1)] = i;
        col_s[atomicAdd(&wp_s[s[i]], 1)] = i;
    }
    if (i < NZ) {
        int pos = atomicAdd(&wp_L[Li[i]], 1);
        col_Lj[pos] = Lj[i];
        col_Lv[pos] = Lv[i];
    }
}

// ---------------- weight packing to bf16 MFMA fragment order ----------------
// Bp layout: [colhalf(2)][kbg][lane(64)][8] ; col = ch*32 + (l&31), k = kbg*16 + (l>>5)*8 + i
__global__ __launch_bounds__(256) void k_pack(
    const float* __restrict__ W_eb, const float* __restrict__ W_nb,
    const float* __restrict__ emb, unsigned short* __restrict__ Bpe,
    unsigned short* __restrict__ Bpn, unsigned short* __restrict__ emb_bf) {
    int t = blockIdx.x * 256 + threadIdx.x;
    if (t < 2 * 24 * 512) {
        int i = t & 7, l = (t >> 3) & 63, kb = (t >> 9) % 24, ch = t / (24 * 512);
        int colv = ch * 32 + (l & 31);
        int k = kb * 16 + (l >> 5) * 8 + i;
        Bpe[t] = f2bf(W_eb[k * 64 + colv]);
    }
    if (t < 2 * 16 * 512) {
        int i = t & 7, l = (t >> 3) & 63, kb = (t >> 9) % 16, ch = t / (16 * 512);
        int colv = ch * 32 + (l & 31);
        int k = kb * 16 + (l >> 5) * 8 + i;
        Bpn[t] = f2bf(W_nb[k * 64 + colv]);
    }
    if (t < 100 * 64) emb_bf[t] = f2bf(emb[t]);
}

// ---------------- node encoder (bf16 out) ----------------
__global__ __launch_bounds__(256) void k_xenc(const float* __restrict__ na,
                                              const float* __restrict__ W_ne,
                                              const float* __restrict__ b_ne,
                                              unsigned short* __restrict__ xenc) {
    int row = blockIdx.x * 4 + (threadIdx.x >> 6);
    int j = threadIdx.x & 63;
    float4 a = *(const float4*)&na[(size_t)row * 4];
    float v = b_ne[j] + a.x * W_ne[j] + a.y * W_ne[64 + j] + a.z * W_ne[128 + j] + a.w * W_ne[192 + j];
    xenc[(size_t)row * 64 + j] = f2bf(fmaxf(v, 0.f));
}

// ---------------- global block + g-bias fold ----------------
__global__ void k_gbias(int do_update, const float* __restrict__ W_gb,
                        const float* __restrict__ b_gb, const float* __restrict__ W_eb,
                        const float* __restrict__ b_eb, const float* __restrict__ W_nb,
                        const float* __restrict__ b_nb, float* __restrict__ g_cur,
                        float* __restrict__ e_sum, float* __restrict__ x_sum,
                        float* __restrict__ gb_eb, float* __restrict__ gb_nb) {
    int j = threadIdx.x; // 64 threads
    float a = 0.f;
    if (do_update) {
        a = b_gb[j];
        for (int k = 0; k < 64; ++k) a += (e_sum[k] / (float)EE) * W_gb[k * 64 + j];
        for (int k = 0; k < 64; ++k) a += (x_sum[k] / (float)NN) * W_gb[(64 + k) * 64 + j];
        for (int k = 0; k < 64; ++k) a += g_cur[k] * W_gb[(128 + k) * 64 + j];
    }
    __syncthreads();
    if (do_update) {
        g_cur[j] = fmaxf(a, 0.f);
        e_sum[j] = 0.f;
        x_sum[j] = 0.f;
    }
    __syncthreads();
    float a1 = b_eb[j], a2 = b_nb[j];
    for (int k = 0; k < 64; ++k) {
        float gk = g_cur[k];
        a1 = fmaf(gk, W_eb[(384 + k) * 64 + j], a1);
        a2 = fmaf(gk, W_nb[(256 + k) * 64 + j], a2);
    }
    gb_eb[j] = a1;
    gb_nb[j] = a2;
}

// ---------------- edge block: barrier-free, all-register MFMA GEMM ----------------
// 4 waves/block, each wave owns 32 edges x 64 cols. A gathered global->reg, B coalesced.
#define EDGE_CHUNK(CIDX, BASE)                                                          \
    {                                                                                   \
        const unsigned short* src = (BASE) + hi * 8;                                    \
        _Pragma("unroll") for (int kb = 0; kb < 4; ++kb) {                              \
            bf16x8 a = *(const bf16x8*)(src + kb * 16);                                 \
            bf16x8 b0 = *(const bf16x8*)&Bp[(size_t)(((CIDX)*4 + kb) * 64 + ln) * 8];   \
            bf16x8 b1 = *(const bf16x8*)&Bp[(size_t)((24 + (CIDX)*4 + kb) * 64 + ln) * 8]; \
            acc0 = __builtin_amdgcn_mfma_f32_32x32x16_bf16(a, b0, acc0, 0, 0, 0);       \
            acc1 = __builtin_amdgcn_mfma_f32_32x32x16_bf16(a, b1, acc1, 0, 0, 0);       \
        }                                                                               \
    }

__global__ __launch_bounds__(256) void k_edge(
    const unsigned short* __restrict__ xenc_t, unsigned short* __restrict__ h_e,
    const unsigned short* __restrict__ hx_bf, const unsigned short* __restrict__ emb_bf,
    const int* __restrict__ eattr_t, const int* __restrict__ sidx,
    const int* __restrict__ ridx, const unsigned short* __restrict__ Bp,
    const float* __restrict__ gbias, float* __restrict__ e_sum) {
    __shared__ float sRed[4][64];
    const int tid = threadIdx.x;
    const int w = tid >> 6, ln = tid & 63;
    const int er = ln & 31, hi = ln >> 5;
    const int ebase = blockIdx.x * 128 + w * 32;
    const int e = ebase + er;
    const int si = sidx[e], ri = ridx[e], ai = eattr_t[e];

    f32x16 acc0, acc1;
    #pragma unroll
    for (int i = 0; i < 16; ++i) { acc0[i] = 0.f; acc1[i] = 0.f; }

    EDGE_CHUNK(0, emb_bf + (size_t)64 * ai)
    EDGE_CHUNK(1, h_e + (size_t)64 * e)
    EDGE_CHUNK(2, xenc_t + (size_t)64 * si)
    EDGE_CHUNK(3, hx_bf + (size_t)64 * si)
    EDGE_CHUNK(4, xenc_t + (size_t)64 * ri)
    EDGE_CHUNK(5, hx_bf + (size_t)64 * ri)

    const float gb0 = gbias[er], gb1 = gbias[er + 32];
    float cs0 = 0.f, cs1 = 0.f;
    #pragma unroll
    for (int r = 0; r < 16; ++r) {
        int row = (r & 3) + 8 * (r >> 2) + 4 * hi;
        size_t o = (size_t)(ebase + row) * 64;
        float v0 = fmaxf(acc0[r] + gb0, 0.f);
        float v1 = fmaxf(acc1[r] + gb1, 0.f);
        cs0 += v0; cs1 += v1;
        h_e[o + er] = f2bf(v0);
        h_e[o + er + 32] = f2bf(v1);
    }
    cs0 += __shfl_xor(cs0, 32, 64);
    cs1 += __shfl_xor(cs1, 32, 64);
    if (hi == 0) { sRed[w][er] = cs0; sRed[w][er + 32] = cs1; }
    __syncthreads();
    if (w == 0) {
        float t = sRed[0][ln] + sRed[1][ln] + sRed[2][ln] + sRed[3][ln];
        atomicAdd(&e_sum[ln], t);
    }
}

// ---------------- recv/sent gather: 8 threads per node ----------------
__global__ __launch_bounds__(256) void k_gather(
    const unsigned short* __restrict__ h_e, const int* __restrict__ row_r,
    const int* __restrict__ col_r, const int* __restrict__ row_s,
    const int* __restrict__ col_s, unsigned short* __restrict__ recv,
    unsigned short* __restrict__ sentb) {
    int t = blockIdx.x * 256 + threadIdx.x;
    int g = t & 7, n = t >> 3;
    float a[8];
    uint4 packed;
    unsigned int* pu = (unsigned int*)&packed;

    #pragma unroll
    for (int i = 0; i < 8; ++i) a[i] = 0.f;
    int b0 = row_r[n], b1 = row_r[n + 1];
    for (int p = b0; p < b1; ++p) {
        uint4 v = *(const uint4*)&h_e[(size_t)64 * col_r[p] + g * 8];
        unsigned int* u = (unsigned int*)&v;
        #pragma unroll
        for (int q = 0; q < 4; ++q) {
            a[2 * q] += bf2f((unsigned short)(u[q] & 0xFFFF));
            a[2 * q + 1] += bf2f((unsigned short)(u[q] >> 16));
        }
    }
    #pragma unroll
    for (int q = 0; q < 4; ++q)
        pu[q] = (unsigned int)f2bf(a[2 * q]) | ((unsigned int)f2bf(a[2 * q + 1]) << 16);
    *(uint4*)&recv[(size_t)64 * n + g * 8] = packed;

    #pragma unroll
    for (int i = 0; i < 8; ++i) a[i] = 0.f;
    b0 = row_s[n]; b1 = row_s[n + 1];
    for (int p = b0; p < b1; ++p) {
        uint4 v = *(const uint4*)&h_e[(size_t)64 * col_s[p] + g * 8];
        unsigned int* u = (unsigned int*)&v;
        #pragma unroll
        for (int q = 0; q < 4; ++q) {
            a[2 * q] += bf2f((unsigned short)(u[q] & 0xFFFF));
            a[2 * q + 1] += bf2f((unsigned short)(u[q] >> 16));
        }
    }
    #pragma unroll
    for (int q = 0; q < 4; ++q)
        pu[q] = (unsigned int)f2bf(a[2 * q]) | ((unsigned int)f2bf(a[2 * q + 1]) << 16);
    *(uint4*)&sentb[(size_t)64 * n + g * 8] = packed;
}

// ---------------- node block: barrier-free MFMA GEMM, 1 wave/block ----------------
#define NODE_CHUNK(CIDX, BASE)                                                          \
    {                                                                                   \
        const unsigned short* src = (BASE) + hi * 8;                                    \
        _Pragma("unroll") for (int kb = 0; kb < 4; ++kb) {                              \
            bf16x8 a = *(const bf16x8*)(src + kb * 16);                                 \
            bf16x8 b0 = *(const bf16x8*)&Bp[(size_t)(((CIDX)*4 + kb) * 64 + ln) * 8];   \
            bf16x8 b1 = *(const bf16x8*)&Bp[(size_t)((16 + (CIDX)*4 + kb) * 64 + ln) * 8]; \
            acc0 = __builtin_amdgcn_mfma_f32_32x32x16_bf16(a, b0, acc0, 0, 0, 0);       \
            acc1 = __builtin_amdgcn_mfma_f32_32x32x16_bf16(a, b1, acc1, 0, 0, 0);       \
        }                                                                               \
    }

__global__ __launch_bounds__(64) void k_node(
    const unsigned short* __restrict__ recv, const unsigned short* __restrict__ sentb,
    const unsigned short* __restrict__ xenc_t, float* __restrict__ h_x,
    unsigned short* __restrict__ hx_bf, const unsigned short* __restrict__ Bp,
    const float* __restrict__ gbias, float* __restrict__ x_sum,
    float* __restrict__ hid_t, float* __restrict__ timed_t) {
    const int ln = threadIdx.x;
    const int er = ln & 31, hi = ln >> 5;
    const int n0 = blockIdx.x * 32;
    const int n = n0 + er;

    f32x16 acc0, acc1;
    #pragma unroll
    for (int i = 0; i < 16; ++i) { acc0[i] = 0.f; acc1[i] = 0.f; }

    NODE_CHUNK(0, recv + (size_t)64 * n)
    NODE_CHUNK(1, sentb + (size_t)64 * n)
    NODE_CHUNK(2, xenc_t + (size_t)64 * n)
    NODE_CHUNK(3, hx_bf + (size_t)64 * n)

    const float gb0 = gbias[er], gb1 = gbias[er + 32];
    float cs0 = 0.f, cs1 = 0.f;
    #pragma unroll
    for (int r = 0; r < 16; ++r) {
        int row = (r & 3) + 8 * (r >> 2) + 4 * hi;
        size_t o = (size_t)(n0 + row) * 64;
        float x0 = fmaxf(acc0[r] + gb0, 0.f);
        float x1 = fmaxf(acc1[r] + gb1, 0.f);
        cs0 += x0; cs1 += x1;
        float hx0 = h_x[o + er] + x0;
        float hx1 = h_x[o + er + 32] + x1;
        h_x[o + er] = hx0;       h_x[o + er + 32] = hx1;
        hx_bf[o + er] = f2bf(hx0); hx_bf[o + er + 32] = f2bf(hx1);
        hid_t[o + er] = hx0;     hid_t[o + er + 32] = hx1;
        timed_t[o + er] = x0;    timed_t[o + er + 32] = x1;
    }
    cs0 += __shfl_xor(cs0, 32, 64);
    cs1 += __shfl_xor(cs1, 32, 64);
    if (hi == 0) {
        atomicAdd(&x_sum[er], cs0);
        atomicAdd(&x_sum[er + 32], cs1);
    }
}

// ---------------- Laplacian: 16 threads per node ----------------
__global__ __launch_bounds__(256) void k_lap(
    const float* __restrict__ h_x, const int* __restrict__ row_L,
    const int* __restrict__ col_Lj, const float* __restrict__ col_Lv,
    const float* __restrict__ coeff, float* __restrict__ spat_t) {
    int t = blockIdx.x * 256 + threadIdx.x;
    int g = t & 15, n = t >> 4;
    float a0 = 0.f, a1 = 0.f, a2 = 0.f, a3 = 0.f;
    int b0 = row_L[n], b1 = row_L[n + 1];
    for (int p = b0; p < b1; ++p) {
        float lv = col_Lv[p];
        int j = col_Lj[p];
        float4 v = *(const float4*)&h_x[(size_t)64 * j + g * 4];
        a0 = fmaf(lv, v.x, a0);
        a1 = fmaf(lv, v.y, a1);
        a2 = fmaf(lv, v.z, a2);
        a3 = fmaf(lv, v.w, a3);
    }
    float c = coeff[0];
    float4 outv = {c * a0, c * a1, c * a2, c * a3};
    *(float4*)&spat_t[(size_t)64 * n + g * 4] = outv;
}

// ---------------- decoders ----------------
__global__ __launch_bounds__(256) void k_dec(
    const float* __restrict__ hid, const float* __restrict__ W_d1,
    const float* __restrict__ b_d1, const float* __restrict__ W_d2,
    const float* __restrict__ b_d2, const float* __restrict__ W_i1,
    const float* __restrict__ b_i1, const float* __restrict__ W_i2,
    const float* __restrict__ b_i2, float* __restrict__ out_nodes,
    float* __restrict__ pred_in) {
    __shared__ float sh[4][64];
    int wv = threadIdx.x >> 6, j = threadIdx.x & 63;
    int row = blockIdx.x * 4 + wv;
    float hv = hid[(size_t)64 * row + j];
    sh[wv][j] = hv;
    __syncthreads();
    float a1 = b_d1[j], a2 = b_i1[j];
    for (int k = 0; k < 64; ++k) {
        float h = sh[wv][k];
        a1 = fmaf(h, W_d1[k * 64 + j], a1);
        a2 = fmaf(h, W_i1[k * 64 + j], a2);
    }
    a1 = fmaxf(a1, 0.f);
    a2 = fmaxf(a2, 0.f);
    float r0 = a1 * W_d2[j];
    float4 wi = *(const float4*)&W_i2[4 * j];
    float p0 = a2 * wi.x, p1 = a2 * wi.y, p2 = a2 * wi.z, p3 = a2 * wi.w;
    for (int o = 32; o > 0; o >>= 1) {
        r0 += __shfl_down(r0, o, 64);
        p0 += __shfl_down(p0, o, 64);
        p1 += __shfl_down(p1, o, 64);
        p2 += __shfl_down(p2, o, 64);
        p3 += __shfl_down(p3, o, 64);
    }
    if (j == 0) {
        out_nodes[row] = r0 + b_d2[0];
        float4 pv;
        pv.x = p0 + b_i2[0];
        pv.y = p1 + b_i2[1];
        pv.z = p2 + b_i2[2];
        pv.w = p3 + b_i2[3];
        *(float4*)&pred_in[(size_t)4 * row] = pv;
    }
}

extern "C" void kernel_launch(void* const* d_in, const int* in_sizes, int n_in,
                              void* d_out, int out_size, void* d_ws, size_t ws_size,
                              hipStream_t stream) {
    (void)in_sizes; (void)n_in; (void)out_size; (void)ws_size;
    const float* node_attr   = (const float*)d_in[0];
    const float* global_attr = (const float*)d_in[1];
    const float* L_values    = (const float*)d_in[2];
    const float* coeff       = (const float*)d_in[3];
    const int*   edge_attr   = (const int*)d_in[4];
    const int*   edge_index  = (const int*)d_in[5];
    const int*   L_index     = (const int*)d_in[6];
    const float* emb  = (const float*)d_in[8];
    const float* W_ne = (const float*)d_in[9];
    const float* b_ne = (const float*)d_in[10];
    const float* W_eb = (const float*)d_in[11];
    const float* b_eb = (const float*)d_in[12];
    const float* W_nb = (const float*)d_in[13];
    const float* b_nb = (const float*)d_in[14];
    const float* W_gb = (const float*)d_in[15];
    const float* b_gb = (const float*)d_in[16];
    const float* W_d1 = (const float*)d_in[17];
    const float* b_d1 = (const float*)d_in[18];
    const float* W_d2 = (const float*)d_in[19];
    const float* b_d2 = (const float*)d_in[20];
    const float* W_i1 = (const float*)d_in[21];
    const float* b_i1 = (const float*)d_in[22];
    const float* W_i2 = (const float*)d_in[23];
    const float* b_i2 = (const float*)d_in[24];

    const int* s_idx = edge_index;
    const int* r_idx = edge_index + EE;
    const int* Li = L_index;
    const int* Lj = L_index + NZ;

    char* ws = (char*)d_ws;
    size_t off = 0;
    auto alloc = [&](size_t bytes) -> void* {
        void* p = ws + off;
        off = (off + bytes + 255) & ~(size_t)255;
        return p;
    };
    unsigned short* xenc   = (unsigned short*)alloc((size_t)TT * NN * 64 * 2);
    float*          hid    = (float*)alloc((size_t)TT * NN * 64 * 4);
    float*          h_x    = (float*)alloc((size_t)NN * 64 * 4);
    unsigned short* hx_bf  = (unsigned short*)alloc((size_t)NN * 64 * 2);
    unsigned short* h_e    = (unsigned short*)alloc((size_t)EE * 64 * 2);
    unsigned short* recv   = (unsigned short*)alloc((size_t)NN * 64 * 2);
    unsigned short* sentb  = (unsigned short*)alloc((size_t)NN * 64 * 2);
    float* smalls          = (float*)alloc(2048);
    unsigned short* Bpe    = (unsigned short*)alloc((size_t)2 * 24 * 512 * 2);
    unsigned short* Bpn    = (unsigned short*)alloc((size_t)2 * 16 * 512 * 2);
    unsigned short* emb_bf = (unsigned short*)alloc((size_t)100 * 64 * 2);
    int* cnt    = (int*)alloc((size_t)3 * NN * 4);
    int* rowp   = (int*)alloc((size_t)3 * (NN + 1) * 4);
    int* wp     = (int*)alloc((size_t)3 * NN * 4);
    int* col_r  = (int*)alloc((size_t)EE * 4);
    int* col_s  = (int*)alloc((size_t)EE * 4);
    int* col_Lj = (int*)alloc((size_t)NZ * 4);
    float* col_Lv = (float*)alloc((size_t)NZ * 4);

    float* g_cur = smalls;
    float* e_sum = smalls + 64;
    float* x_sum = smalls + 128;
    float* gb_eb = smalls + 192;
    float* gb_nb = smalls + 256;
    int* cnt_r = cnt, *cnt_s = cnt + NN, *cnt_L = cnt + 2 * NN;
    int* row_r = rowp, *row_s = rowp + (NN + 1), *row_L = rowp + 2 * (NN + 1);
    int* wp_r = wp, *wp_s = wp + NN, *wp_L = wp + 2 * NN;

    float* out_nodes = (float*)d_out;                    // [T,N,1]
    float* time_d = out_nodes + (size_t)TT * NN;         // [T,N,64]
    float* spat_d = time_d + (size_t)TT * NN * 64;       // [T,N,64]
    float* pred_in = spat_d + (size_t)TT * NN * 64;      // [T,N,4]

    hipMemsetAsync(h_x, 0, (size_t)NN * 64 * 4, stream);
    hipMemsetAsync(hx_bf, 0, (size_t)NN * 64 * 2, stream);
    hipMemsetAsync(h_e, 0, (size_t)EE * 64 * 2, stream);
    hipMemsetAsync(smalls, 0, 2048, stream);
    hipMemsetAsync(cnt, 0, (size_t)3 * NN * 4, stream);
    hipMemcpyAsync(g_cur, global_attr, 64 * 4, hipMemcpyDeviceToDevice, stream);

    k_count<<<(NZ + 255) / 256, 256, 0, stream>>>(r_idx, s_idx, Li, cnt_r, cnt_s, cnt_L);
    k_scan<<<3, 1024, 0, stream>>>(cnt, rowp, wp);
    k_scatter<<<(NZ + 255) / 256, 256, 0, stream>>>(r_idx, s_idx, Li, Lj, L_values,
                                                    wp_r, wp_s, wp_L,
                                                    col_r, col_s, col_Lj, col_Lv);
    k_pack<<<96, 256, 0, stream>>>(W_eb, W_nb, emb, Bpe, Bpn, emb_bf);
    k_xenc<<<TT * NN / 4, 256, 0, stream>>>(node_attr, W_ne, b_ne, xenc);
    k_gbias<<<1, 64, 0, stream>>>(0, W_gb, b_gb, W_eb, b_eb, W_nb, b_nb,
                                  g_cur, e_sum, x_sum, gb_eb, gb_nb);

    for (int t = 0; t < TT; ++t) {
        const unsigned short* xenc_t = xenc + (size_t)t * NN * 64;
        k_edge<<<EE / 128, 256, 0, stream>>>(xenc_t, h_e, hx_bf, emb_bf,
                                             edge_attr + (size_t)t * EE, s_idx, r_idx,
                                             Bpe, gb_eb, e_sum);
        k_gather<<<NN * 8 / 256, 256, 0, stream>>>(h_e, row_r, col_r, row_s, col_s,
                                                   recv, sentb);
        k_node<<<NN / 32, 64, 0, stream>>>(recv, sentb, xenc_t, h_x, hx_bf,
                                           Bpn, gb_nb, x_sum,
                                           hid + (size_t)t * NN * 64,
                                           time_d + (size_t)t * NN * 64);
        k_lap<<<NN * 16 / 256, 256, 0, stream>>>(h_x, row_L, col_Lj, col_Lv, coeff,
                                                 spat_d + (size_t)t * NN * 64);
        k_gbias<<<1, 64, 0, stream>>>(1, W_gb, b_gb, W_eb, b_eb, W_nb, b_nb,
                                      g_cur, e_sum, x_sum, gb_eb, gb_nb);
    }
    k_dec<<<TT * NN / 4, 256, 0, stream>>>(hid, W_d1, b_d1, W_d2, b_d2,
                                           W_i1, b_i1, W_i2, b_i2, out_nodes, pred_in);
}

// Round 4
// 897.219 us; speedup vs baseline: 3.3212x; 1.0465x over previous
//
#include <hip/hip_runtime.h>

#define TT 4
#define NN 20000
#define EE 320000
#define NZ 340000

typedef __attribute__((ext_vector_type(8))) __bf16 bf16x8;
typedef __attribute__((ext_vector_type(16))) float f32x16;

__device__ __forceinline__ unsigned short f2bf(float f) {
    unsigned int u = __float_as_uint(f);
    u = (u + 0x7FFFu + ((u >> 16) & 1u)) >> 16;
    return (unsigned short)u;
}
__device__ __forceinline__ float bf2f(unsigned short h) {
    return __uint_as_float(((unsigned int)h) << 16);
}

#define GLL16(src, dst) __builtin_amdgcn_global_load_lds( \
    (const __attribute__((address_space(1))) unsigned int*)(src), \
    (__attribute__((address_space(3))) unsigned int*)(dst), 16, 0, 0)

// ---------------- CSR build ----------------
__global__ void k_count(const int* __restrict__ r, const int* __restrict__ s,
                        const int* __restrict__ Li,
                        int* cnt_r, int* cnt_s, int* cnt_L) {
    int i = blockIdx.x * 256 + threadIdx.x;
    if (i < EE) { atomicAdd(&cnt_r[r[i]], 1); atomicAdd(&cnt_s[s[i]], 1); }
    if (i < NZ) { atomicAdd(&cnt_L[Li[i]], 1); }
}

__global__ __launch_bounds__(1024) void k_scan(int* cnt, int* rowp, int* wp) {
    int which = blockIdx.x;
    int* c = cnt + which * NN;
    int* row = rowp + which * (NN + 1);
    int* w = wp + which * NN;
    __shared__ int ssum[1024];
    int tid = threadIdx.x;
    const int CH = (NN + 1023) / 1024;
    int base = tid * CH;
    int s = 0;
    for (int i = 0; i < CH; ++i) { int idx = base + i; s += (idx < NN) ? c[idx] : 0; }
    ssum[tid] = s;
    __syncthreads();
    for (int o = 1; o < 1024; o <<= 1) {
        int v = (tid >= o) ? ssum[tid - o] : 0;
        __syncthreads();
        ssum[tid] += v;
        __syncthreads();
    }
    int run = (tid > 0) ? ssum[tid - 1] : 0;
    for (int i = 0; i < CH; ++i) {
        int idx = base + i;
        if (idx < NN) { row[idx] = run; w[idx] = run; run += c[idx]; }
    }
    if (tid == 1023) row[NN] = ssum[1023];
}

__global__ void k_scatter(const int* __restrict__ r, const int* __restrict__ s,
                          const int* __restrict__ Li, const int* __restrict__ Lj,
                          const float* __restrict__ Lv,
                          int* wp_r, int* wp_s, int* wp_L,
                          int* col_r, int* col_s, int* col_Lj, float* col_Lv) {
    int i = blockIdx.x * 256 + threadIdx.x;
    if (i < EE) {
        col_r[atomicAdd(&wp_r[r[i]], 1)] = i;
        col_s[atomicAdd(&wp_s[s[i]], 1)] = i;
    }
    if (i < NZ) {
        int pos = atomicAdd(&wp_L[Li[i]], 1);
        col_Lj[pos] = Lj[i];
        col_Lv[pos] = Lv[i];
    }
}

// ---------------- weight packing to bf16 MFMA fragment order ----------------
// Bp layout: [section][kb][lane(64)][8]; col = base + (l&31), k = kb*16 + (l>>5)*8 + i
__global__ __launch_bounds__(256) void k_pack(
    const float* __restrict__ W_eb, const float* __restrict__ W_nb,
    const float* __restrict__ W_d1, const float* __restrict__ W_i1,
    const float* __restrict__ emb, unsigned short* __restrict__ Bpe,
    unsigned short* __restrict__ Bpn, unsigned short* __restrict__ Bpd,
    unsigned short* __restrict__ emb_bf) {
    int t = blockIdx.x * 256 + threadIdx.x;
    if (t < 2 * 24 * 512) {
        int i = t & 7, l = (t >> 3) & 63, kb = (t >> 9) % 24, ch = t / (24 * 512);
        int colv = ch * 32 + (l & 31);
        int k = kb * 16 + (l >> 5) * 8 + i;
        Bpe[t] = f2bf(W_eb[k * 64 + colv]);
    }
    if (t < 2 * 16 * 512) {
        int i = t & 7, l = (t >> 3) & 63, kb = (t >> 9) % 16, ch = t / (16 * 512);
        int colv = ch * 32 + (l & 31);
        int k = kb * 16 + (l >> 5) * 8 + i;
        Bpn[t] = f2bf(W_nb[k * 64 + colv]);
    }
    if (t < 4 * 4 * 512) {
        int i = t & 7, l = (t >> 3) & 63, kb = (t >> 9) & 3, sec = t >> 11;
        int colv = (sec & 1) * 32 + (l & 31);
        int k = kb * 16 + (l >> 5) * 8 + i;
        const float* W = (sec < 2) ? W_d1 : W_i1;
        Bpd[t] = f2bf(W[k * 64 + colv]);
    }
    if (t < 100 * 64) emb_bf[t] = f2bf(emb[t]);
}

// ---------------- node encoder (bf16 out) ----------------
__global__ __launch_bounds__(256) void k_xenc(const float* __restrict__ na,
                                              const float* __restrict__ W_ne,
                                              const float* __restrict__ b_ne,
                                              unsigned short* __restrict__ xenc) {
    int row = blockIdx.x * 4 + (threadIdx.x >> 6);
    int j = threadIdx.x & 63;
    float4 a = *(const float4*)&na[(size_t)row * 4];
    float v = b_ne[j] + a.x * W_ne[j] + a.y * W_ne[64 + j] + a.z * W_ne[128 + j] + a.w * W_ne[192 + j];
    xenc[(size_t)row * 64 + j] = f2bf(fmaxf(v, 0.f));
}

// ---------------- global block + g-bias fold ----------------
__global__ void k_gbias(int do_update, const float* __restrict__ W_gb,
                        const float* __restrict__ b_gb, const float* __restrict__ W_eb,
                        const float* __restrict__ b_eb, const float* __restrict__ W_nb,
                        const float* __restrict__ b_nb, float* __restrict__ g_cur,
                        float* __restrict__ e_sum, float* __restrict__ x_sum,
                        float* __restrict__ gb_eb, float* __restrict__ gb_nb) {
    int j = threadIdx.x; // 64 threads
    float a = 0.f;
    if (do_update) {
        a = b_gb[j];
        for (int k = 0; k < 64; ++k) a += (e_sum[k] / (float)EE) * W_gb[k * 64 + j];
        for (int k = 0; k < 64; ++k) a += (x_sum[k] / (float)NN) * W_gb[(64 + k) * 64 + j];
        for (int k = 0; k < 64; ++k) a += g_cur[k] * W_gb[(128 + k) * 64 + j];
    }
    __syncthreads();
    if (do_update) {
        g_cur[j] = fmaxf(a, 0.f);
        e_sum[j] = 0.f;
        x_sum[j] = 0.f;
    }
    __syncthreads();
    float a1 = b_eb[j], a2 = b_nb[j];
    for (int k = 0; k < 64; ++k) {
        float gk = g_cur[k];
        a1 = fmaf(gk, W_eb[(384 + k) * 64 + j], a1);
        a2 = fmaf(gk, W_nb[(256 + k) * 64 + j], a2);
    }
    gb_eb[j] = a1;
    gb_nb[j] = a2;
}

// ---------------- edge block: B staged in LDS, A global->reg, MFMA ----------------
#define EDGE_CHUNK(CIDX, BASE)                                                          \
    {                                                                                   \
        const unsigned short* src = (BASE) + hi * 8;                                    \
        _Pragma("unroll") for (int kb = 0; kb < 4; ++kb) {                              \
            bf16x8 a = *(const bf16x8*)(src + kb * 16);                                 \
            bf16x8 b0 = *(const bf16x8*)&sBe[(((CIDX)*4 + kb) * 64 + ln) * 8];          \
            bf16x8 b1 = *(const bf16x8*)&sBe[((24 + (CIDX)*4 + kb) * 64 + ln) * 8];     \
            acc0 = __builtin_amdgcn_mfma_f32_32x32x16_bf16(a, b0, acc0, 0, 0, 0);       \
            acc1 = __builtin_amdgcn_mfma_f32_32x32x16_bf16(a, b1, acc1, 0, 0, 0);       \
        }                                                                               \
    }

__global__ __launch_bounds__(256) void k_edge(
    const unsigned short* __restrict__ xenc_t, unsigned short* __restrict__ h_e,
    const unsigned short* __restrict__ hx_bf, const unsigned short* __restrict__ emb_bf,
    const int* __restrict__ eattr_t, const int* __restrict__ sidx,
    const int* __restrict__ ridx, const unsigned short* __restrict__ Bp,
    const float* __restrict__ gbias, float* __restrict__ e_sum) {
    __shared__ unsigned short sBe[24576];  // 48 KB packed W_eb
    __shared__ float sRed[4][64];
    const int tid = threadIdx.x;
    const int w = tid >> 6, ln = tid & 63;
    const int er = ln & 31, hi = ln >> 5;
    const int ebase = blockIdx.x * 128 + w * 32;
    const int e = ebase + er;
    const int si = sidx[e], ri = ridx[e], ai = eattr_t[e];

    // stage B: 48 KB, 12 x (256 threads x 16 B)
    #pragma unroll
    for (int i = 0; i < 12; ++i) {
        int off = i * 2048 + w * 512;  // shorts
        GLL16(Bp + off + ln * 8, sBe + off);
    }

    f32x16 acc0, acc1;
    #pragma unroll
    for (int i = 0; i < 16; ++i) { acc0[i] = 0.f; acc1[i] = 0.f; }

    __syncthreads();

    EDGE_CHUNK(0, emb_bf + (size_t)64 * ai)
    EDGE_CHUNK(1, h_e + (size_t)64 * e)
    EDGE_CHUNK(2, xenc_t + (size_t)64 * si)
    EDGE_CHUNK(3, hx_bf + (size_t)64 * si)
    EDGE_CHUNK(4, xenc_t + (size_t)64 * ri)
    EDGE_CHUNK(5, hx_bf + (size_t)64 * ri)

    const float gb0 = gbias[er], gb1 = gbias[er + 32];
    float cs0 = 0.f, cs1 = 0.f;
    #pragma unroll
    for (int r = 0; r < 16; ++r) {
        int row = (r & 3) + 8 * (r >> 2) + 4 * hi;
        size_t o = (size_t)(ebase + row) * 64;
        float v0 = fmaxf(acc0[r] + gb0, 0.f);
        float v1 = fmaxf(acc1[r] + gb1, 0.f);
        cs0 += v0; cs1 += v1;
        h_e[o + er] = f2bf(v0);
        h_e[o + er + 32] = f2bf(v1);
    }
    cs0 += __shfl_xor(cs0, 32, 64);
    cs1 += __shfl_xor(cs1, 32, 64);
    if (hi == 0) { sRed[w][er] = cs0; sRed[w][er + 32] = cs1; }
    __syncthreads();
    if (w == 0) {
        float t = sRed[0][ln] + sRed[1][ln] + sRed[2][ln] + sRed[3][ln];
        atomicAdd(&e_sum[ln], t);
    }
}

// ---------------- recv/sent gather: 8 threads per node ----------------
__global__ __launch_bounds__(256) void k_gather(
    const unsigned short* __restrict__ h_e, const int* __restrict__ row_r,
    const int* __restrict__ col_r, const int* __restrict__ row_s,
    const int* __restrict__ col_s, unsigned short* __restrict__ recv,
    unsigned short* __restrict__ sentb) {
    int t = blockIdx.x * 256 + threadIdx.x;
    int g = t & 7, n = t >> 3;
    float a[8];
    uint4 packed;
    unsigned int* pu = (unsigned int*)&packed;

    #pragma unroll
    for (int i = 0; i < 8; ++i) a[i] = 0.f;
    int b0 = row_r[n], b1 = row_r[n + 1];
    for (int p = b0; p < b1; ++p) {
        uint4 v = *(const uint4*)&h_e[(size_t)64 * col_r[p] + g * 8];
        unsigned int* u = (unsigned int*)&v;
        #pragma unroll
        for (int q = 0; q < 4; ++q) {
            a[2 * q] += bf2f((unsigned short)(u[q] & 0xFFFF));
            a[2 * q + 1] += bf2f((unsigned short)(u[q] >> 16));
        }
    }
    #pragma unroll
    for (int q = 0; q < 4; ++q)
        pu[q] = (unsigned int)f2bf(a[2 * q]) | ((unsigned int)f2bf(a[2 * q + 1]) << 16);
    *(uint4*)&recv[(size_t)64 * n + g * 8] = packed;

    #pragma unroll
    for (int i = 0; i < 8; ++i) a[i] = 0.f;
    b0 = row_s[n]; b1 = row_s[n + 1];
    for (int p = b0; p < b1; ++p) {
        uint4 v = *(const uint4*)&h_e[(size_t)64 * col_s[p] + g * 8];
        unsigned int* u = (unsigned int*)&v;
        #pragma unroll
        for (int q = 0; q < 4; ++q) {
            a[2 * q] += bf2f((unsigned short)(u[q] & 0xFFFF));
            a[2 * q + 1] += bf2f((unsigned short)(u[q] >> 16));
        }
    }
    #pragma unroll
    for (int q = 0; q < 4; ++q)
        pu[q] = (unsigned int)f2bf(a[2 * q]) | ((unsigned int)f2bf(a[2 * q + 1]) << 16);
    *(uint4*)&sentb[(size_t)64 * n + g * 8] = packed;
}

// ---------------- node block: barrier-free MFMA GEMM, 1 wave/block ----------------
#define NODE_CHUNK(CIDX, BASE)                                                          \
    {                                                                                   \
        const unsigned short* src = (BASE) + hi * 8;                                    \
        _Pragma("unroll") for (int kb = 0; kb < 4; ++kb) {                              \
            bf16x8 a = *(const bf16x8*)(src + kb * 16);                                 \
            bf16x8 b0 = *(const bf16x8*)&Bp[(size_t)(((CIDX)*4 + kb) * 64 + ln) * 8];   \
            bf16x8 b1 = *(const bf16x8*)&Bp[(size_t)((16 + (CIDX)*4 + kb) * 64 + ln) * 8]; \
            acc0 = __builtin_amdgcn_mfma_f32_32x32x16_bf16(a, b0, acc0, 0, 0, 0);       \
            acc1 = __builtin_amdgcn_mfma_f32_32x32x16_bf16(a, b1, acc1, 0, 0, 0);       \
        }                                                                               \
    }

__global__ __launch_bounds__(64) void k_node(
    const unsigned short* __restrict__ recv, const unsigned short* __restrict__ sentb,
    const unsigned short* __restrict__ xenc_t, float* __restrict__ h_x,
    unsigned short* __restrict__ hx_bf, const unsigned short* __restrict__ Bp,
    const float* __restrict__ gbias, float* __restrict__ x_sum,
    unsigned short* __restrict__ hid_t, float* __restrict__ timed_t) {
    const int ln = threadIdx.x;
    const int er = ln & 31, hi = ln >> 5;
    const int n0 = blockIdx.x * 32;
    const int n = n0 + er;

    f32x16 acc0, acc1;
    #pragma unroll
    for (int i = 0; i < 16; ++i) { acc0[i] = 0.f; acc1[i] = 0.f; }

    NODE_CHUNK(0, recv + (size_t)64 * n)
    NODE_CHUNK(1, sentb + (size_t)64 * n)
    NODE_CHUNK(2, xenc_t + (size_t)64 * n)
    NODE_CHUNK(3, hx_bf + (size_t)64 * n)

    const float gb0 = gbias[er], gb1 = gbias[er + 32];
    float cs0 = 0.f, cs1 = 0.f;
    #pragma unroll
    for (int r = 0; r < 16; ++r) {
        int row = (r & 3) + 8 * (r >> 2) + 4 * hi;
        size_t o = (size_t)(n0 + row) * 64;
        float x0 = fmaxf(acc0[r] + gb0, 0.f);
        float x1 = fmaxf(acc1[r] + gb1, 0.f);
        cs0 += x0; cs1 += x1;
        float hx0 = h_x[o + er] + x0;
        float hx1 = h_x[o + er + 32] + x1;
        unsigned short hb0 = f2bf(hx0), hb1 = f2bf(hx1);
        h_x[o + er] = hx0;        h_x[o + er + 32] = hx1;
        hx_bf[o + er] = hb0;      hx_bf[o + er + 32] = hb1;
        hid_t[o + er] = hb0;      hid_t[o + er + 32] = hb1;
        timed_t[o + er] = x0;     timed_t[o + er + 32] = x1;
    }
    cs0 += __shfl_xor(cs0, 32, 64);
    cs1 += __shfl_xor(cs1, 32, 64);
    if (hi == 0) {
        atomicAdd(&x_sum[er], cs0);
        atomicAdd(&x_sum[er + 32], cs1);
    }
}

// ---------------- Laplacian: 16 threads per node ----------------
__global__ __launch_bounds__(256) void k_lap(
    const float* __restrict__ h_x, const int* __restrict__ row_L,
    const int* __restrict__ col_Lj, const float* __restrict__ col_Lv,
    const float* __restrict__ coeff, float* __restrict__ spat_t) {
    int t = blockIdx.x * 256 + threadIdx.x;
    int g = t & 15, n = t >> 4;
    float a0 = 0.f, a1 = 0.f, a2 = 0.f, a3 = 0.f;
    int b0 = row_L[n], b1 = row_L[n + 1];
    for (int p = b0; p < b1; ++p) {
        float lv = col_Lv[p];
        int j = col_Lj[p];
        float4 v = *(const float4*)&h_x[(size_t)64 * j + g * 4];
        a0 = fmaf(lv, v.x, a0);
        a1 = fmaf(lv, v.y, a1);
        a2 = fmaf(lv, v.z, a2);
        a3 = fmaf(lv, v.w, a3);
    }
    float c = coeff[0];
    float4 outv = {c * a0, c * a1, c * a2, c * a3};
    *(float4*)&spat_t[(size_t)64 * n + g * 4] = outv;
}

// ---------------- decoders: MFMA layer1, LDS transpose, scalar layer2 ----------------
__global__ __launch_bounds__(256) void k_dec(
    const unsigned short* __restrict__ hid_bf, const unsigned short* __restrict__ Bpd,
    const float* __restrict__ b_d1, const float* __restrict__ W_d2,
    const float* __restrict__ b_d2, const float* __restrict__ b_i1,
    const float* __restrict__ W_i2, const float* __restrict__ b_i2,
    float* __restrict__ out_nodes, float* __restrict__ pred_in) {
    __shared__ unsigned short sDec[4][32 * 138];  // per-wave [32 rows][128 cols + 10 pad]
    const int tid = threadIdx.x;
    const int w = tid >> 6, ln = tid & 63;
    const int er = ln & 31, hi = ln >> 5;
    const int row0 = (blockIdx.x * 4 + w) * 32;

    f32x16 ad0, ad1, ai0, ai1;
    #pragma unroll
    for (int i = 0; i < 16; ++i) { ad0[i] = 0.f; ad1[i] = 0.f; ai0[i] = 0.f; ai1[i] = 0.f; }

    const unsigned short* src = hid_bf + (size_t)(row0 + er) * 64 + hi * 8;
    #pragma unroll
    for (int kb = 0; kb < 4; ++kb) {
        bf16x8 a = *(const bf16x8*)(src + kb * 16);
        bf16x8 bd0 = *(const bf16x8*)&Bpd[((0 * 4 + kb) * 64 + ln) * 8];
        bf16x8 bd1 = *(const bf16x8*)&Bpd[((4 + kb) * 64 + ln) * 8];
        bf16x8 bi0 = *(const bf16x8*)&Bpd[((8 + kb) * 64 + ln) * 8];
        bf16x8 bi1 = *(const bf16x8*)&Bpd[((12 + kb) * 64 + ln) * 8];
        ad0 = __builtin_amdgcn_mfma_f32_32x32x16_bf16(a, bd0, ad0, 0, 0, 0);
        ad1 = __builtin_amdgcn_mfma_f32_32x32x16_bf16(a, bd1, ad1, 0, 0, 0);
        ai0 = __builtin_amdgcn_mfma_f32_32x32x16_bf16(a, bi0, ai0, 0, 0, 0);
        ai1 = __builtin_amdgcn_mfma_f32_32x32x16_bf16(a, bi1, ai1, 0, 0, 0);
    }

    const float bd0v = b_d1[er], bd1v = b_d1[er + 32];
    const float bi0v = b_i1[er], bi1v = b_i1[er + 32];
    unsigned short* sw = &sDec[w][0];
    #pragma unroll
    for (int r = 0; r < 16; ++r) {
        int row = (r & 3) + 8 * (r >> 2) + 4 * hi;
        sw[row * 138 + er]       = f2bf(fmaxf(ad0[r] + bd0v, 0.f));
        sw[row * 138 + er + 32]  = f2bf(fmaxf(ad1[r] + bd1v, 0.f));
        sw[row * 138 + er + 64]  = f2bf(fmaxf(ai0[r] + bi0v, 0.f));
        sw[row * 138 + er + 96]  = f2bf(fmaxf(ai1[r] + bi1v, 0.f));
    }
    __syncthreads();

    const int g_row = row0 + er;
    if (hi == 0) {
        float s = 0.f;
        for (int k = 0; k < 32; ++k) {
            unsigned int u = *(const unsigned int*)&sw[er * 138 + 2 * k];
            s = fmaf(bf2f((unsigned short)(u & 0xFFFF)), W_d2[2 * k], s);
            s = fmaf(bf2f((unsigned short)(u >> 16)), W_d2[2 * k + 1], s);
        }
        out_nodes[g_row] = s + b_d2[0];
    } else {
        float s0 = 0.f, s1 = 0.f, s2 = 0.f, s3 = 0.f;
        for (int k = 0; k < 32; ++k) {
            unsigned int u = *(const unsigned int*)&sw[er * 138 + 64 + 2 * k];
            float vlo = bf2f((unsigned short)(u & 0xFFFF));
            float vhi = bf2f((unsigned short)(u >> 16));
            float4 w0 = *(const float4*)&W_i2[(2 * k) * 4];
            float4 w1 = *(const float4*)&W_i2[(2 * k + 1) * 4];
            s0 = fmaf(vlo, w0.x, fmaf(vhi, w1.x, s0));
            s1 = fmaf(vlo, w0.y, fmaf(vhi, w1.y, s1));
            s2 = fmaf(vlo, w0.z, fmaf(vhi, w1.z, s2));
            s3 = fmaf(vlo, w0.w, fmaf(vhi, w1.w, s3));
        }
        float4 pv = {s0 + b_i2[0], s1 + b_i2[1], s2 + b_i2[2], s3 + b_i2[3]};
        *(float4*)&pred_in[(size_t)4 * g_row] = pv;
    }
}

extern "C" void kernel_launch(void* const* d_in, const int* in_sizes, int n_in,
                              void* d_out, int out_size, void* d_ws, size_t ws_size,
                              hipStream_t stream) {
    (void)in_sizes; (void)n_in; (void)out_size; (void)ws_size;
    const float* node_attr   = (const float*)d_in[0];
    const float* global_attr = (const float*)d_in[1];
    const float* L_values    = (const float*)d_in[2];
    const float* coeff       = (const float*)d_in[3];
    const int*   edge_attr   = (const int*)d_in[4];
    const int*   edge_index  = (const int*)d_in[5];
    const int*   L_index     = (const int*)d_in[6];
    const float* emb  = (const float*)d_in[8];
    const float* W_ne = (const float*)d_in[9];
    const float* b_ne = (const float*)d_in[10];
    const float* W_eb = (const float*)d_in[11];
    const float* b_eb = (const float*)d_in[12];
    const float* W_nb = (const float*)d_in[13];
    const float* b_nb = (const float*)d_in[14];
    const float* W_gb = (const float*)d_in[15];
    const float* b_gb = (const float*)d_in[16];
    const float* W_d1 = (const float*)d_in[17];
    const float* b_d1 = (const float*)d_in[18];
    const float* W_d2 = (const float*)d_in[19];
    const float* b_d2 = (const float*)d_in[20];
    const float* W_i1 = (const float*)d_in[21];
    const float* b_i1 = (const float*)d_in[22];
    const float* W_i2 = (const float*)d_in[23];
    const float* b_i2 = (const float*)d_in[24];

    const int* s_idx = edge_index;
    const int* r_idx = edge_index + EE;
    const int* Li = L_index;
    const int* Lj = L_index + NZ;

    char* ws = (char*)d_ws;
    size_t off = 0;
    auto alloc = [&](size_t bytes) -> void* {
        void* p = ws + off;
        off = (off + bytes + 255) & ~(size_t)255;
        return p;
    };
    unsigned short* xenc   = (unsigned short*)alloc((size_t)TT * NN * 64 * 2);
    unsigned short* hid    = (unsigned short*)alloc((size_t)TT * NN * 64 * 2);
    float*          h_x    = (float*)alloc((size_t)NN * 64 * 4);
    unsigned short* hx_bf  = (unsigned short*)alloc((size_t)NN * 64 * 2);
    unsigned short* h_e    = (unsigned short*)alloc((size_t)EE * 64 * 2);
    unsigned short* recv   = (unsigned short*)alloc((size_t)NN * 64 * 2);
    unsigned short* sentb  = (unsigned short*)alloc((size_t)NN * 64 * 2);
    float* smalls          = (float*)alloc(2048);
    unsigned short* Bpe    = (unsigned short*)alloc((size_t)2 * 24 * 512 * 2);
    unsigned short* Bpn    = (unsigned short*)alloc((size_t)2 * 16 * 512 * 2);
    unsigned short* Bpd    = (unsigned short*)alloc((size_t)4 * 4 * 512 * 2);
    unsigned short* emb_bf = (unsigned short*)alloc((size_t)100 * 64 * 2);
    int* cnt    = (int*)alloc((size_t)3 * NN * 4);
    int* rowp   = (int*)alloc((size_t)3 * (NN + 1) * 4);
    int* wp     = (int*)alloc((size_t)3 * NN * 4);
    int* col_r  = (int*)alloc((size_t)EE * 4);
    int* col_s  = (int*)alloc((size_t)EE * 4);
    int* col_Lj = (int*)alloc((size_t)NZ * 4);
    float* col_Lv = (float*)alloc((size_t)NZ * 4);

    float* g_cur = smalls;
    float* e_sum = smalls + 64;
    float* x_sum = smalls + 128;
    float* gb_eb = smalls + 192;
    float* gb_nb = smalls + 256;
    int* cnt_r = cnt, *cnt_s = cnt + NN, *cnt_L = cnt + 2 * NN;
    int* row_r = rowp, *row_s = rowp + (NN + 1), *row_L = rowp + 2 * (NN + 1);
    int* wp_r = wp, *wp_s = wp + NN, *wp_L = wp + 2 * NN;

    float* out_nodes = (float*)d_out;                    // [T,N,1]
    float* time_d = out_nodes + (size_t)TT * NN;         // [T,N,64]
    float* spat_d = time_d + (size_t)TT * NN * 64;       // [T,N,64]
    float* pred_in = spat_d + (size_t)TT * NN * 64;      // [T,N,4]

    hipMemsetAsync(h_x, 0, (size_t)NN * 64 * 4, stream);
    hipMemsetAsync(hx_bf, 0, (size_t)NN * 64 * 2, stream);
    hipMemsetAsync(h_e, 0, (size_t)EE * 64 * 2, stream);
    hipMemsetAsync(smalls, 0, 2048, stream);
    hipMemsetAsync(cnt, 0, (size_t)3 * NN * 4, stream);
    hipMemcpyAsync(g_cur, global_attr, 64 * 4, hipMemcpyDeviceToDevice, stream);

    k_count<<<(NZ + 255) / 256, 256, 0, stream>>>(r_idx, s_idx, Li, cnt_r, cnt_s, cnt_L);
    k_scan<<<3, 1024, 0, stream>>>(cnt, rowp, wp);
    k_scatter<<<(NZ + 255) / 256, 256, 0, stream>>>(r_idx, s_idx, Li, Lj, L_values,
                                                    wp_r, wp_s, wp_L,
                                                    col_r, col_s, col_Lj, col_Lv);
    k_pack<<<96, 256, 0, stream>>>(W_eb, W_nb, W_d1, W_i1, emb, Bpe, Bpn, Bpd, emb_bf);
    k_xenc<<<TT * NN / 4, 256, 0, stream>>>(node_attr, W_ne, b_ne, xenc);
    k_gbias<<<1, 64, 0, stream>>>(0, W_gb, b_gb, W_eb, b_eb, W_nb, b_nb,
                                  g_cur, e_sum, x_sum, gb_eb, gb_nb);

    for (int t = 0; t < TT; ++t) {
        const unsigned short* xenc_t = xenc + (size_t)t * NN * 64;
        k_edge<<<EE / 128, 256, 0, stream>>>(xenc_t, h_e, hx_bf, emb_bf,
                                             edge_attr + (size_t)t * EE, s_idx, r_idx,
                                             Bpe, gb_eb, e_sum);
        k_gather<<<NN * 8 / 256, 256, 0, stream>>>(h_e, row_r, col_r, row_s, col_s,
                                                   recv, sentb);
        k_node<<<NN / 32, 64, 0, stream>>>(recv, sentb, xenc_t, h_x, hx_bf,
                                           Bpn, gb_nb, x_sum,
                                           hid + (size_t)t * NN * 64,
                                           time_d + (size_t)t * NN * 64);
        k_lap<<<NN * 16 / 256, 256, 0, stream>>>(h_x, row_L, col_Lj, col_Lv, coeff,
                                                 spat_d + (size_t)t * NN * 64);
        k_gbias<<<1, 64, 0, stream>>>(1, W_gb, b_gb, W_eb, b_eb, W_nb, b_nb,
                                      g_cur, e_sum, x_sum, gb_eb, gb_nb);
    }
    k_dec<<<TT * NN / 128, 256, 0, stream>>>(hid, Bpd, b_d1, W_d2, b_d2,
                                             b_i1, W_i2, b_i2, out_nodes, pred_in);
}

// Round 5
// 761.761 us; speedup vs baseline: 3.9118x; 1.1778x over previous
//
#include <hip/hip_runtime.h>

#define TT 4
#define NN 20000
#define EE 320000
#define NZ 340000

typedef __attribute__((ext_vector_type(8))) __bf16 bf16x8;
typedef __attribute__((ext_vector_type(16))) float f32x16;

__device__ __forceinline__ unsigned short f2bf(float f) {
    unsigned int u = __float_as_uint(f);
    u = (u + 0x7FFFu + ((u >> 16) & 1u)) >> 16;
    return (unsigned short)u;
}
__device__ __forceinline__ float bf2f(unsigned short h) {
    return __uint_as_float(((unsigned int)h) << 16);
}

#define GLL16(src, dst) __builtin_amdgcn_global_load_lds( \
    (const __attribute__((address_space(1))) unsigned int*)(src), \
    (__attribute__((address_space(3))) unsigned int*)(dst), 16, 0, 0)

// ---------------- CSR build ----------------
__global__ void k_count(const int* __restrict__ r, const int* __restrict__ s,
                        const int* __restrict__ Li,
                        int* cnt_r, int* cnt_s, int* cnt_L) {
    int i = blockIdx.x * 256 + threadIdx.x;
    if (i < EE) { atomicAdd(&cnt_r[r[i]], 1); atomicAdd(&cnt_s[s[i]], 1); }
    if (i < NZ) { atomicAdd(&cnt_L[Li[i]], 1); }
}

__global__ __launch_bounds__(1024) void k_scan(int* cnt, int* rowp, int* wp) {
    int which = blockIdx.x;
    int* c = cnt + which * NN;
    int* row = rowp + which * (NN + 1);
    int* w = wp + which * NN;
    __shared__ int ssum[1024];
    int tid = threadIdx.x;
    const int CH = (NN + 1023) / 1024;
    int base = tid * CH;
    int s = 0;
    for (int i = 0; i < CH; ++i) { int idx = base + i; s += (idx < NN) ? c[idx] : 0; }
    ssum[tid] = s;
    __syncthreads();
    for (int o = 1; o < 1024; o <<= 1) {
        int v = (tid >= o) ? ssum[tid - o] : 0;
        __syncthreads();
        ssum[tid] += v;
        __syncthreads();
    }
    int run = (tid > 0) ? ssum[tid - 1] : 0;
    for (int i = 0; i < CH; ++i) {
        int idx = base + i;
        if (idx < NN) { row[idx] = run; w[idx] = run; run += c[idx]; }
    }
    if (tid == 1023) row[NN] = ssum[1023];
}

__global__ void k_scatter(const int* __restrict__ r, const int* __restrict__ s,
                          const int* __restrict__ Li, const int* __restrict__ Lj,
                          const float* __restrict__ Lv,
                          int* wp_r, int* wp_s, int* wp_L,
                          int* col_r, int* col_s, int* col_Lj, float* col_Lv) {
    int i = blockIdx.x * 256 + threadIdx.x;
    if (i < EE) {
        col_r[atomicAdd(&wp_r[r[i]], 1)] = i;
        col_s[atomicAdd(&wp_s[s[i]], 1)] = i;
    }
    if (i < NZ) {
        int pos = atomicAdd(&wp_L[Li[i]], 1);
        col_Lj[pos] = Lj[i];
        col_Lv[pos] = Lv[i];
    }
}

// ---------------- weight packing to bf16 MFMA fragment order ----------------
__global__ __launch_bounds__(256) void k_pack(
    const float* __restrict__ W_eb, const float* __restrict__ W_nb,
    const float* __restrict__ W_d1, const float* __restrict__ W_i1,
    const float* __restrict__ emb, unsigned short* __restrict__ Bpe,
    unsigned short* __restrict__ Bpn, unsigned short* __restrict__ Bpd,
    unsigned short* __restrict__ emb_bf) {
    int t = blockIdx.x * 256 + threadIdx.x;
    if (t < 2 * 24 * 512) {
        int i = t & 7, l = (t >> 3) & 63, kb = (t >> 9) % 24, ch = t / (24 * 512);
        int colv = ch * 32 + (l & 31);
        int k = kb * 16 + (l >> 5) * 8 + i;
        Bpe[t] = f2bf(W_eb[k * 64 + colv]);
    }
    if (t < 2 * 16 * 512) {
        int i = t & 7, l = (t >> 3) & 63, kb = (t >> 9) % 16, ch = t / (16 * 512);
        int colv = ch * 32 + (l & 31);
        int k = kb * 16 + (l >> 5) * 8 + i;
        Bpn[t] = f2bf(W_nb[k * 64 + colv]);
    }
    if (t < 4 * 4 * 512) {
        int i = t & 7, l = (t >> 3) & 63, kb = (t >> 9) & 3, sec = t >> 11;
        int colv = (sec & 1) * 32 + (l & 31);
        int k = kb * 16 + (l >> 5) * 8 + i;
        const float* W = (sec < 2) ? W_d1 : W_i1;
        Bpd[t] = f2bf(W[k * 64 + colv]);
    }
    if (t < 100 * 64) emb_bf[t] = f2bf(emb[t]);
}

// ---------------- node encoder (bf16 out) ----------------
__global__ __launch_bounds__(256) void k_xenc(const float* __restrict__ na,
                                              const float* __restrict__ W_ne,
                                              const float* __restrict__ b_ne,
                                              unsigned short* __restrict__ xenc) {
    int row = blockIdx.x * 4 + (threadIdx.x >> 6);
    int j = threadIdx.x & 63;
    float4 a = *(const float4*)&na[(size_t)row * 4];
    float v = b_ne[j] + a.x * W_ne[j] + a.y * W_ne[64 + j] + a.z * W_ne[128 + j] + a.w * W_ne[192 + j];
    xenc[(size_t)row * 64 + j] = f2bf(fmaxf(v, 0.f));
}

// ---------------- global block + g-bias fold ----------------
__global__ void k_gbias(int do_update, const float* __restrict__ W_gb,
                        const float* __restrict__ b_gb, const float* __restrict__ W_eb,
                        const float* __restrict__ b_eb, const float* __restrict__ W_nb,
                        const float* __restrict__ b_nb, float* __restrict__ g_cur,
                        float* __restrict__ e_sum, float* __restrict__ x_sum,
                        float* __restrict__ gb_eb, float* __restrict__ gb_nb) {
    int j = threadIdx.x; // 64 threads
    float a = 0.f;
    if (do_update) {
        a = b_gb[j];
        for (int k = 0; k < 64; ++k) a += (e_sum[k] / (float)EE) * W_gb[k * 64 + j];
        for (int k = 0; k < 64; ++k) a += (x_sum[k] / (float)NN) * W_gb[(64 + k) * 64 + j];
        for (int k = 0; k < 64; ++k) a += g_cur[k] * W_gb[(128 + k) * 64 + j];
    }
    __syncthreads();
    if (do_update) {
        g_cur[j] = fmaxf(a, 0.f);
        e_sum[j] = 0.f;
        x_sum[j] = 0.f;
    }
    __syncthreads();
    float a1 = b_eb[j], a2 = b_nb[j];
    for (int k = 0; k < 64; ++k) {
        float gk = g_cur[k];
        a1 = fmaf(gk, W_eb[(384 + k) * 64 + j], a1);
        a2 = fmaf(gk, W_nb[(256 + k) * 64 + j], a2);
    }
    gb_eb[j] = a1;
    gb_nb[j] = a2;
}

// ---------------- edge block: 8 waves, B in LDS, A reg-double-buffered ----------------
__global__ __launch_bounds__(512) void k_edge(
    const unsigned short* __restrict__ xenc_t, unsigned short* __restrict__ h_e,
    const unsigned short* __restrict__ hx_bf, const unsigned short* __restrict__ emb_bf,
    const int* __restrict__ eattr_t, const int* __restrict__ sidx,
    const int* __restrict__ ridx, const unsigned short* __restrict__ Bp,
    const float* __restrict__ gbias, float* __restrict__ e_sum) {
    __shared__ unsigned short sBe[24576];  // 48 KB packed W_eb
    __shared__ float sRed[8][64];
    const int tid = threadIdx.x;
    const int w = tid >> 6, ln = tid & 63;
    const int er = ln & 31, hi = ln >> 5;
    const int ebase = blockIdx.x * 256 + w * 32;
    const int e = ebase + er;
    const int si = sidx[e], ri = ridx[e], ai = eattr_t[e];

    // stage B: 48 KB = 6 x (512 threads x 16 B), linear both sides
    #pragma unroll
    for (int i = 0; i < 6; ++i) {
        int off = i * 4096 + w * 512;  // shorts, wave-uniform LDS base
        GLL16(Bp + off + ln * 8, sBe + off);
    }

    const unsigned short* base0 = emb_bf + (size_t)64 * ai + hi * 8;
    const unsigned short* base1 = h_e + (size_t)64 * e + hi * 8;
    const unsigned short* base2 = xenc_t + (size_t)64 * si + hi * 8;
    const unsigned short* base3 = hx_bf + (size_t)64 * si + hi * 8;
    const unsigned short* base4 = xenc_t + (size_t)64 * ri + hi * 8;
    const unsigned short* base5 = hx_bf + (size_t)64 * ri + hi * 8;
    const unsigned short* bases[6] = {base0, base1, base2, base3, base4, base5};

    f32x16 acc0, acc1;
    #pragma unroll
    for (int i = 0; i < 16; ++i) { acc0[i] = 0.f; acc1[i] = 0.f; }

    // prefetch chunk 0 A-fragments into registers
    bf16x8 c0 = *(const bf16x8*)(base0);
    bf16x8 c1 = *(const bf16x8*)(base0 + 16);
    bf16x8 c2 = *(const bf16x8*)(base0 + 32);
    bf16x8 c3 = *(const bf16x8*)(base0 + 48);

    __syncthreads();

    #pragma unroll
    for (int c = 0; c < 6; ++c) {
        bf16x8 n0, n1, n2, n3;
        if (c < 5) {
            const unsigned short* nb = bases[c + 1];
            n0 = *(const bf16x8*)(nb);
            n1 = *(const bf16x8*)(nb + 16);
            n2 = *(const bf16x8*)(nb + 32);
            n3 = *(const bf16x8*)(nb + 48);
        }
        {
            bf16x8 b0 = *(const bf16x8*)&sBe[((c * 4 + 0) * 64 + ln) * 8];
            bf16x8 b1 = *(const bf16x8*)&sBe[((24 + c * 4 + 0) * 64 + ln) * 8];
            acc0 = __builtin_amdgcn_mfma_f32_32x32x16_bf16(c0, b0, acc0, 0, 0, 0);
            acc1 = __builtin_amdgcn_mfma_f32_32x32x16_bf16(c0, b1, acc1, 0, 0, 0);
            b0 = *(const bf16x8*)&sBe[((c * 4 + 1) * 64 + ln) * 8];
            b1 = *(const bf16x8*)&sBe[((24 + c * 4 + 1) * 64 + ln) * 8];
            acc0 = __builtin_amdgcn_mfma_f32_32x32x16_bf16(c1, b0, acc0, 0, 0, 0);
            acc1 = __builtin_amdgcn_mfma_f32_32x32x16_bf16(c1, b1, acc1, 0, 0, 0);
            b0 = *(const bf16x8*)&sBe[((c * 4 + 2) * 64 + ln) * 8];
            b1 = *(const bf16x8*)&sBe[((24 + c * 4 + 2) * 64 + ln) * 8];
            acc0 = __builtin_amdgcn_mfma_f32_32x32x16_bf16(c2, b0, acc0, 0, 0, 0);
            acc1 = __builtin_amdgcn_mfma_f32_32x32x16_bf16(c2, b1, acc1, 0, 0, 0);
            b0 = *(const bf16x8*)&sBe[((c * 4 + 3) * 64 + ln) * 8];
            b1 = *(const bf16x8*)&sBe[((24 + c * 4 + 3) * 64 + ln) * 8];
            acc0 = __builtin_amdgcn_mfma_f32_32x32x16_bf16(c3, b0, acc0, 0, 0, 0);
            acc1 = __builtin_amdgcn_mfma_f32_32x32x16_bf16(c3, b1, acc1, 0, 0, 0);
        }
        c0 = n0; c1 = n1; c2 = n2; c3 = n3;
    }

    const float gb0 = gbias[er], gb1 = gbias[er + 32];
    float cs0 = 0.f, cs1 = 0.f;
    #pragma unroll
    for (int r = 0; r < 16; ++r) {
        int row = (r & 3) + 8 * (r >> 2) + 4 * hi;
        size_t o = (size_t)(ebase + row) * 64;
        float v0 = fmaxf(acc0[r] + gb0, 0.f);
        float v1 = fmaxf(acc1[r] + gb1, 0.f);
        cs0 += v0; cs1 += v1;
        h_e[o + er] = f2bf(v0);
        h_e[o + er + 32] = f2bf(v1);
    }
    cs0 += __shfl_xor(cs0, 32, 64);
    cs1 += __shfl_xor(cs1, 32, 64);
    if (hi == 0) { sRed[w][er] = cs0; sRed[w][er + 32] = cs1; }
    __syncthreads();
    if (w == 0) {
        float t = 0.f;
        #pragma unroll
        for (int q = 0; q < 8; ++q) t += sRed[q][ln];
        atomicAdd(&e_sum[ln], t);
    }
}

// ---------------- recv/sent gather: 16 threads per node ----------------
__global__ __launch_bounds__(256) void k_gather(
    const unsigned short* __restrict__ h_e, const int* __restrict__ row_r,
    const int* __restrict__ col_r, const int* __restrict__ row_s,
    const int* __restrict__ col_s, unsigned short* __restrict__ recv,
    unsigned short* __restrict__ sentb) {
    int t = blockIdx.x * 256 + threadIdx.x;
    int g = t & 15, n = t >> 4;
    float a0, a1, a2, a3;
    uint2 packed;

    a0 = a1 = a2 = a3 = 0.f;
    int b0 = row_r[n], b1 = row_r[n + 1];
    for (int p = b0; p < b1; ++p) {
        uint2 v = *(const uint2*)&h_e[(size_t)64 * col_r[p] + g * 4];
        a0 += bf2f((unsigned short)(v.x & 0xFFFF));
        a1 += bf2f((unsigned short)(v.x >> 16));
        a2 += bf2f((unsigned short)(v.y & 0xFFFF));
        a3 += bf2f((unsigned short)(v.y >> 16));
    }
    packed.x = (unsigned int)f2bf(a0) | ((unsigned int)f2bf(a1) << 16);
    packed.y = (unsigned int)f2bf(a2) | ((unsigned int)f2bf(a3) << 16);
    *(uint2*)&recv[(size_t)64 * n + g * 4] = packed;

    a0 = a1 = a2 = a3 = 0.f;
    b0 = row_s[n]; b1 = row_s[n + 1];
    for (int p = b0; p < b1; ++p) {
        uint2 v = *(const uint2*)&h_e[(size_t)64 * col_s[p] + g * 4];
        a0 += bf2f((unsigned short)(v.x & 0xFFFF));
        a1 += bf2f((unsigned short)(v.x >> 16));
        a2 += bf2f((unsigned short)(v.y & 0xFFFF));
        a3 += bf2f((unsigned short)(v.y >> 16));
    }
    packed.x = (unsigned int)f2bf(a0) | ((unsigned int)f2bf(a1) << 16);
    packed.y = (unsigned int)f2bf(a2) | ((unsigned int)f2bf(a3) << 16);
    *(uint2*)&sentb[(size_t)64 * n + g * 4] = packed;
}

// ---------------- node block: barrier-free MFMA GEMM, 1 wave/block ----------------
#define NODE_CHUNK(CIDX, BASE)                                                          \
    {                                                                                   \
        const unsigned short* src = (BASE) + hi * 8;                                    \
        _Pragma("unroll") for (int kb = 0; kb < 4; ++kb) {                              \
            bf16x8 a = *(const bf16x8*)(src + kb * 16);                                 \
            bf16x8 b0 = *(const bf16x8*)&Bp[(size_t)(((CIDX)*4 + kb) * 64 + ln) * 8];   \
            bf16x8 b1 = *(const bf16x8*)&Bp[(size_t)((16 + (CIDX)*4 + kb) * 64 + ln) * 8]; \
            acc0 = __builtin_amdgcn_mfma_f32_32x32x16_bf16(a, b0, acc0, 0, 0, 0);       \
            acc1 = __builtin_amdgcn_mfma_f32_32x32x16_bf16(a, b1, acc1, 0, 0, 0);       \
        }                                                                               \
    }

__global__ __launch_bounds__(64) void k_node(
    const unsigned short* __restrict__ recv, const unsigned short* __restrict__ sentb,
    const unsigned short* __restrict__ xenc_t, float* __restrict__ h_x,
    unsigned short* __restrict__ hx_bf, const unsigned short* __restrict__ Bp,
    const float* __restrict__ gbias, float* __restrict__ x_sum,
    unsigned short* __restrict__ hid_t, float* __restrict__ timed_t) {
    const int ln = threadIdx.x;
    const int er = ln & 31, hi = ln >> 5;
    const int n0 = blockIdx.x * 32;
    const int n = n0 + er;

    f32x16 acc0, acc1;
    #pragma unroll
    for (int i = 0; i < 16; ++i) { acc0[i] = 0.f; acc1[i] = 0.f; }

    NODE_CHUNK(0, recv + (size_t)64 * n)
    NODE_CHUNK(1, sentb + (size_t)64 * n)
    NODE_CHUNK(2, xenc_t + (size_t)64 * n)
    NODE_CHUNK(3, hx_bf + (size_t)64 * n)

    const float gb0 = gbias[er], gb1 = gbias[er + 32];
    float cs0 = 0.f, cs1 = 0.f;
    #pragma unroll
    for (int r = 0; r < 16; ++r) {
        int row = (r & 3) + 8 * (r >> 2) + 4 * hi;
        size_t o = (size_t)(n0 + row) * 64;
        float x0 = fmaxf(acc0[r] + gb0, 0.f);
        float x1 = fmaxf(acc1[r] + gb1, 0.f);
        cs0 += x0; cs1 += x1;
        float hx0 = h_x[o + er] + x0;
        float hx1 = h_x[o + er + 32] + x1;
        unsigned short hb0 = f2bf(hx0), hb1 = f2bf(hx1);
        h_x[o + er] = hx0;        h_x[o + er + 32] = hx1;
        hx_bf[o + er] = hb0;      hx_bf[o + er + 32] = hb1;
        hid_t[o + er] = hb0;      hid_t[o + er + 32] = hb1;
        timed_t[o + er] = x0;     timed_t[o + er + 32] = x1;
    }
    cs0 += __shfl_xor(cs0, 32, 64);
    cs1 += __shfl_xor(cs1, 32, 64);
    if (hi == 0) {
        atomicAdd(&x_sum[er], cs0);
        atomicAdd(&x_sum[er + 32], cs1);
    }
}

// ---------------- Laplacian: 16 threads per node ----------------
__global__ __launch_bounds__(256) void k_lap(
    const float* __restrict__ h_x, const int* __restrict__ row_L,
    const int* __restrict__ col_Lj, const float* __restrict__ col_Lv,
    const float* __restrict__ coeff, float* __restrict__ spat_t) {
    int t = blockIdx.x * 256 + threadIdx.x;
    int g = t & 15, n = t >> 4;
    float a0 = 0.f, a1 = 0.f, a2 = 0.f, a3 = 0.f;
    int b0 = row_L[n], b1 = row_L[n + 1];
    for (int p = b0; p < b1; ++p) {
        float lv = col_Lv[p];
        int j = col_Lj[p];
        float4 v = *(const float4*)&h_x[(size_t)64 * j + g * 4];
        a0 = fmaf(lv, v.x, a0);
        a1 = fmaf(lv, v.y, a1);
        a2 = fmaf(lv, v.z, a2);
        a3 = fmaf(lv, v.w, a3);
    }
    float c = coeff[0];
    float4 outv = {c * a0, c * a1, c * a2, c * a3};
    *(float4*)&spat_t[(size_t)64 * n + g * 4] = outv;
}

// ---------------- decoders: MFMA layer1, LDS transpose, scalar layer2 ----------------
__global__ __launch_bounds__(256) void k_dec(
    const unsigned short* __restrict__ hid_bf, const unsigned short* __restrict__ Bpd,
    const float* __restrict__ b_d1, const float* __restrict__ W_d2,
    const float* __restrict__ b_d2, const float* __restrict__ b_i1,
    const float* __restrict__ W_i2, const float* __restrict__ b_i2,
    float* __restrict__ out_nodes, float* __restrict__ pred_in) {
    __shared__ unsigned short sDec[4][32 * 138];
    const int tid = threadIdx.x;
    const int w = tid >> 6, ln = tid & 63;
    const int er = ln & 31, hi = ln >> 5;
    const int row0 = (blockIdx.x * 4 + w) * 32;

    f32x16 ad0, ad1, ai0, ai1;
    #pragma unroll
    for (int i = 0; i < 16; ++i) { ad0[i] = 0.f; ad1[i] = 0.f; ai0[i] = 0.f; ai1[i] = 0.f; }

    const unsigned short* src = hid_bf + (size_t)(row0 + er) * 64 + hi * 8;
    #pragma unroll
    for (int kb = 0; kb < 4; ++kb) {
        bf16x8 a = *(const bf16x8*)(src + kb * 16);
        bf16x8 bd0 = *(const bf16x8*)&Bpd[((0 * 4 + kb) * 64 + ln) * 8];
        bf16x8 bd1 = *(const bf16x8*)&Bpd[((4 + kb) * 64 + ln) * 8];
        bf16x8 bi0 = *(const bf16x8*)&Bpd[((8 + kb) * 64 + ln) * 8];
        bf16x8 bi1 = *(const bf16x8*)&Bpd[((12 + kb) * 64 + ln) * 8];
        ad0 = __builtin_amdgcn_mfma_f32_32x32x16_bf16(a, bd0, ad0, 0, 0, 0);
        ad1 = __builtin_amdgcn_mfma_f32_32x32x16_bf16(a, bd1, ad1, 0, 0, 0);
        ai0 = __builtin_amdgcn_mfma_f32_32x32x16_bf16(a, bi0, ai0, 0, 0, 0);
        ai1 = __builtin_amdgcn_mfma_f32_32x32x16_bf16(a, bi1, ai1, 0, 0, 0);
    }

    const float bd0v = b_d1[er], bd1v = b_d1[er + 32];
    const float bi0v = b_i1[er], bi1v = b_i1[er + 32];
    unsigned short* sw = &sDec[w][0];
    #pragma unroll
    for (int r = 0; r < 16; ++r) {
        int row = (r & 3) + 8 * (r >> 2) + 4 * hi;
        sw[row * 138 + er]       = f2bf(fmaxf(ad0[r] + bd0v, 0.f));
        sw[row * 138 + er + 32]  = f2bf(fmaxf(ad1[r] + bd1v, 0.f));
        sw[row * 138 + er + 64]  = f2bf(fmaxf(ai0[r] + bi0v, 0.f));
        sw[row * 138 + er + 96]  = f2bf(fmaxf(ai1[r] + bi1v, 0.f));
    }
    __syncthreads();

    const int g_row = row0 + er;
    if (hi == 0) {
        float s = 0.f;
        for (int k = 0; k < 32; ++k) {
            unsigned int u = *(const unsigned int*)&sw[er * 138 + 2 * k];
            s = fmaf(bf2f((unsigned short)(u & 0xFFFF)), W_d2[2 * k], s);
            s = fmaf(bf2f((unsigned short)(u >> 16)), W_d2[2 * k + 1], s);
        }
        out_nodes[g_row] = s + b_d2[0];
    } else {
        float s0 = 0.f, s1 = 0.f, s2 = 0.f, s3 = 0.f;
        for (int k = 0; k < 32; ++k) {
            unsigned int u = *(const unsigned int*)&sw[er * 138 + 64 + 2 * k];
            float vlo = bf2f((unsigned short)(u & 0xFFFF));
            float vhi = bf2f((unsigned short)(u >> 16));
            float4 w0 = *(const float4*)&W_i2[(2 * k) * 4];
            float4 w1 = *(const float4*)&W_i2[(2 * k + 1) * 4];
            s0 = fmaf(vlo, w0.x, fmaf(vhi, w1.x, s0));
            s1 = fmaf(vlo, w0.y, fmaf(vhi, w1.y, s1));
            s2 = fmaf(vlo, w0.z, fmaf(vhi, w1.z, s2));
            s3 = fmaf(vlo, w0.w, fmaf(vhi, w1.w, s3));
        }
        float4 pv = {s0 + b_i2[0], s1 + b_i2[1], s2 + b_i2[2], s3 + b_i2[3]};
        *(float4*)&pred_in[(size_t)4 * g_row] = pv;
    }
}

extern "C" void kernel_launch(void* const* d_in, const int* in_sizes, int n_in,
                              void* d_out, int out_size, void* d_ws, size_t ws_size,
                              hipStream_t stream) {
    (void)in_sizes; (void)n_in; (void)out_size; (void)ws_size;
    const float* node_attr   = (const float*)d_in[0];
    const float* global_attr = (const float*)d_in[1];
    const float* L_values    = (const float*)d_in[2];
    const float* coeff       = (const float*)d_in[3];
    const int*   edge_attr   = (const int*)d_in[4];
    const int*   edge_index  = (const int*)d_in[5];
    const int*   L_index     = (const int*)d_in[6];
    const float* emb  = (const float*)d_in[8];
    const float* W_ne = (const float*)d_in[9];
    const float* b_ne = (const float*)d_in[10];
    const float* W_eb = (const float*)d_in[11];
    const float* b_eb = (const float*)d_in[12];
    const float* W_nb = (const float*)d_in[13];
    const float* b_nb = (const float*)d_in[14];
    const float* W_gb = (const float*)d_in[15];
    const float* b_gb = (const float*)d_in[16];
    const float* W_d1 = (const float*)d_in[17];
    const float* b_d1 = (const float*)d_in[18];
    const float* W_d2 = (const float*)d_in[19];
    const float* b_d2 = (const float*)d_in[20];
    const float* W_i1 = (const float*)d_in[21];
    const float* b_i1 = (const float*)d_in[22];
    const float* W_i2 = (const float*)d_in[23];
    const float* b_i2 = (const float*)d_in[24];

    const int* s_idx = edge_index;
    const int* r_idx = edge_index + EE;
    const int* Li = L_index;
    const int* Lj = L_index + NZ;

    char* ws = (char*)d_ws;
    size_t off = 0;
    auto alloc = [&](size_t bytes) -> void* {
        void* p = ws + off;
        off = (off + bytes + 255) & ~(size_t)255;
        return p;
    };
    unsigned short* xenc   = (unsigned short*)alloc((size_t)TT * NN * 64 * 2);
    unsigned short* hid    = (unsigned short*)alloc((size_t)TT * NN * 64 * 2);
    float*          h_x    = (float*)alloc((size_t)NN * 64 * 4);
    unsigned short* hx_bf  = (unsigned short*)alloc((size_t)NN * 64 * 2);
    unsigned short* h_e    = (unsigned short*)alloc((size_t)EE * 64 * 2);
    unsigned short* recv   = (unsigned short*)alloc((size_t)NN * 64 * 2);
    unsigned short* sentb  = (unsigned short*)alloc((size_t)NN * 64 * 2);
    float* smalls          = (float*)alloc(2048);
    unsigned short* Bpe    = (unsigned short*)alloc((size_t)2 * 24 * 512 * 2);
    unsigned short* Bpn    = (unsigned short*)alloc((size_t)2 * 16 * 512 * 2);
    unsigned short* Bpd    = (unsigned short*)alloc((size_t)4 * 4 * 512 * 2);
    unsigned short* emb_bf = (unsigned short*)alloc((size_t)100 * 64 * 2);
    int* cnt    = (int*)alloc((size_t)3 * NN * 4);
    int* rowp   = (int*)alloc((size_t)3 * (NN + 1) * 4);
    int* wp     = (int*)alloc((size_t)3 * NN * 4);
    int* col_r  = (int*)alloc((size_t)EE * 4);
    int* col_s  = (int*)alloc((size_t)EE * 4);
    int* col_Lj = (int*)alloc((size_t)NZ * 4);
    float* col_Lv = (float*)alloc((size_t)NZ * 4);

    float* g_cur = smalls;
    float* e_sum = smalls + 64;
    float* x_sum = smalls + 128;
    float* gb_eb = smalls + 192;
    float* gb_nb = smalls + 256;
    int* cnt_r = cnt, *cnt_s = cnt + NN, *cnt_L = cnt + 2 * NN;
    int* row_r = rowp, *row_s = rowp + (NN + 1), *row_L = rowp + 2 * (NN + 1);
    int* wp_r = wp, *wp_s = wp + NN, *wp_L = wp + 2 * NN;

    float* out_nodes = (float*)d_out;                    // [T,N,1]
    float* time_d = out_nodes + (size_t)TT * NN;         // [T,N,64]
    float* spat_d = time_d + (size_t)TT * NN * 64;       // [T,N,64]
    float* pred_in = spat_d + (size_t)TT * NN * 64;      // [T,N,4]

    hipMemsetAsync(h_x, 0, (size_t)NN * 64 * 4, stream);
    hipMemsetAsync(hx_bf, 0, (size_t)NN * 64 * 2, stream);
    hipMemsetAsync(h_e, 0, (size_t)EE * 64 * 2, stream);
    hipMemsetAsync(smalls, 0, 2048, stream);
    hipMemsetAsync(cnt, 0, (size_t)3 * NN * 4, stream);
    hipMemcpyAsync(g_cur, global_attr, 64 * 4, hipMemcpyDeviceToDevice, stream);

    k_count<<<(NZ + 255) / 256, 256, 0, stream>>>(r_idx, s_idx, Li, cnt_r, cnt_s, cnt_L);
    k_scan<<<3, 1024, 0, stream>>>(cnt, rowp, wp);
    k_scatter<<<(NZ + 255) / 256, 256, 0, stream>>>(r_idx, s_idx, Li, Lj, L_values,
                                                    wp_r, wp_s, wp_L,
                                                    col_r, col_s, col_Lj, col_Lv);
    k_pack<<<96, 256, 0, stream>>>(W_eb, W_nb, W_d1, W_i1, emb, Bpe, Bpn, Bpd, emb_bf);
    k_xenc<<<TT * NN / 4, 256, 0, stream>>>(node_attr, W_ne, b_ne, xenc);
    k_gbias<<<1, 64, 0, stream>>>(0, W_gb, b_gb, W_eb, b_eb, W_nb, b_nb,
                                  g_cur, e_sum, x_sum, gb_eb, gb_nb);

    for (int t = 0; t < TT; ++t) {
        const unsigned short* xenc_t = xenc + (size_t)t * NN * 64;
        k_edge<<<EE / 256, 512, 0, stream>>>(xenc_t, h_e, hx_bf, emb_bf,
                                             edge_attr + (size_t)t * EE, s_idx, r_idx,
                                             Bpe, gb_eb, e_sum);
        k_gather<<<NN * 16 / 256, 256, 0, stream>>>(h_e, row_r, col_r, row_s, col_s,
                                                    recv, sentb);
        k_node<<<NN / 32, 64, 0, stream>>>(recv, sentb, xenc_t, h_x, hx_bf,
                                           Bpn, gb_nb, x_sum,
                                           hid + (size_t)t * NN * 64,
                                           time_d + (size_t)t * NN * 64);
        k_lap<<<NN * 16 / 256, 256, 0, stream>>>(h_x, row_L, col_Lj, col_Lv, coeff,
                                                 spat_d + (size_t)t * NN * 64);
        k_gbias<<<1, 64, 0, stream>>>(1, W_gb, b_gb, W_eb, b_eb, W_nb, b_nb,
                                      g_cur, e_sum, x_sum, gb_eb, gb_nb);
    }
    k_dec<<<TT * NN / 128, 256, 0, stream>>>(hid, Bpd, b_d1, W_d2, b_d2,
                                             b_i1, W_i2, b_i2, out_nodes, pred_in);
}

// Round 6
// 755.030 us; speedup vs baseline: 3.9466x; 1.0089x over previous
//
#include <hip/hip_runtime.h>

#define TT 4
#define NN 20000
#define EE 320000
#define NZ 340000

typedef __attribute__((ext_vector_type(8))) __bf16 bf16x8;
typedef __attribute__((ext_vector_type(16))) float f32x16;

__device__ __forceinline__ unsigned short f2bf(float f) {
    unsigned int u = __float_as_uint(f);
    u = (u + 0x7FFFu + ((u >> 16) & 1u)) >> 16;
    return (unsigned short)u;
}
__device__ __forceinline__ float bf2f(unsigned short h) {
    return __uint_as_float(((unsigned int)h) << 16);
}

#define GLL16(src, dst) __builtin_amdgcn_global_load_lds( \
    (const __attribute__((address_space(1))) unsigned int*)(src), \
    (__attribute__((address_space(3))) unsigned int*)(dst), 16, 0, 0)

// ---------------- CSR build ----------------
__global__ void k_count(const int* __restrict__ r, const int* __restrict__ s,
                        const int* __restrict__ Li,
                        int* cnt_r, int* cnt_s, int* cnt_L) {
    int i = blockIdx.x * 256 + threadIdx.x;
    if (i < EE) { atomicAdd(&cnt_r[r[i]], 1); atomicAdd(&cnt_s[s[i]], 1); }
    if (i < NZ) { atomicAdd(&cnt_L[Li[i]], 1); }
}

__global__ __launch_bounds__(1024) void k_scan(int* cnt, int* rowp, int* wp) {
    int which = blockIdx.x;
    int* c = cnt + which * NN;
    int* row = rowp + which * (NN + 1);
    int* w = wp + which * NN;
    __shared__ int ssum[1024];
    int tid = threadIdx.x;
    const int CH = (NN + 1023) / 1024;
    int base = tid * CH;
    int s = 0;
    for (int i = 0; i < CH; ++i) { int idx = base + i; s += (idx < NN) ? c[idx] : 0; }
    ssum[tid] = s;
    __syncthreads();
    for (int o = 1; o < 1024; o <<= 1) {
        int v = (tid >= o) ? ssum[tid - o] : 0;
        __syncthreads();
        ssum[tid] += v;
        __syncthreads();
    }
    int run = (tid > 0) ? ssum[tid - 1] : 0;
    for (int i = 0; i < CH; ++i) {
        int idx = base + i;
        if (idx < NN) { row[idx] = run; w[idx] = run; run += c[idx]; }
    }
    if (tid == 1023) row[NN] = ssum[1023];
}

__global__ void k_scatter(const int* __restrict__ r, const int* __restrict__ s,
                          const int* __restrict__ Li, const int* __restrict__ Lj,
                          const float* __restrict__ Lv,
                          int* wp_r, int* wp_s, int* wp_L,
                          int* col_r, int* col_s, uint2* col_L8) {
    int i = blockIdx.x * 256 + threadIdx.x;
    if (i < EE) {
        col_r[atomicAdd(&wp_r[r[i]], 1)] = i;
        col_s[atomicAdd(&wp_s[s[i]], 1)] = i;
    }
    if (i < NZ) {
        int pos = atomicAdd(&wp_L[Li[i]], 1);
        uint2 v;
        v.x = (unsigned int)Lj[i];
        v.y = __float_as_uint(Lv[i]);
        col_L8[pos] = v;
    }
}

// ---------------- weight packing to bf16 MFMA fragment order ----------------
// Bpe: W_eb rows 0..128 -> [colhalf(2)][kb(8)][lane(64)][8]
// Bpu: W_eb rows 128..384 -> [grp(4)][kb(8)][lane(64)][8]
//      grp g: usr col g*32+er  <- W col (g&1)*32+(l&31), W row 128+(g>>1)*128+k
// Bpn: W_nb rows 0..256 -> [colhalf(2)][kb(16)][lane][8]
// Bpd: W_d1|W_i1 -> [sec(4)][kb(4)][lane][8]
__global__ __launch_bounds__(256) void k_pack(
    const float* __restrict__ W_eb, const float* __restrict__ W_nb,
    const float* __restrict__ W_d1, const float* __restrict__ W_i1,
    const float* __restrict__ emb, unsigned short* __restrict__ Bpe,
    unsigned short* __restrict__ Bpu, unsigned short* __restrict__ Bpn,
    unsigned short* __restrict__ Bpd, unsigned short* __restrict__ emb_bf) {
    int t = blockIdx.x * 256 + threadIdx.x;
    if (t < 2 * 8 * 512) {
        int i = t & 7, l = (t >> 3) & 63, kb = (t >> 9) & 7, ch = t >> 12;
        int colv = ch * 32 + (l & 31);
        int k = kb * 16 + (l >> 5) * 8 + i;
        Bpe[t] = f2bf(W_eb[k * 64 + colv]);
    }
    if (t < 4 * 8 * 512) {
        int i = t & 7, l = (t >> 3) & 63, kb = (t >> 9) & 7, g = t >> 12;
        int colv = (g & 1) * 32 + (l & 31);
        int k = 128 + (g >> 1) * 128 + kb * 16 + (l >> 5) * 8 + i;
        Bpu[t] = f2bf(W_eb[k * 64 + colv]);
    }
    if (t < 2 * 16 * 512) {
        int i = t & 7, l = (t >> 3) & 63, kb = (t >> 9) % 16, ch = t / (16 * 512);
        int colv = ch * 32 + (l & 31);
        int k = kb * 16 + (l >> 5) * 8 + i;
        Bpn[t] = f2bf(W_nb[k * 64 + colv]);
    }
    if (t < 4 * 4 * 512) {
        int i = t & 7, l = (t >> 3) & 63, kb = (t >> 9) & 3, sec = t >> 11;
        int colv = (sec & 1) * 32 + (l & 31);
        int k = kb * 16 + (l >> 5) * 8 + i;
        const float* W = (sec < 2) ? W_d1 : W_i1;
        Bpd[t] = f2bf(W[k * 64 + colv]);
    }
    if (t < 100 * 64) emb_bf[t] = f2bf(emb[t]);
}

// ---------------- node encoder (bf16 out) ----------------
__global__ __launch_bounds__(256) void k_xenc(const float* __restrict__ na,
                                              const float* __restrict__ W_ne,
                                              const float* __restrict__ b_ne,
                                              unsigned short* __restrict__ xenc) {
    int row = blockIdx.x * 4 + (threadIdx.x >> 6);
    int j = threadIdx.x & 63;
    float4 a = *(const float4*)&na[(size_t)row * 4];
    float v = b_ne[j] + a.x * W_ne[j] + a.y * W_ne[64 + j] + a.z * W_ne[128 + j] + a.w * W_ne[192 + j];
    xenc[(size_t)row * 64 + j] = f2bf(fmaxf(v, 0.f));
}

// ---------------- global block + g-bias fold ----------------
__global__ void k_gbias(int do_update, const float* __restrict__ W_gb,
                        const float* __restrict__ b_gb, const float* __restrict__ W_eb,
                        const float* __restrict__ b_eb, const float* __restrict__ W_nb,
                        const float* __restrict__ b_nb, float* __restrict__ g_cur,
                        float* __restrict__ e_sum, float* __restrict__ x_sum,
                        float* __restrict__ gb_eb, float* __restrict__ gb_nb) {
    int j = threadIdx.x; // 64 threads
    float a = 0.f;
    if (do_update) {
        a = b_gb[j];
        for (int k = 0; k < 64; ++k) a += (e_sum[k] / (float)EE) * W_gb[k * 64 + j];
        for (int k = 0; k < 64; ++k) a += (x_sum[k] / (float)NN) * W_gb[(64 + k) * 64 + j];
        for (int k = 0; k < 64; ++k) a += g_cur[k] * W_gb[(128 + k) * 64 + j];
    }
    __syncthreads();
    if (do_update) {
        g_cur[j] = fmaxf(a, 0.f);
        e_sum[j] = 0.f;
        x_sum[j] = 0.f;
    }
    __syncthreads();
    float a1 = b_eb[j], a2 = b_nb[j];
    for (int k = 0; k < 64; ++k) {
        float gk = g_cur[k];
        a1 = fmaf(gk, W_eb[(384 + k) * 64 + j], a1);
        a2 = fmaf(gk, W_nb[(256 + k) * 64 + j], a2);
    }
    gb_eb[j] = a1;
    gb_nb[j] = a2;
}

// ---------------- usr: per-node [x|h_x] @ W_eb[128:384] -> (u_s,u_r) f32 paired ----
// usr layout: float2[NN][64]: [n][er] = (u_s[er], u_s[er+32]); [n][32+er] = (u_r...)
__global__ __launch_bounds__(64) void k_usr(
    const unsigned short* __restrict__ xenc_t, const unsigned short* __restrict__ hx_bf,
    const unsigned short* __restrict__ Bpu, float2* __restrict__ usr) {
    const int ln = threadIdx.x;
    const int er = ln & 31, hi = ln >> 5;
    const int n0 = blockIdx.x * 32;
    const int n = n0 + er;

    f32x16 a0, a1, a2, a3;
    #pragma unroll
    for (int i = 0; i < 16; ++i) { a0[i] = 0.f; a1[i] = 0.f; a2[i] = 0.f; a3[i] = 0.f; }

    const unsigned short* sx = xenc_t + (size_t)64 * n + hi * 8;
    const unsigned short* sh = hx_bf + (size_t)64 * n + hi * 8;
    #pragma unroll
    for (int c = 0; c < 2; ++c) {
        const unsigned short* src = c ? sh : sx;
        #pragma unroll
        for (int kb = 0; kb < 4; ++kb) {
            bf16x8 a = *(const bf16x8*)(src + kb * 16);
            int kg = c * 4 + kb;
            bf16x8 b0 = *(const bf16x8*)&Bpu[(size_t)((0 * 8 + kg) * 64 + ln) * 8];
            bf16x8 b1 = *(const bf16x8*)&Bpu[(size_t)((1 * 8 + kg) * 64 + ln) * 8];
            bf16x8 b2 = *(const bf16x8*)&Bpu[(size_t)((2 * 8 + kg) * 64 + ln) * 8];
            bf16x8 b3 = *(const bf16x8*)&Bpu[(size_t)((3 * 8 + kg) * 64 + ln) * 8];
            a0 = __builtin_amdgcn_mfma_f32_32x32x16_bf16(a, b0, a0, 0, 0, 0);
            a1 = __builtin_amdgcn_mfma_f32_32x32x16_bf16(a, b1, a1, 0, 0, 0);
            a2 = __builtin_amdgcn_mfma_f32_32x32x16_bf16(a, b2, a2, 0, 0, 0);
            a3 = __builtin_amdgcn_mfma_f32_32x32x16_bf16(a, b3, a3, 0, 0, 0);
        }
    }
    #pragma unroll
    for (int r = 0; r < 16; ++r) {
        int row = (r & 3) + 8 * (r >> 2) + 4 * hi;
        size_t o = (size_t)(n0 + row) * 64;
        float2 vs = {a0[r], a1[r]};
        float2 vr = {a2[r], a3[r]};
        usr[o + er] = vs;
        usr[o + 32 + er] = vr;
    }
}

// ---------------- edge block: K=128 (emb,h_e) MFMA + usr epilogue ----------------
__global__ __launch_bounds__(512) void k_edge(
    unsigned short* __restrict__ h_e, const unsigned short* __restrict__ emb_bf,
    const float2* __restrict__ usr, const int* __restrict__ eattr_t,
    const int* __restrict__ sidx, const int* __restrict__ ridx,
    const unsigned short* __restrict__ Bp, const float* __restrict__ gbias,
    float* __restrict__ e_sum) {
    __shared__ unsigned short sBe[8192];  // 16 KB packed W_eb rows 0..128
    __shared__ float sRed[8][64];
    const int tid = threadIdx.x;
    const int w = tid >> 6, ln = tid & 63;
    const int er = ln & 31, hi = ln >> 5;
    const int ebase = blockIdx.x * 256 + w * 32;
    const int e = ebase + er;

    // per-lane sender/receiver of edge (ebase + er); broadcast later via shfl
    const int siv = sidx[ebase + er];
    const int riv = ridx[ebase + er];
    const int ai = eattr_t[e];

    // stage B: 16 KB = 2 x (512 threads x 16 B)
    #pragma unroll
    for (int i = 0; i < 2; ++i) {
        int off = i * 4096 + w * 512;
        GLL16(Bp + off + ln * 8, sBe + off);
    }

    // A fragments: emb chunk + h_e chunk (both cheap/sequential)
    const unsigned short* s0 = emb_bf + (size_t)64 * ai + hi * 8;
    const unsigned short* s1 = h_e + (size_t)64 * e + hi * 8;
    bf16x8 a0 = *(const bf16x8*)(s0);
    bf16x8 a1 = *(const bf16x8*)(s0 + 16);
    bf16x8 a2 = *(const bf16x8*)(s0 + 32);
    bf16x8 a3 = *(const bf16x8*)(s0 + 48);
    bf16x8 a4 = *(const bf16x8*)(s1);
    bf16x8 a5 = *(const bf16x8*)(s1 + 16);
    bf16x8 a6 = *(const bf16x8*)(s1 + 32);
    bf16x8 a7 = *(const bf16x8*)(s1 + 48);

    f32x16 acc0, acc1;
    #pragma unroll
    for (int i = 0; i < 16; ++i) { acc0[i] = 0.f; acc1[i] = 0.f; }

    __syncthreads();

    #define EMM(AF, KG)                                                              \
        {                                                                            \
            bf16x8 b0 = *(const bf16x8*)&sBe[(((KG)) * 64 + ln) * 8];                \
            bf16x8 b1 = *(const bf16x8*)&sBe[((8 + (KG)) * 64 + ln) * 8];            \
            acc0 = __builtin_amdgcn_mfma_f32_32x32x16_bf16(AF, b0, acc0, 0, 0, 0);   \
            acc1 = __builtin_amdgcn_mfma_f32_32x32x16_bf16(AF, b1, acc1, 0, 0, 0);   \
        }
    EMM(a0, 0) EMM(a1, 1) EMM(a2, 2) EMM(a3, 3)
    EMM(a4, 4) EMM(a5, 5) EMM(a6, 6) EMM(a7, 7)
    #undef EMM

    const float gb0 = gbias[er], gb1 = gbias[er + 32];
    float cs0 = 0.f, cs1 = 0.f;
    #pragma unroll
    for (int r = 0; r < 16; ++r) {
        int row = (r & 3) + 8 * (r >> 2) + 4 * hi;
        int si_row = __shfl(siv, row, 64);
        int ri_row = __shfl(riv, row, 64);
        float2 us = usr[(size_t)si_row * 64 + er];
        float2 ur = usr[(size_t)ri_row * 64 + 32 + er];
        size_t o = (size_t)(ebase + row) * 64;
        float v0 = fmaxf(acc0[r] + us.x + ur.x + gb0, 0.f);
        float v1 = fmaxf(acc1[r] + us.y + ur.y + gb1, 0.f);
        cs0 += v0; cs1 += v1;
        h_e[o + er] = f2bf(v0);
        h_e[o + er + 32] = f2bf(v1);
    }
    cs0 += __shfl_xor(cs0, 32, 64);
    cs1 += __shfl_xor(cs1, 32, 64);
    if (hi == 0) { sRed[w][er] = cs0; sRed[w][er + 32] = cs1; }
    __syncthreads();
    if (w == 0) {
        float t = 0.f;
        #pragma unroll
        for (int q = 0; q < 8; ++q) t += sRed[q][ln];
        atomicAdd(&e_sum[ln], t);
    }
}

// ---------------- recv/sent gather: 32 threads per node (16 recv + 16 sent) ----
__global__ __launch_bounds__(256) void k_gather(
    const unsigned short* __restrict__ h_e, const int* __restrict__ row_r,
    const int* __restrict__ col_r, const int* __restrict__ row_s,
    const int* __restrict__ col_s, unsigned short* __restrict__ recv,
    unsigned short* __restrict__ sentb) {
    int t = blockIdx.x * 256 + threadIdx.x;
    int sub = t & 31, n = t >> 5;
    int g = sub & 15, which = sub >> 4;
    const int* rowp = which ? row_s : row_r;
    const int* colp = which ? col_s : col_r;
    unsigned short* outp = which ? sentb : recv;

    float a0 = 0.f, a1 = 0.f, a2 = 0.f, a3 = 0.f;
    int b0 = rowp[n], b1 = rowp[n + 1];
    for (int p = b0; p < b1; ++p) {
        uint2 v = *(const uint2*)&h_e[(size_t)64 * colp[p] + g * 4];
        a0 += bf2f((unsigned short)(v.x & 0xFFFF));
        a1 += bf2f((unsigned short)(v.x >> 16));
        a2 += bf2f((unsigned short)(v.y & 0xFFFF));
        a3 += bf2f((unsigned short)(v.y >> 16));
    }
    uint2 packed;
    packed.x = (unsigned int)f2bf(a0) | ((unsigned int)f2bf(a1) << 16);
    packed.y = (unsigned int)f2bf(a2) | ((unsigned int)f2bf(a3) << 16);
    *(uint2*)&outp[(size_t)64 * n + g * 4] = packed;
}

// ---------------- node block: barrier-free MFMA GEMM, 1 wave/block ----------------
#define NODE_CHUNK(CIDX, BASE)                                                          \
    {                                                                                   \
        const unsigned short* src = (BASE) + hi * 8;                                    \
        _Pragma("unroll") for (int kb = 0; kb < 4; ++kb) {                              \
            bf16x8 a = *(const bf16x8*)(src + kb * 16);                                 \
            bf16x8 b0 = *(const bf16x8*)&Bp[(size_t)(((CIDX)*4 + kb) * 64 + ln) * 8];   \
            bf16x8 b1 = *(const bf16x8*)&Bp[(size_t)((16 + (CIDX)*4 + kb) * 64 + ln) * 8]; \
            acc0 = __builtin_amdgcn_mfma_f32_32x32x16_bf16(a, b0, acc0, 0, 0, 0);       \
            acc1 = __builtin_amdgcn_mfma_f32_32x32x16_bf16(a, b1, acc1, 0, 0, 0);       \
        }                                                                               \
    }

__global__ __launch_bounds__(64) void k_node(
    const unsigned short* __restrict__ recv, const unsigned short* __restrict__ sentb,
    const unsigned short* __restrict__ xenc_t, float* __restrict__ h_x,
    unsigned short* __restrict__ hx_bf, const unsigned short* __restrict__ Bp,
    const float* __restrict__ gbias, float* __restrict__ x_sum,
    unsigned short* __restrict__ hid_t, float* __restrict__ timed_t) {
    const int ln = threadIdx.x;
    const int er = ln & 31, hi = ln >> 5;
    const int n0 = blockIdx.x * 32;
    const int n = n0 + er;

    f32x16 acc0, acc1;
    #pragma unroll
    for (int i = 0; i < 16; ++i) { acc0[i] = 0.f; acc1[i] = 0.f; }

    NODE_CHUNK(0, recv + (size_t)64 * n)
    NODE_CHUNK(1, sentb + (size_t)64 * n)
    NODE_CHUNK(2, xenc_t + (size_t)64 * n)
    NODE_CHUNK(3, hx_bf + (size_t)64 * n)

    const float gb0 = gbias[er], gb1 = gbias[er + 32];
    float cs0 = 0.f, cs1 = 0.f;
    #pragma unroll
    for (int r = 0; r < 16; ++r) {
        int row = (r & 3) + 8 * (r >> 2) + 4 * hi;
        size_t o = (size_t)(n0 + row) * 64;
        float x0 = fmaxf(acc0[r] + gb0, 0.f);
        float x1 = fmaxf(acc1[r] + gb1, 0.f);
        cs0 += x0; cs1 += x1;
        float hx0 = h_x[o + er] + x0;
        float hx1 = h_x[o + er + 32] + x1;
        unsigned short hb0 = f2bf(hx0), hb1 = f2bf(hx1);
        h_x[o + er] = hx0;        h_x[o + er + 32] = hx1;
        hx_bf[o + er] = hb0;      hx_bf[o + er + 32] = hb1;
        hid_t[o + er] = hb0;      hid_t[o + er + 32] = hb1;
        timed_t[o + er] = x0;     timed_t[o + er + 32] = x1;
    }
    cs0 += __shfl_xor(cs0, 32, 64);
    cs1 += __shfl_xor(cs1, 32, 64);
    if (hi == 0) {
        atomicAdd(&x_sum[er], cs0);
        atomicAdd(&x_sum[er + 32], cs1);
    }
}

// ---------------- Laplacian: 32 threads per node (split nnz halves) ----------------
__global__ __launch_bounds__(256) void k_lap(
    const float* __restrict__ h_x, const int* __restrict__ row_L,
    const uint2* __restrict__ col_L8, const float* __restrict__ coeff,
    float* __restrict__ spat_t) {
    int t = blockIdx.x * 256 + threadIdx.x;
    int sub = t & 31, n = t >> 5;
    int g = sub & 15, half = sub >> 4;
    float a0 = 0.f, a1 = 0.f, a2 = 0.f, a3 = 0.f;
    int b0 = row_L[n], b1 = row_L[n + 1];
    int mid = b0 + ((b1 - b0) >> 1);
    int p0 = half ? mid : b0;
    int p1 = half ? b1 : mid;
    for (int p = p0; p < p1; ++p) {
        uint2 e = col_L8[p];
        float lv = __uint_as_float(e.y);
        float4 v = *(const float4*)&h_x[(size_t)64 * e.x + g * 4];
        a0 = fmaf(lv, v.x, a0);
        a1 = fmaf(lv, v.y, a1);
        a2 = fmaf(lv, v.z, a2);
        a3 = fmaf(lv, v.w, a3);
    }
    a0 += __shfl_xor(a0, 16, 64);
    a1 += __shfl_xor(a1, 16, 64);
    a2 += __shfl_xor(a2, 16, 64);
    a3 += __shfl_xor(a3, 16, 64);
    if (half == 0) {
        float c = coeff[0];
        float4 outv = {c * a0, c * a1, c * a2, c * a3};
        *(float4*)&spat_t[(size_t)64 * n + g * 4] = outv;
    }
}

// ---------------- decoders: MFMA layer1, LDS transpose, scalar layer2 ----------------
__global__ __launch_bounds__(256) void k_dec(
    const unsigned short* __restrict__ hid_bf, const unsigned short* __restrict__ Bpd,
    const float* __restrict__ b_d1, const float* __restrict__ W_d2,
    const float* __restrict__ b_d2, const float* __restrict__ b_i1,
    const float* __restrict__ W_i2, const float* __restrict__ b_i2,
    float* __restrict__ out_nodes, float* __restrict__ pred_in) {
    __shared__ unsigned short sDec[4][32 * 138];
    const int tid = threadIdx.x;
    const int w = tid >> 6, ln = tid & 63;
    const int er = ln & 31, hi = ln >> 5;
    const int row0 = (blockIdx.x * 4 + w) * 32;

    f32x16 ad0, ad1, ai0, ai1;
    #pragma unroll
    for (int i = 0; i < 16; ++i) { ad0[i] = 0.f; ad1[i] = 0.f; ai0[i] = 0.f; ai1[i] = 0.f; }

    const unsigned short* src = hid_bf + (size_t)(row0 + er) * 64 + hi * 8;
    #pragma unroll
    for (int kb = 0; kb < 4; ++kb) {
        bf16x8 a = *(const bf16x8*)(src + kb * 16);
        bf16x8 bd0 = *(const bf16x8*)&Bpd[((0 * 4 + kb) * 64 + ln) * 8];
        bf16x8 bd1 = *(const bf16x8*)&Bpd[((4 + kb) * 64 + ln) * 8];
        bf16x8 bi0 = *(const bf16x8*)&Bpd[((8 + kb) * 64 + ln) * 8];
        bf16x8 bi1 = *(const bf16x8*)&Bpd[((12 + kb) * 64 + ln) * 8];
        ad0 = __builtin_amdgcn_mfma_f32_32x32x16_bf16(a, bd0, ad0, 0, 0, 0);
        ad1 = __builtin_amdgcn_mfma_f32_32x32x16_bf16(a, bd1, ad1, 0, 0, 0);
        ai0 = __builtin_amdgcn_mfma_f32_32x32x16_bf16(a, bi0, ai0, 0, 0, 0);
        ai1 = __builtin_amdgcn_mfma_f32_32x32x16_bf16(a, bi1, ai1, 0, 0, 0);
    }

    const float bd0v = b_d1[er], bd1v = b_d1[er + 32];
    const float bi0v = b_i1[er], bi1v = b_i1[er + 32];
    unsigned short* sw = &sDec[w][0];
    #pragma unroll
    for (int r = 0; r < 16; ++r) {
        int row = (r & 3) + 8 * (r >> 2) + 4 * hi;
        sw[row * 138 + er]       = f2bf(fmaxf(ad0[r] + bd0v, 0.f));
        sw[row * 138 + er + 32]  = f2bf(fmaxf(ad1[r] + bd1v, 0.f));
        sw[row * 138 + er + 64]  = f2bf(fmaxf(ai0[r] + bi0v, 0.f));
        sw[row * 138 + er + 96]  = f2bf(fmaxf(ai1[r] + bi1v, 0.f));
    }
    __syncthreads();

    const int g_row = row0 + er;
    if (hi == 0) {
        float s = 0.f;
        for (int k = 0; k < 32; ++k) {
            unsigned int u = *(const unsigned int*)&sw[er * 138 + 2 * k];
            s = fmaf(bf2f((unsigned short)(u & 0xFFFF)), W_d2[2 * k], s);
            s = fmaf(bf2f((unsigned short)(u >> 16)), W_d2[2 * k + 1], s);
        }
        out_nodes[g_row] = s + b_d2[0];
    } else {
        float s0 = 0.f, s1 = 0.f, s2 = 0.f, s3 = 0.f;
        for (int k = 0; k < 32; ++k) {
            unsigned int u = *(const unsigned int*)&sw[er * 138 + 64 + 2 * k];
            float vlo = bf2f((unsigned short)(u & 0xFFFF));
            float vhi = bf2f((unsigned short)(u >> 16));
            float4 w0 = *(const float4*)&W_i2[(2 * k) * 4];
            float4 w1 = *(const float4*)&W_i2[(2 * k + 1) * 4];
            s0 = fmaf(vlo, w0.x, fmaf(vhi, w1.x, s0));
            s1 = fmaf(vlo, w0.y, fmaf(vhi, w1.y, s1));
            s2 = fmaf(vlo, w0.z, fmaf(vhi, w1.z, s2));
            s3 = fmaf(vlo, w0.w, fmaf(vhi, w1.w, s3));
        }
        float4 pv = {s0 + b_i2[0], s1 + b_i2[1], s2 + b_i2[2], s3 + b_i2[3]};
        *(float4*)&pred_in[(size_t)4 * g_row] = pv;
    }
}

extern "C" void kernel_launch(void* const* d_in, const int* in_sizes, int n_in,
                              void* d_out, int out_size, void* d_ws, size_t ws_size,
                              hipStream_t stream) {
    (void)in_sizes; (void)n_in; (void)out_size; (void)ws_size;
    const float* node_attr   = (const float*)d_in[0];
    const float* global_attr = (const float*)d_in[1];
    const float* L_values    = (const float*)d_in[2];
    const float* coeff       = (const float*)d_in[3];
    const int*   edge_attr   = (const int*)d_in[4];
    const int*   edge_index  = (const int*)d_in[5];
    const int*   L_index     = (const int*)d_in[6];
    const float* emb  = (const float*)d_in[8];
    const float* W_ne = (const float*)d_in[9];
    const float* b_ne = (const float*)d_in[10];
    const float* W_eb = (const float*)d_in[11];
    const float* b_eb = (const float*)d_in[12];
    const float* W_nb = (const float*)d_in[13];
    const float* b_nb = (const float*)d_in[14];
    const float* W_gb = (const float*)d_in[15];
    const float* b_gb = (const float*)d_in[16];
    const float* W_d1 = (const float*)d_in[17];
    const float* b_d1 = (const float*)d_in[18];
    const float* W_d2 = (const float*)d_in[19];
    const float* b_d2 = (const float*)d_in[20];
    const float* W_i1 = (const float*)d_in[21];
    const float* b_i1 = (const float*)d_in[22];
    const float* W_i2 = (const float*)d_in[23];
    const float* b_i2 = (const float*)d_in[24];

    const int* s_idx = edge_index;
    const int* r_idx = edge_index + EE;
    const int* Li = L_index;
    const int* Lj = L_index + NZ;

    char* ws = (char*)d_ws;
    size_t off = 0;
    auto alloc = [&](size_t bytes) -> void* {
        void* p = ws + off;
        off = (off + bytes + 255) & ~(size_t)255;
        return p;
    };
    unsigned short* xenc   = (unsigned short*)alloc((size_t)TT * NN * 64 * 2);
    unsigned short* hid    = (unsigned short*)alloc((size_t)TT * NN * 64 * 2);
    float*          h_x    = (float*)alloc((size_t)NN * 64 * 4);
    unsigned short* hx_bf  = (unsigned short*)alloc((size_t)NN * 64 * 2);
    unsigned short* h_e    = (unsigned short*)alloc((size_t)EE * 64 * 2);
    unsigned short* recv   = (unsigned short*)alloc((size_t)NN * 64 * 2);
    unsigned short* sentb  = (unsigned short*)alloc((size_t)NN * 64 * 2);
    float2*         usr    = (float2*)alloc((size_t)NN * 64 * 8);
    float* smalls          = (float*)alloc(2048);
    unsigned short* Bpe    = (unsigned short*)alloc((size_t)2 * 8 * 512 * 2);
    unsigned short* Bpu    = (unsigned short*)alloc((size_t)4 * 8 * 512 * 2);
    unsigned short* Bpn    = (unsigned short*)alloc((size_t)2 * 16 * 512 * 2);
    unsigned short* Bpd    = (unsigned short*)alloc((size_t)4 * 4 * 512 * 2);
    unsigned short* emb_bf = (unsigned short*)alloc((size_t)100 * 64 * 2);
    int* cnt    = (int*)alloc((size_t)3 * NN * 4);
    int* rowp   = (int*)alloc((size_t)3 * (NN + 1) * 4);
    int* wp     = (int*)alloc((size_t)3 * NN * 4);
    int* col_r  = (int*)alloc((size_t)EE * 4);
    int* col_s  = (int*)alloc((size_t)EE * 4);
    uint2* col_L8 = (uint2*)alloc((size_t)NZ * 8);

    float* g_cur = smalls;
    float* e_sum = smalls + 64;
    float* x_sum = smalls + 128;
    float* gb_eb = smalls + 192;
    float* gb_nb = smalls + 256;
    int* cnt_r = cnt, *cnt_s = cnt + NN, *cnt_L = cnt + 2 * NN;
    int* row_r = rowp, *row_s = rowp + (NN + 1), *row_L = rowp + 2 * (NN + 1);
    int* wp_r = wp, *wp_s = wp + NN, *wp_L = wp + 2 * NN;

    float* out_nodes = (float*)d_out;                    // [T,N,1]
    float* time_d = out_nodes + (size_t)TT * NN;         // [T,N,64]
    float* spat_d = time_d + (size_t)TT * NN * 64;       // [T,N,64]
    float* pred_in = spat_d + (size_t)TT * NN * 64;      // [T,N,4]

    hipMemsetAsync(h_x, 0, (size_t)NN * 64 * 4, stream);
    hipMemsetAsync(hx_bf, 0, (size_t)NN * 64 * 2, stream);
    hipMemsetAsync(h_e, 0, (size_t)EE * 64 * 2, stream);
    hipMemsetAsync(smalls, 0, 2048, stream);
    hipMemsetAsync(cnt, 0, (size_t)3 * NN * 4, stream);
    hipMemcpyAsync(g_cur, global_attr, 64 * 4, hipMemcpyDeviceToDevice, stream);

    k_count<<<(NZ + 255) / 256, 256, 0, stream>>>(r_idx, s_idx, Li, cnt_r, cnt_s, cnt_L);
    k_scan<<<3, 1024, 0, stream>>>(cnt, rowp, wp);
    k_scatter<<<(NZ + 255) / 256, 256, 0, stream>>>(r_idx, s_idx, Li, Lj, L_values,
                                                    wp_r, wp_s, wp_L,
                                                    col_r, col_s, col_L8);
    k_pack<<<96, 256, 0, stream>>>(W_eb, W_nb, W_d1, W_i1, emb,
                                   Bpe, Bpu, Bpn, Bpd, emb_bf);
    k_xenc<<<TT * NN / 4, 256, 0, stream>>>(node_attr, W_ne, b_ne, xenc);
    k_gbias<<<1, 64, 0, stream>>>(0, W_gb, b_gb, W_eb, b_eb, W_nb, b_nb,
                                  g_cur, e_sum, x_sum, gb_eb, gb_nb);

    for (int t = 0; t < TT; ++t) {
        const unsigned short* xenc_t = xenc + (size_t)t * NN * 64;
        k_usr<<<NN / 32, 64, 0, stream>>>(xenc_t, hx_bf, Bpu, usr);
        k_edge<<<EE / 256, 512, 0, stream>>>(h_e, emb_bf, usr,
                                             edge_attr + (size_t)t * EE, s_idx, r_idx,
                                             Bpe, gb_eb, e_sum);
        k_gather<<<NN * 32 / 256, 256, 0, stream>>>(h_e, row_r, col_r, row_s, col_s,
                                                    recv, sentb);
        k_node<<<NN / 32, 64, 0, stream>>>(recv, sentb, xenc_t, h_x, hx_bf,
                                           Bpn, gb_nb, x_sum,
                                           hid + (size_t)t * NN * 64,
                                           time_d + (size_t)t * NN * 64);
        k_lap<<<NN * 32 / 256, 256, 0, stream>>>(h_x, row_L, col_L8, coeff,
                                                 spat_d + (size_t)t * NN * 64);
        k_gbias<<<1, 64, 0, stream>>>(1, W_gb, b_gb, W_eb, b_eb, W_nb, b_nb,
                                      g_cur, e_sum, x_sum, gb_eb, gb_nb);
    }
    k_dec<<<TT * NN / 128, 256, 0, stream>>>(hid, Bpd, b_d1, W_d2, b_d2,
                                             b_i1, W_i2, b_i2, out_nodes, pred_in);
}

// Round 7
// 695.662 us; speedup vs baseline: 4.2835x; 1.0853x over previous
//
#include <hip/hip_runtime.h>

#define TT 4
#define NN 20000
#define EE 320000
#define NZ 340000

typedef __attribute__((ext_vector_type(8))) __bf16 bf16x8;
typedef __attribute__((ext_vector_type(16))) float f32x16;

__device__ __forceinline__ unsigned short f2bf(float f) {
    unsigned int u = __float_as_uint(f);
    u = (u + 0x7FFFu + ((u >> 16) & 1u)) >> 16;
    return (unsigned short)u;
}
__device__ __forceinline__ float bf2f(unsigned short h) {
    return __uint_as_float(((unsigned int)h) << 16);
}

#define GLL16(src, dst) __builtin_amdgcn_global_load_lds( \
    (const __attribute__((address_space(1))) unsigned int*)(src), \
    (__attribute__((address_space(3))) unsigned int*)(dst), 16, 0, 0)

// ---------------- CSR build ----------------
__global__ void k_count(const int* __restrict__ r, const int* __restrict__ s,
                        const int* __restrict__ Li,
                        int* cnt_r, int* cnt_s, int* cnt_L) {
    int i = blockIdx.x * 256 + threadIdx.x;
    if (i < EE) { atomicAdd(&cnt_r[r[i]], 1); atomicAdd(&cnt_s[s[i]], 1); }
    if (i < NZ) { atomicAdd(&cnt_L[Li[i]], 1); }
}

__global__ __launch_bounds__(1024) void k_scan(int* cnt, int* rowp, int* wp) {
    int which = blockIdx.x;
    int* c = cnt + which * NN;
    int* row = rowp + which * (NN + 1);
    int* w = wp + which * NN;
    __shared__ int ssum[1024];
    int tid = threadIdx.x;
    const int CH = (NN + 1023) / 1024;
    int base = tid * CH;
    int s = 0;
    for (int i = 0; i < CH; ++i) { int idx = base + i; s += (idx < NN) ? c[idx] : 0; }
    ssum[tid] = s;
    __syncthreads();
    for (int o = 1; o < 1024; o <<= 1) {
        int v = (tid >= o) ? ssum[tid - o] : 0;
        __syncthreads();
        ssum[tid] += v;
        __syncthreads();
    }
    int run = (tid > 0) ? ssum[tid - 1] : 0;
    for (int i = 0; i < CH; ++i) {
        int idx = base + i;
        if (idx < NN) { row[idx] = run; w[idx] = run; run += c[idx]; }
    }
    if (tid == 1023) row[NN] = ssum[1023];
}

__global__ void k_scatter(const int* __restrict__ r, const int* __restrict__ s,
                          const int* __restrict__ Li, const int* __restrict__ Lj,
                          const float* __restrict__ Lv,
                          int* wp_r, int* wp_s, int* wp_L,
                          int* col_r, int* col_s, uint2* col_L8) {
    int i = blockIdx.x * 256 + threadIdx.x;
    if (i < EE) {
        col_r[atomicAdd(&wp_r[r[i]], 1)] = i;
        col_s[atomicAdd(&wp_s[s[i]], 1)] = i;
    }
    if (i < NZ) {
        int pos = atomicAdd(&wp_L[Li[i]], 1);
        uint2 v;
        v.x = (unsigned int)Lj[i];
        v.y = __float_as_uint(Lv[i]);
        col_L8[pos] = v;
    }
}

// ---------------- weight packing to bf16 MFMA fragment order ----------------
__global__ __launch_bounds__(256) void k_pack(
    const float* __restrict__ W_eb, const float* __restrict__ W_nb,
    const float* __restrict__ W_d1, const float* __restrict__ W_i1,
    const float* __restrict__ emb, unsigned short* __restrict__ Bpe,
    unsigned short* __restrict__ Bpu, unsigned short* __restrict__ Bpn,
    unsigned short* __restrict__ Bpd, unsigned short* __restrict__ emb_bf) {
    int t = blockIdx.x * 256 + threadIdx.x;
    if (t < 2 * 8 * 512) {
        int i = t & 7, l = (t >> 3) & 63, kb = (t >> 9) & 7, ch = t >> 12;
        int colv = ch * 32 + (l & 31);
        int k = kb * 16 + (l >> 5) * 8 + i;
        Bpe[t] = f2bf(W_eb[k * 64 + colv]);
    }
    if (t < 4 * 8 * 512) {
        int i = t & 7, l = (t >> 3) & 63, kb = (t >> 9) & 7, g = t >> 12;
        int colv = (g & 1) * 32 + (l & 31);
        int k = 128 + (g >> 1) * 128 + kb * 16 + (l >> 5) * 8 + i;
        Bpu[t] = f2bf(W_eb[k * 64 + colv]);
    }
    if (t < 2 * 16 * 512) {
        int i = t & 7, l = (t >> 3) & 63, kb = (t >> 9) % 16, ch = t / (16 * 512);
        int colv = ch * 32 + (l & 31);
        int k = kb * 16 + (l >> 5) * 8 + i;
        Bpn[t] = f2bf(W_nb[k * 64 + colv]);
    }
    if (t < 4 * 4 * 512) {
        int i = t & 7, l = (t >> 3) & 63, kb = (t >> 9) & 3, sec = t >> 11;
        int colv = (sec & 1) * 32 + (l & 31);
        int k = kb * 16 + (l >> 5) * 8 + i;
        const float* W = (sec < 2) ? W_d1 : W_i1;
        Bpd[t] = f2bf(W[k * 64 + colv]);
    }
    if (t < 100 * 64) emb_bf[t] = f2bf(emb[t]);
}

// ---------------- node encoder (bf16 out) ----------------
__global__ __launch_bounds__(256) void k_xenc(const float* __restrict__ na,
                                              const float* __restrict__ W_ne,
                                              const float* __restrict__ b_ne,
                                              unsigned short* __restrict__ xenc) {
    int row = blockIdx.x * 4 + (threadIdx.x >> 6);
    int j = threadIdx.x & 63;
    float4 a = *(const float4*)&na[(size_t)row * 4];
    float v = b_ne[j] + a.x * W_ne[j] + a.y * W_ne[64 + j] + a.z * W_ne[128 + j] + a.w * W_ne[192 + j];
    xenc[(size_t)row * 64 + j] = f2bf(fmaxf(v, 0.f));
}

// ---------------- usr (+ fused global-block bias update in block 0) ----------------
// usr layout: float2[NN][64]: [n][er] = (u_s[er], u_s[er+32]); [n][32+er] = (u_r...)
__global__ __launch_bounds__(64) void k_usr(
    int do_update,
    const unsigned short* __restrict__ xenc_t, const unsigned short* __restrict__ hx_bf,
    const unsigned short* __restrict__ Bpu, float2* __restrict__ usr,
    const float* __restrict__ W_gb, const float* __restrict__ b_gb,
    const float* __restrict__ W_eb, const float* __restrict__ b_eb,
    const float* __restrict__ W_nb, const float* __restrict__ b_nb,
    float* __restrict__ g_cur, float* __restrict__ e_sum, float* __restrict__ x_sum,
    float* __restrict__ gb_eb, float* __restrict__ gb_nb) {
    const int ln = threadIdx.x;
    const int er = ln & 31, hi = ln >> 5;

    if (blockIdx.x == 0) {
        // global-block update + g-bias fold, one wave
        int j = ln;
        float gv = g_cur[j];
        if (do_update) {
            float a = b_gb[j];
            for (int k = 0; k < 64; ++k) a += (e_sum[k] / (float)EE) * W_gb[k * 64 + j];
            for (int k = 0; k < 64; ++k) a += (x_sum[k] / (float)NN) * W_gb[(64 + k) * 64 + j];
            for (int k = 0; k < 64; ++k) a += g_cur[k] * W_gb[(128 + k) * 64 + j];
            gv = fmaxf(a, 0.f);
            g_cur[j] = gv;
            e_sum[j] = 0.f;
            x_sum[j] = 0.f;
        }
        float a1 = b_eb[j], a2 = b_nb[j];
        for (int k = 0; k < 64; ++k) {
            float gk = __shfl(gv, k, 64);
            a1 = fmaf(gk, W_eb[(384 + k) * 64 + j], a1);
            a2 = fmaf(gk, W_nb[(256 + k) * 64 + j], a2);
        }
        gb_eb[j] = a1;
        gb_nb[j] = a2;
    }

    const int n0 = blockIdx.x * 32;
    const int n = n0 + er;

    f32x16 a0, a1, a2, a3;
    #pragma unroll
    for (int i = 0; i < 16; ++i) { a0[i] = 0.f; a1[i] = 0.f; a2[i] = 0.f; a3[i] = 0.f; }

    const unsigned short* sx = xenc_t + (size_t)64 * n + hi * 8;
    const unsigned short* sh = hx_bf + (size_t)64 * n + hi * 8;
    #pragma unroll
    for (int c = 0; c < 2; ++c) {
        const unsigned short* src = c ? sh : sx;
        #pragma unroll
        for (int kb = 0; kb < 4; ++kb) {
            bf16x8 a = *(const bf16x8*)(src + kb * 16);
            int kg = c * 4 + kb;
            bf16x8 b0 = *(const bf16x8*)&Bpu[(size_t)((0 * 8 + kg) * 64 + ln) * 8];
            bf16x8 b1 = *(const bf16x8*)&Bpu[(size_t)((1 * 8 + kg) * 64 + ln) * 8];
            bf16x8 b2 = *(const bf16x8*)&Bpu[(size_t)((2 * 8 + kg) * 64 + ln) * 8];
            bf16x8 b3 = *(const bf16x8*)&Bpu[(size_t)((3 * 8 + kg) * 64 + ln) * 8];
            a0 = __builtin_amdgcn_mfma_f32_32x32x16_bf16(a, b0, a0, 0, 0, 0);
            a1 = __builtin_amdgcn_mfma_f32_32x32x16_bf16(a, b1, a1, 0, 0, 0);
            a2 = __builtin_amdgcn_mfma_f32_32x32x16_bf16(a, b2, a2, 0, 0, 0);
            a3 = __builtin_amdgcn_mfma_f32_32x32x16_bf16(a, b3, a3, 0, 0, 0);
        }
    }
    #pragma unroll
    for (int r = 0; r < 16; ++r) {
        int row = (r & 3) + 8 * (r >> 2) + 4 * hi;
        size_t o = (size_t)(n0 + row) * 64;
        float2 vs = {a0[r], a1[r]};
        float2 vr = {a2[r], a3[r]};
        usr[o + er] = vs;
        usr[o + 32 + er] = vr;
    }
}

// ---------------- edge block: K=128 (emb,h_e) MFMA + usr epilogue ----------------
__global__ __launch_bounds__(512) void k_edge(
    int first, unsigned short* __restrict__ h_e,
    const unsigned short* __restrict__ emb_bf,
    const float2* __restrict__ usr, const int* __restrict__ eattr_t,
    const int* __restrict__ sidx, const int* __restrict__ ridx,
    const unsigned short* __restrict__ Bp, const float* __restrict__ gbias,
    float* __restrict__ e_sum) {
    __shared__ unsigned short sBe[8192];  // 16 KB packed W_eb rows 0..128
    __shared__ float sRed[8][64];
    const int tid = threadIdx.x;
    const int w = tid >> 6, ln = tid & 63;
    const int er = ln & 31, hi = ln >> 5;
    const int ebase = blockIdx.x * 256 + w * 32;
    const int e = ebase + er;

    const int siv = sidx[ebase + er];
    const int riv = ridx[ebase + er];
    const int ai = eattr_t[e];

    #pragma unroll
    for (int i = 0; i < 2; ++i) {
        int off = i * 4096 + w * 512;
        GLL16(Bp + off + ln * 8, sBe + off);
    }

    const unsigned short* s0 = emb_bf + (size_t)64 * ai + hi * 8;
    const unsigned short* s1 = h_e + (size_t)64 * e + hi * 8;
    bf16x8 a0 = *(const bf16x8*)(s0);
    bf16x8 a1 = *(const bf16x8*)(s0 + 16);
    bf16x8 a2 = *(const bf16x8*)(s0 + 32);
    bf16x8 a3 = *(const bf16x8*)(s0 + 48);
    bf16x8 a4{}, a5{}, a6{}, a7{};
    if (!first) {
        a4 = *(const bf16x8*)(s1);
        a5 = *(const bf16x8*)(s1 + 16);
        a6 = *(const bf16x8*)(s1 + 32);
        a7 = *(const bf16x8*)(s1 + 48);
    }

    f32x16 acc0, acc1;
    #pragma unroll
    for (int i = 0; i < 16; ++i) { acc0[i] = 0.f; acc1[i] = 0.f; }

    __syncthreads();

    #define EMM(AF, KG)                                                              \
        {                                                                            \
            bf16x8 b0 = *(const bf16x8*)&sBe[(((KG)) * 64 + ln) * 8];                \
            bf16x8 b1 = *(const bf16x8*)&sBe[((8 + (KG)) * 64 + ln) * 8];            \
            acc0 = __builtin_amdgcn_mfma_f32_32x32x16_bf16(AF, b0, acc0, 0, 0, 0);   \
            acc1 = __builtin_amdgcn_mfma_f32_32x32x16_bf16(AF, b1, acc1, 0, 0, 0);   \
        }
    EMM(a0, 0) EMM(a1, 1) EMM(a2, 2) EMM(a3, 3)
    if (!first) {
        EMM(a4, 4) EMM(a5, 5) EMM(a6, 6) EMM(a7, 7)
    }
    #undef EMM

    const float gb0 = gbias[er], gb1 = gbias[er + 32];
    float cs0 = 0.f, cs1 = 0.f;
    #pragma unroll
    for (int r = 0; r < 16; ++r) {
        int row = (r & 3) + 8 * (r >> 2) + 4 * hi;
        int si_row = __shfl(siv, row, 64);
        int ri_row = __shfl(riv, row, 64);
        float2 us = usr[(size_t)si_row * 64 + er];
        float2 ur = usr[(size_t)ri_row * 64 + 32 + er];
        size_t o = (size_t)(ebase + row) * 64;
        float v0 = fmaxf(acc0[r] + us.x + ur.x + gb0, 0.f);
        float v1 = fmaxf(acc1[r] + us.y + ur.y + gb1, 0.f);
        cs0 += v0; cs1 += v1;
        h_e[o + er] = f2bf(v0);
        h_e[o + er + 32] = f2bf(v1);
    }
    cs0 += __shfl_xor(cs0, 32, 64);
    cs1 += __shfl_xor(cs1, 32, 64);
    if (hi == 0) { sRed[w][er] = cs0; sRed[w][er + 32] = cs1; }
    __syncthreads();
    if (w == 0) {
        float t = 0.f;
        #pragma unroll
        for (int q = 0; q < 8; ++q) t += sRed[q][ln];
        atomicAdd(&e_sum[ln], t);
    }
}

// ---------------- recv/sent gather: 32 threads per node (16 recv + 16 sent) ----
__global__ __launch_bounds__(256) void k_gather(
    const unsigned short* __restrict__ h_e, const int* __restrict__ row_r,
    const int* __restrict__ col_r, const int* __restrict__ row_s,
    const int* __restrict__ col_s, unsigned short* __restrict__ recv,
    unsigned short* __restrict__ sentb) {
    int t = blockIdx.x * 256 + threadIdx.x;
    int sub = t & 31, n = t >> 5;
    int g = sub & 15, which = sub >> 4;
    const int* rowp = which ? row_s : row_r;
    const int* colp = which ? col_s : col_r;
    unsigned short* outp = which ? sentb : recv;

    float a0 = 0.f, a1 = 0.f, a2 = 0.f, a3 = 0.f;
    int b0 = rowp[n], b1 = rowp[n + 1];
    for (int p = b0; p < b1; ++p) {
        uint2 v = *(const uint2*)&h_e[(size_t)64 * colp[p] + g * 4];
        a0 += bf2f((unsigned short)(v.x & 0xFFFF));
        a1 += bf2f((unsigned short)(v.x >> 16));
        a2 += bf2f((unsigned short)(v.y & 0xFFFF));
        a3 += bf2f((unsigned short)(v.y >> 16));
    }
    uint2 packed;
    packed.x = (unsigned int)f2bf(a0) | ((unsigned int)f2bf(a1) << 16);
    packed.y = (unsigned int)f2bf(a2) | ((unsigned int)f2bf(a3) << 16);
    *(uint2*)&outp[(size_t)64 * n + g * 4] = packed;
}

// ---------------- node block: barrier-free MFMA GEMM, 1 wave/block ----------------
#define NODE_CHUNK(CIDX, BASE)                                                          \
    {                                                                                   \
        const unsigned short* src = (BASE) + hi * 8;                                    \
        _Pragma("unroll") for (int kb = 0; kb < 4; ++kb) {                              \
            bf16x8 a = *(const bf16x8*)(src + kb * 16);                                 \
            bf16x8 b0 = *(const bf16x8*)&Bp[(size_t)(((CIDX)*4 + kb) * 64 + ln) * 8];   \
            bf16x8 b1 = *(const bf16x8*)&Bp[(size_t)((16 + (CIDX)*4 + kb) * 64 + ln) * 8]; \
            acc0 = __builtin_amdgcn_mfma_f32_32x32x16_bf16(a, b0, acc0, 0, 0, 0);       \
            acc1 = __builtin_amdgcn_mfma_f32_32x32x16_bf16(a, b1, acc1, 0, 0, 0);       \
        }                                                                               \
    }

__global__ __launch_bounds__(64) void k_node(
    const unsigned short* __restrict__ recv, const unsigned short* __restrict__ sentb,
    const unsigned short* __restrict__ xenc_t, float* __restrict__ h_x,
    unsigned short* __restrict__ hx_bf, const unsigned short* __restrict__ Bp,
    const float* __restrict__ gbias, float* __restrict__ x_sum,
    unsigned short* __restrict__ hid_t, float* __restrict__ timed_t) {
    const int ln = threadIdx.x;
    const int er = ln & 31, hi = ln >> 5;
    const int n0 = blockIdx.x * 32;
    const int n = n0 + er;

    f32x16 acc0, acc1;
    #pragma unroll
    for (int i = 0; i < 16; ++i) { acc0[i] = 0.f; acc1[i] = 0.f; }

    NODE_CHUNK(0, recv + (size_t)64 * n)
    NODE_CHUNK(1, sentb + (size_t)64 * n)
    NODE_CHUNK(2, xenc_t + (size_t)64 * n)
    NODE_CHUNK(3, hx_bf + (size_t)64 * n)

    const float gb0 = gbias[er], gb1 = gbias[er + 32];
    float cs0 = 0.f, cs1 = 0.f;
    #pragma unroll
    for (int r = 0; r < 16; ++r) {
        int row = (r & 3) + 8 * (r >> 2) + 4 * hi;
        size_t o = (size_t)(n0 + row) * 64;
        float x0 = fmaxf(acc0[r] + gb0, 0.f);
        float x1 = fmaxf(acc1[r] + gb1, 0.f);
        cs0 += x0; cs1 += x1;
        float hx0 = h_x[o + er] + x0;
        float hx1 = h_x[o + er + 32] + x1;
        unsigned short hb0 = f2bf(hx0), hb1 = f2bf(hx1);
        h_x[o + er] = hx0;        h_x[o + er + 32] = hx1;
        hx_bf[o + er] = hb0;      hx_bf[o + er + 32] = hb1;
        hid_t[o + er] = hb0;      hid_t[o + er + 32] = hb1;
        timed_t[o + er] = x0;     timed_t[o + er + 32] = x1;
    }
    cs0 += __shfl_xor(cs0, 32, 64);
    cs1 += __shfl_xor(cs1, 32, 64);
    if (hi == 0) {
        atomicAdd(&x_sum[er], cs0);
        atomicAdd(&x_sum[er + 32], cs1);
    }
}

// ---------------- Laplacian: 32 threads per node, bf16 h_x reads ----------------
__global__ __launch_bounds__(256) void k_lap(
    const unsigned short* __restrict__ hx_bf, const int* __restrict__ row_L,
    const uint2* __restrict__ col_L8, const float* __restrict__ coeff,
    float* __restrict__ spat_t) {
    int t = blockIdx.x * 256 + threadIdx.x;
    int sub = t & 31, n = t >> 5;
    int g = sub & 15, half = sub >> 4;
    float a0 = 0.f, a1 = 0.f, a2 = 0.f, a3 = 0.f;
    int b0 = row_L[n], b1 = row_L[n + 1];
    int mid = b0 + ((b1 - b0) >> 1);
    int p0 = half ? mid : b0;
    int p1 = half ? b1 : mid;
    for (int p = p0; p < p1; ++p) {
        uint2 e = col_L8[p];
        float lv = __uint_as_float(e.y);
        uint2 hv = *(const uint2*)&hx_bf[(size_t)64 * e.x + g * 4];
        a0 = fmaf(lv, bf2f((unsigned short)(hv.x & 0xFFFF)), a0);
        a1 = fmaf(lv, bf2f((unsigned short)(hv.x >> 16)), a1);
        a2 = fmaf(lv, bf2f((unsigned short)(hv.y & 0xFFFF)), a2);
        a3 = fmaf(lv, bf2f((unsigned short)(hv.y >> 16)), a3);
    }
    a0 += __shfl_xor(a0, 16, 64);
    a1 += __shfl_xor(a1, 16, 64);
    a2 += __shfl_xor(a2, 16, 64);
    a3 += __shfl_xor(a3, 16, 64);
    if (half == 0) {
        float c = coeff[0];
        float4 outv = {c * a0, c * a1, c * a2, c * a3};
        *(float4*)&spat_t[(size_t)64 * n + g * 4] = outv;
    }
}

// ---------------- decoders: MFMA layer1, LDS transpose, scalar layer2 ----------------
__global__ __launch_bounds__(256) void k_dec(
    const unsigned short* __restrict__ hid_bf, const unsigned short* __restrict__ Bpd,
    const float* __restrict__ b_d1, const float* __restrict__ W_d2,
    const float* __restrict__ b_d2, const float* __restrict__ b_i1,
    const float* __restrict__ W_i2, const float* __restrict__ b_i2,
    float* __restrict__ out_nodes, float* __restrict__ pred_in) {
    __shared__ unsigned short sDec[4][32 * 138];
    const int tid = threadIdx.x;
    const int w = tid >> 6, ln = tid & 63;
    const int er = ln & 31, hi = ln >> 5;
    const int row0 = (blockIdx.x * 4 + w) * 32;

    f32x16 ad0, ad1, ai0, ai1;
    #pragma unroll
    for (int i = 0; i < 16; ++i) { ad0[i] = 0.f; ad1[i] = 0.f; ai0[i] = 0.f; ai1[i] = 0.f; }

    const unsigned short* src = hid_bf + (size_t)(row0 + er) * 64 + hi * 8;
    #pragma unroll
    for (int kb = 0; kb < 4; ++kb) {
        bf16x8 a = *(const bf16x8*)(src + kb * 16);
        bf16x8 bd0 = *(const bf16x8*)&Bpd[((0 * 4 + kb) * 64 + ln) * 8];
        bf16x8 bd1 = *(const bf16x8*)&Bpd[((4 + kb) * 64 + ln) * 8];
        bf16x8 bi0 = *(const bf16x8*)&Bpd[((8 + kb) * 64 + ln) * 8];
        bf16x8 bi1 = *(const bf16x8*)&Bpd[((12 + kb) * 64 + ln) * 8];
        ad0 = __builtin_amdgcn_mfma_f32_32x32x16_bf16(a, bd0, ad0, 0, 0, 0);
        ad1 = __builtin_amdgcn_mfma_f32_32x32x16_bf16(a, bd1, ad1, 0, 0, 0);
        ai0 = __builtin_amdgcn_mfma_f32_32x32x16_bf16(a, bi0, ai0, 0, 0, 0);
        ai1 = __builtin_amdgcn_mfma_f32_32x32x16_bf16(a, bi1, ai1, 0, 0, 0);
    }

    const float bd0v = b_d1[er], bd1v = b_d1[er + 32];
    const float bi0v = b_i1[er], bi1v = b_i1[er + 32];
    unsigned short* sw = &sDec[w][0];
    #pragma unroll
    for (int r = 0; r < 16; ++r) {
        int row = (r & 3) + 8 * (r >> 2) + 4 * hi;
        sw[row * 138 + er]       = f2bf(fmaxf(ad0[r] + bd0v, 0.f));
        sw[row * 138 + er + 32]  = f2bf(fmaxf(ad1[r] + bd1v, 0.f));
        sw[row * 138 + er + 64]  = f2bf(fmaxf(ai0[r] + bi0v, 0.f));
        sw[row * 138 + er + 96]  = f2bf(fmaxf(ai1[r] + bi1v, 0.f));
    }
    __syncthreads();

    const int g_row = row0 + er;
    if (hi == 0) {
        float s = 0.f;
        for (int k = 0; k < 32; ++k) {
            unsigned int u = *(const unsigned int*)&sw[er * 138 + 2 * k];
            s = fmaf(bf2f((unsigned short)(u & 0xFFFF)), W_d2[2 * k], s);
            s = fmaf(bf2f((unsigned short)(u >> 16)), W_d2[2 * k + 1], s);
        }
        out_nodes[g_row] = s + b_d2[0];
    } else {
        float s0 = 0.f, s1 = 0.f, s2 = 0.f, s3 = 0.f;
        for (int k = 0; k < 32; ++k) {
            unsigned int u = *(const unsigned int*)&sw[er * 138 + 64 + 2 * k];
            float vlo = bf2f((unsigned short)(u & 0xFFFF));
            float vhi = bf2f((unsigned short)(u >> 16));
            float4 w0 = *(const float4*)&W_i2[(2 * k) * 4];
            float4 w1 = *(const float4*)&W_i2[(2 * k + 1) * 4];
            s0 = fmaf(vlo, w0.x, fmaf(vhi, w1.x, s0));
            s1 = fmaf(vlo, w0.y, fmaf(vhi, w1.y, s1));
            s2 = fmaf(vlo, w0.z, fmaf(vhi, w1.z, s2));
            s3 = fmaf(vlo, w0.w, fmaf(vhi, w1.w, s3));
        }
        float4 pv = {s0 + b_i2[0], s1 + b_i2[1], s2 + b_i2[2], s3 + b_i2[3]};
        *(float4*)&pred_in[(size_t)4 * g_row] = pv;
    }
}

extern "C" void kernel_launch(void* const* d_in, const int* in_sizes, int n_in,
                              void* d_out, int out_size, void* d_ws, size_t ws_size,
                              hipStream_t stream) {
    (void)in_sizes; (void)n_in; (void)out_size; (void)ws_size;
    const float* node_attr   = (const float*)d_in[0];
    const float* global_attr = (const float*)d_in[1];
    const float* L_values    = (const float*)d_in[2];
    const float* coeff       = (const float*)d_in[3];
    const int*   edge_attr   = (const int*)d_in[4];
    const int*   edge_index  = (const int*)d_in[5];
    const int*   L_index     = (const int*)d_in[6];
    const float* emb  = (const float*)d_in[8];
    const float* W_ne = (const float*)d_in[9];
    const float* b_ne = (const float*)d_in[10];
    const float* W_eb = (const float*)d_in[11];
    const float* b_eb = (const float*)d_in[12];
    const float* W_nb = (const float*)d_in[13];
    const float* b_nb = (const float*)d_in[14];
    const float* W_gb = (const float*)d_in[15];
    const float* b_gb = (const float*)d_in[16];
    const float* W_d1 = (const float*)d_in[17];
    const float* b_d1 = (const float*)d_in[18];
    const float* W_d2 = (const float*)d_in[19];
    const float* b_d2 = (const float*)d_in[20];
    const float* W_i1 = (const float*)d_in[21];
    const float* b_i1 = (const float*)d_in[22];
    const float* W_i2 = (const float*)d_in[23];
    const float* b_i2 = (const float*)d_in[24];

    const int* s_idx = edge_index;
    const int* r_idx = edge_index + EE;
    const int* Li = L_index;
    const int* Lj = L_index + NZ;

    char* ws = (char*)d_ws;
    size_t off = 0;
    auto alloc = [&](size_t bytes) -> void* {
        void* p = ws + off;
        off = (off + bytes + 255) & ~(size_t)255;
        return p;
    };
    unsigned short* xenc   = (unsigned short*)alloc((size_t)TT * NN * 64 * 2);
    unsigned short* hid    = (unsigned short*)alloc((size_t)TT * NN * 64 * 2);
    float*          h_x    = (float*)alloc((size_t)NN * 64 * 4);
    unsigned short* hx_bf  = (unsigned short*)alloc((size_t)NN * 64 * 2);
    unsigned short* h_e    = (unsigned short*)alloc((size_t)EE * 64 * 2);
    unsigned short* recv   = (unsigned short*)alloc((size_t)NN * 64 * 2);
    unsigned short* sentb  = (unsigned short*)alloc((size_t)NN * 64 * 2);
    float2*         usr    = (float2*)alloc((size_t)NN * 64 * 8);
    float* smalls          = (float*)alloc(2048);
    unsigned short* Bpe    = (unsigned short*)alloc((size_t)2 * 8 * 512 * 2);
    unsigned short* Bpu    = (unsigned short*)alloc((size_t)4 * 8 * 512 * 2);
    unsigned short* Bpn    = (unsigned short*)alloc((size_t)2 * 16 * 512 * 2);
    unsigned short* Bpd    = (unsigned short*)alloc((size_t)4 * 4 * 512 * 2);
    unsigned short* emb_bf = (unsigned short*)alloc((size_t)100 * 64 * 2);
    int* cnt    = (int*)alloc((size_t)3 * NN * 4);
    int* rowp   = (int*)alloc((size_t)3 * (NN + 1) * 4);
    int* wp     = (int*)alloc((size_t)3 * NN * 4);
    int* col_r  = (int*)alloc((size_t)EE * 4);
    int* col_s  = (int*)alloc((size_t)EE * 4);
    uint2* col_L8 = (uint2*)alloc((size_t)NZ * 8);

    float* g_cur = smalls;
    float* e_sum = smalls + 64;
    float* x_sum = smalls + 128;
    float* gb_eb = smalls + 192;
    float* gb_nb = smalls + 256;
    int* cnt_r = cnt, *cnt_s = cnt + NN, *cnt_L = cnt + 2 * NN;
    int* row_r = rowp, *row_s = rowp + (NN + 1), *row_L = rowp + 2 * (NN + 1);
    int* wp_r = wp, *wp_s = wp + NN, *wp_L = wp + 2 * NN;

    float* out_nodes = (float*)d_out;                    // [T,N,1]
    float* time_d = out_nodes + (size_t)TT * NN;         // [T,N,64]
    float* spat_d = time_d + (size_t)TT * NN * 64;       // [T,N,64]
    float* pred_in = spat_d + (size_t)TT * NN * 64;      // [T,N,4]

    hipMemsetAsync(h_x, 0, (size_t)NN * 64 * 4, stream);
    hipMemsetAsync(hx_bf, 0, (size_t)NN * 64 * 2, stream);
    hipMemsetAsync(smalls, 0, 2048, stream);
    hipMemsetAsync(cnt, 0, (size_t)3 * NN * 4, stream);
    hipMemcpyAsync(g_cur, global_attr, 64 * 4, hipMemcpyDeviceToDevice, stream);

    k_count<<<(NZ + 255) / 256, 256, 0, stream>>>(r_idx, s_idx, Li, cnt_r, cnt_s, cnt_L);
    k_scan<<<3, 1024, 0, stream>>>(cnt, rowp, wp);
    k_scatter<<<(NZ + 255) / 256, 256, 0, stream>>>(r_idx, s_idx, Li, Lj, L_values,
                                                    wp_r, wp_s, wp_L,
                                                    col_r, col_s, col_L8);
    k_pack<<<96, 256, 0, stream>>>(W_eb, W_nb, W_d1, W_i1, emb,
                                   Bpe, Bpu, Bpn, Bpd, emb_bf);
    k_xenc<<<TT * NN / 4, 256, 0, stream>>>(node_attr, W_ne, b_ne, xenc);

    for (int t = 0; t < TT; ++t) {
        const unsigned short* xenc_t = xenc + (size_t)t * NN * 64;
        k_usr<<<NN / 32, 64, 0, stream>>>(t > 0, xenc_t, hx_bf, Bpu, usr,
                                          W_gb, b_gb, W_eb, b_eb, W_nb, b_nb,
                                          g_cur, e_sum, x_sum, gb_eb, gb_nb);
        k_edge<<<EE / 256, 512, 0, stream>>>(t == 0, h_e, emb_bf, usr,
                                             edge_attr + (size_t)t * EE, s_idx, r_idx,
                                             Bpe, gb_eb, e_sum);
        k_gather<<<NN * 32 / 256, 256, 0, stream>>>(h_e, row_r, col_r, row_s, col_s,
                                                    recv, sentb);
        k_node<<<NN / 32, 64, 0, stream>>>(recv, sentb, xenc_t, h_x, hx_bf,
                                           Bpn, gb_nb, x_sum,
                                           hid + (size_t)t * NN * 64,
                                           time_d + (size_t)t * NN * 64);
        k_lap<<<NN * 32 / 256, 256, 0, stream>>>(hx_bf, row_L, col_L8, coeff,
                                                 spat_d + (size_t)t * NN * 64);
    }
    k_dec<<<TT * NN / 128, 256, 0, stream>>>(hid, Bpd, b_d1, W_d2, b_d2,
                                             b_i1, W_i2, b_i2, out_nodes, pred_in);
}

// Round 8
// 675.897 us; speedup vs baseline: 4.4087x; 1.0292x over previous
//
#include <hip/hip_runtime.h>

#define TT 4
#define NN 20000
#define EE 320000
#define NZ 340000
#define NBKT 2500  // NN/8 per XCD bucket

typedef __attribute__((ext_vector_type(8))) __bf16 bf16x8;
typedef __attribute__((ext_vector_type(16))) float f32x16;

__device__ __forceinline__ unsigned short f2bf(float f) {
    unsigned int u = __float_as_uint(f);
    u = (u + 0x7FFFu + ((u >> 16) & 1u)) >> 16;
    return (unsigned short)u;
}
__device__ __forceinline__ float bf2f(unsigned short h) {
    return __uint_as_float(((unsigned int)h) << 16);
}

#define GLL16(src, dst) __builtin_amdgcn_global_load_lds( \
    (const __attribute__((address_space(1))) unsigned int*)(src), \
    (__attribute__((address_space(3))) unsigned int*)(dst), 16, 0, 0)

// ---------------- CSR build ----------------
__global__ void k_count(const int* __restrict__ r, const int* __restrict__ s,
                        const int* __restrict__ Li,
                        int* cnt_r, int* cnt_s, int* cnt_L) {
    int i = blockIdx.x * 256 + threadIdx.x;
    if (i < EE) { atomicAdd(&cnt_r[r[i]], 1); atomicAdd(&cnt_s[s[i]], 1); }
    if (i < NZ) { atomicAdd(&cnt_L[Li[i]], 1); }
}

__global__ __launch_bounds__(1024) void k_scan(int* cnt, int* rowp, int* wp) {
    int which = blockIdx.x;
    int* c = cnt + which * NN;
    int* row = rowp + which * (NN + 1);
    int* w = wp + which * NN;
    __shared__ int ssum[1024];
    int tid = threadIdx.x;
    const int CH = (NN + 1023) / 1024;
    int base = tid * CH;
    int s = 0;
    for (int i = 0; i < CH; ++i) { int idx = base + i; s += (idx < NN) ? c[idx] : 0; }
    ssum[tid] = s;
    __syncthreads();
    for (int o = 1; o < 1024; o <<= 1) {
        int v = (tid >= o) ? ssum[tid - o] : 0;
        __syncthreads();
        ssum[tid] += v;
        __syncthreads();
    }
    int run = (tid > 0) ? ssum[tid - 1] : 0;
    for (int i = 0; i < CH; ++i) {
        int idx = base + i;
        if (idx < NN) { row[idx] = run; w[idx] = run; run += c[idx]; }
    }
    if (tid == 1023) row[NN] = ssum[1023];
}

// XCD-bucketed scatter: bucket = blockIdx & 7 (round-robin XCD heuristic).
// Each bucket's CSR write region (~160-340 KB contiguous) stays in one XCD's L2,
// so partial-line random writes get absorbed and written back as full lines.
__global__ __launch_bounds__(256) void k_scatter(
    const int* __restrict__ r, const int* __restrict__ s,
    const int* __restrict__ Li, const int* __restrict__ Lj,
    const float* __restrict__ Lv,
    int* wp_r, int* wp_s, int* wp_L,
    int* col_r, int* col_s, uint2* col_L8) {
    const int bucket = blockIdx.x & 7;
    const int nlo = bucket * NBKT;
    const int cid = blockIdx.x >> 3;
    const int stride = (gridDim.x >> 3) * 256;
    for (int i = cid * 256 + threadIdx.x; i < EE; i += stride) {
        int rv = r[i];
        if ((unsigned)(rv - nlo) < (unsigned)NBKT)
            col_r[atomicAdd(&wp_r[rv], 1)] = i;
        int sv = s[i];
        if ((unsigned)(sv - nlo) < (unsigned)NBKT)
            col_s[atomicAdd(&wp_s[sv], 1)] = i;
    }
    for (int i = cid * 256 + threadIdx.x; i < NZ; i += stride) {
        int lv = Li[i];
        if ((unsigned)(lv - nlo) < (unsigned)NBKT) {
            int pos = atomicAdd(&wp_L[lv], 1);
            uint2 v;
            v.x = (unsigned int)Lj[i];
            v.y = __float_as_uint(Lv[i]);
            col_L8[pos] = v;
        }
    }
}

// ---------------- weight packing to bf16 MFMA fragment order ----------------
__global__ __launch_bounds__(256) void k_pack(
    const float* __restrict__ W_eb, const float* __restrict__ W_nb,
    const float* __restrict__ W_d1, const float* __restrict__ W_i1,
    const float* __restrict__ emb, unsigned short* __restrict__ Bpe,
    unsigned short* __restrict__ Bpu, unsigned short* __restrict__ Bpn,
    unsigned short* __restrict__ Bpd, unsigned short* __restrict__ emb_bf) {
    int t = blockIdx.x * 256 + threadIdx.x;
    if (t < 2 * 8 * 512) {
        int i = t & 7, l = (t >> 3) & 63, kb = (t >> 9) & 7, ch = t >> 12;
        int colv = ch * 32 + (l & 31);
        int k = kb * 16 + (l >> 5) * 8 + i;
        Bpe[t] = f2bf(W_eb[k * 64 + colv]);
    }
    if (t < 4 * 8 * 512) {
        int i = t & 7, l = (t >> 3) & 63, kb = (t >> 9) & 7, g = t >> 12;
        int colv = (g & 1) * 32 + (l & 31);
        int k = 128 + (g >> 1) * 128 + kb * 16 + (l >> 5) * 8 + i;
        Bpu[t] = f2bf(W_eb[k * 64 + colv]);
    }
    if (t < 2 * 16 * 512) {
        int i = t & 7, l = (t >> 3) & 63, kb = (t >> 9) % 16, ch = t / (16 * 512);
        int colv = ch * 32 + (l & 31);
        int k = kb * 16 + (l >> 5) * 8 + i;
        Bpn[t] = f2bf(W_nb[k * 64 + colv]);
    }
    if (t < 4 * 4 * 512) {
        int i = t & 7, l = (t >> 3) & 63, kb = (t >> 9) & 3, sec = t >> 11;
        int colv = (sec & 1) * 32 + (l & 31);
        int k = kb * 16 + (l >> 5) * 8 + i;
        const float* W = (sec < 2) ? W_d1 : W_i1;
        Bpd[t] = f2bf(W[k * 64 + colv]);
    }
    if (t < 100 * 64) emb_bf[t] = f2bf(emb[t]);
}

// ---------------- node encoder (bf16 out) ----------------
__global__ __launch_bounds__(256) void k_xenc(const float* __restrict__ na,
                                              const float* __restrict__ W_ne,
                                              const float* __restrict__ b_ne,
                                              unsigned short* __restrict__ xenc) {
    int row = blockIdx.x * 4 + (threadIdx.x >> 6);
    int j = threadIdx.x & 63;
    float4 a = *(const float4*)&na[(size_t)row * 4];
    float v = b_ne[j] + a.x * W_ne[j] + a.y * W_ne[64 + j] + a.z * W_ne[128 + j] + a.w * W_ne[192 + j];
    xenc[(size_t)row * 64 + j] = f2bf(fmaxf(v, 0.f));
}

// ---------------- usr (+ fused global-block bias update in block 0) ----------------
// usr layout (packed bf16x2): uint[NN][64]:
//   [n][er]    = pack(u_s[er], u_s[er+32])
//   [n][32+er] = pack(u_r[er], u_r[er+32])
__global__ __launch_bounds__(64) void k_usr(
    int do_update,
    const unsigned short* __restrict__ xenc_t, const unsigned short* __restrict__ hx_bf,
    const unsigned short* __restrict__ Bpu, unsigned int* __restrict__ usr,
    const float* __restrict__ W_gb, const float* __restrict__ b_gb,
    const float* __restrict__ W_eb, const float* __restrict__ b_eb,
    const float* __restrict__ W_nb, const float* __restrict__ b_nb,
    float* __restrict__ g_cur, float* __restrict__ e_sum, float* __restrict__ x_sum,
    float* __restrict__ gb_eb, float* __restrict__ gb_nb) {
    const int ln = threadIdx.x;
    const int er = ln & 31, hi = ln >> 5;

    if (blockIdx.x == 0) {
        int j = ln;
        float gv = g_cur[j];
        if (do_update) {
            float a = b_gb[j];
            for (int k = 0; k < 64; ++k) a += (e_sum[k] / (float)EE) * W_gb[k * 64 + j];
            for (int k = 0; k < 64; ++k) a += (x_sum[k] / (float)NN) * W_gb[(64 + k) * 64 + j];
            for (int k = 0; k < 64; ++k) a += g_cur[k] * W_gb[(128 + k) * 64 + j];
            gv = fmaxf(a, 0.f);
            g_cur[j] = gv;
            e_sum[j] = 0.f;
            x_sum[j] = 0.f;
        }
        float a1 = b_eb[j], a2 = b_nb[j];
        for (int k = 0; k < 64; ++k) {
            float gk = __shfl(gv, k, 64);
            a1 = fmaf(gk, W_eb[(384 + k) * 64 + j], a1);
            a2 = fmaf(gk, W_nb[(256 + k) * 64 + j], a2);
        }
        gb_eb[j] = a1;
        gb_nb[j] = a2;
    }

    const int n0 = blockIdx.x * 32;
    const int n = n0 + er;

    f32x16 a0, a1, a2, a3;
    #pragma unroll
    for (int i = 0; i < 16; ++i) { a0[i] = 0.f; a1[i] = 0.f; a2[i] = 0.f; a3[i] = 0.f; }

    const unsigned short* sx = xenc_t + (size_t)64 * n + hi * 8;
    const unsigned short* sh = hx_bf + (size_t)64 * n + hi * 8;
    #pragma unroll
    for (int c = 0; c < 2; ++c) {
        const unsigned short* src = c ? sh : sx;
        #pragma unroll
        for (int kb = 0; kb < 4; ++kb) {
            bf16x8 a = *(const bf16x8*)(src + kb * 16);
            int kg = c * 4 + kb;
            bf16x8 b0 = *(const bf16x8*)&Bpu[(size_t)((0 * 8 + kg) * 64 + ln) * 8];
            bf16x8 b1 = *(const bf16x8*)&Bpu[(size_t)((1 * 8 + kg) * 64 + ln) * 8];
            bf16x8 b2 = *(const bf16x8*)&Bpu[(size_t)((2 * 8 + kg) * 64 + ln) * 8];
            bf16x8 b3 = *(const bf16x8*)&Bpu[(size_t)((3 * 8 + kg) * 64 + ln) * 8];
            a0 = __builtin_amdgcn_mfma_f32_32x32x16_bf16(a, b0, a0, 0, 0, 0);
            a1 = __builtin_amdgcn_mfma_f32_32x32x16_bf16(a, b1, a1, 0, 0, 0);
            a2 = __builtin_amdgcn_mfma_f32_32x32x16_bf16(a, b2, a2, 0, 0, 0);
            a3 = __builtin_amdgcn_mfma_f32_32x32x16_bf16(a, b3, a3, 0, 0, 0);
        }
    }
    #pragma unroll
    for (int r = 0; r < 16; ++r) {
        int row = (r & 3) + 8 * (r >> 2) + 4 * hi;
        size_t o = (size_t)(n0 + row) * 64;
        usr[o + er]      = (unsigned int)f2bf(a0[r]) | ((unsigned int)f2bf(a1[r]) << 16);
        usr[o + 32 + er] = (unsigned int)f2bf(a2[r]) | ((unsigned int)f2bf(a3[r]) << 16);
    }
}

// ---------------- edge block: K=128 (emb,h_e) MFMA + usr epilogue ----------------
__global__ __launch_bounds__(512) void k_edge(
    int first, unsigned short* __restrict__ h_e,
    const unsigned short* __restrict__ emb_bf,
    const unsigned int* __restrict__ usr, const int* __restrict__ eattr_t,
    const int* __restrict__ sidx, const int* __restrict__ ridx,
    const unsigned short* __restrict__ Bp, const float* __restrict__ gbias,
    float* __restrict__ e_sum) {
    __shared__ unsigned short sBe[8192];  // 16 KB packed W_eb rows 0..128
    __shared__ float sRed[8][64];
    const int tid = threadIdx.x;
    const int w = tid >> 6, ln = tid & 63;
    const int er = ln & 31, hi = ln >> 5;
    const int ebase = blockIdx.x * 256 + w * 32;
    const int e = ebase + er;

    const int siv = sidx[ebase + er];
    const int riv = ridx[ebase + er];
    const int ai = eattr_t[e];

    #pragma unroll
    for (int i = 0; i < 2; ++i) {
        int off = i * 4096 + w * 512;
        GLL16(Bp + off + ln * 8, sBe + off);
    }

    const unsigned short* s0 = emb_bf + (size_t)64 * ai + hi * 8;
    const unsigned short* s1 = h_e + (size_t)64 * e + hi * 8;
    bf16x8 a0 = *(const bf16x8*)(s0);
    bf16x8 a1 = *(const bf16x8*)(s0 + 16);
    bf16x8 a2 = *(const bf16x8*)(s0 + 32);
    bf16x8 a3 = *(const bf16x8*)(s0 + 48);
    bf16x8 a4{}, a5{}, a6{}, a7{};
    if (!first) {
        a4 = *(const bf16x8*)(s1);
        a5 = *(const bf16x8*)(s1 + 16);
        a6 = *(const bf16x8*)(s1 + 32);
        a7 = *(const bf16x8*)(s1 + 48);
    }

    f32x16 acc0, acc1;
    #pragma unroll
    for (int i = 0; i < 16; ++i) { acc0[i] = 0.f; acc1[i] = 0.f; }

    __syncthreads();

    #define EMM(AF, KG)                                                              \
        {                                                                            \
            bf16x8 b0 = *(const bf16x8*)&sBe[(((KG)) * 64 + ln) * 8];                \
            bf16x8 b1 = *(const bf16x8*)&sBe[((8 + (KG)) * 64 + ln) * 8];            \
            acc0 = __builtin_amdgcn_mfma_f32_32x32x16_bf16(AF, b0, acc0, 0, 0, 0);   \
            acc1 = __builtin_amdgcn_mfma_f32_32x32x16_bf16(AF, b1, acc1, 0, 0, 0);   \
        }
    EMM(a0, 0) EMM(a1, 1) EMM(a2, 2) EMM(a3, 3)
    if (!first) {
        EMM(a4, 4) EMM(a5, 5) EMM(a6, 6) EMM(a7, 7)
    }
    #undef EMM

    const float gb0 = gbias[er], gb1 = gbias[er + 32];
    float cs0 = 0.f, cs1 = 0.f;
    #pragma unroll
    for (int r = 0; r < 16; ++r) {
        int row = (r & 3) + 8 * (r >> 2) + 4 * hi;
        int si_row = __shfl(siv, row, 64);
        int ri_row = __shfl(riv, row, 64);
        unsigned int us = usr[(size_t)si_row * 64 + er];
        unsigned int ur = usr[(size_t)ri_row * 64 + 32 + er];
        size_t o = (size_t)(ebase + row) * 64;
        float v0 = fmaxf(acc0[r] + bf2f((unsigned short)(us & 0xFFFF))
                                 + bf2f((unsigned short)(ur & 0xFFFF)) + gb0, 0.f);
        float v1 = fmaxf(acc1[r] + bf2f((unsigned short)(us >> 16))
                                 + bf2f((unsigned short)(ur >> 16)) + gb1, 0.f);
        cs0 += v0; cs1 += v1;
        h_e[o + er] = f2bf(v0);
        h_e[o + er + 32] = f2bf(v1);
    }
    cs0 += __shfl_xor(cs0, 32, 64);
    cs1 += __shfl_xor(cs1, 32, 64);
    if (hi == 0) { sRed[w][er] = cs0; sRed[w][er + 32] = cs1; }
    __syncthreads();
    if (w == 0) {
        float t = 0.f;
        #pragma unroll
        for (int q = 0; q < 8; ++q) t += sRed[q][ln];
        atomicAdd(&e_sum[ln], t);
    }
}

// ---------------- recv/sent gather: 32 threads per node (16 recv + 16 sent) ----
__global__ __launch_bounds__(256) void k_gather(
    const unsigned short* __restrict__ h_e, const int* __restrict__ row_r,
    const int* __restrict__ col_r, const int* __restrict__ row_s,
    const int* __restrict__ col_s, unsigned short* __restrict__ recv,
    unsigned short* __restrict__ sentb) {
    int t = blockIdx.x * 256 + threadIdx.x;
    int sub = t & 31, n = t >> 5;
    int g = sub & 15, which = sub >> 4;
    const int* rowp = which ? row_s : row_r;
    const int* colp = which ? col_s : col_r;
    unsigned short* outp = which ? sentb : recv;

    float a0 = 0.f, a1 = 0.f, a2 = 0.f, a3 = 0.f;
    int b0 = rowp[n], b1 = rowp[n + 1];
    for (int p = b0; p < b1; ++p) {
        uint2 v = *(const uint2*)&h_e[(size_t)64 * colp[p] + g * 4];
        a0 += bf2f((unsigned short)(v.x & 0xFFFF));
        a1 += bf2f((unsigned short)(v.x >> 16));
        a2 += bf2f((unsigned short)(v.y & 0xFFFF));
        a3 += bf2f((unsigned short)(v.y >> 16));
    }
    uint2 packed;
    packed.x = (unsigned int)f2bf(a0) | ((unsigned int)f2bf(a1) << 16);
    packed.y = (unsigned int)f2bf(a2) | ((unsigned int)f2bf(a3) << 16);
    *(uint2*)&outp[(size_t)64 * n + g * 4] = packed;
}

// ---------------- node block: barrier-free MFMA GEMM, 1 wave/block ----------------
#define NODE_CHUNK(CIDX, BASE)                                                          \
    {                                                                                   \
        const unsigned short* src = (BASE) + hi * 8;                                    \
        _Pragma("unroll") for (int kb = 0; kb < 4; ++kb) {                              \
            bf16x8 a = *(const bf16x8*)(src + kb * 16);                                 \
            bf16x8 b0 = *(const bf16x8*)&Bp[(size_t)(((CIDX)*4 + kb) * 64 + ln) * 8];   \
            bf16x8 b1 = *(const bf16x8*)&Bp[(size_t)((16 + (CIDX)*4 + kb) * 64 + ln) * 8]; \
            acc0 = __builtin_amdgcn_mfma_f32_32x32x16_bf16(a, b0, acc0, 0, 0, 0);       \
            acc1 = __builtin_amdgcn_mfma_f32_32x32x16_bf16(a, b1, acc1, 0, 0, 0);       \
        }                                                                               \
    }

__global__ __launch_bounds__(64) void k_node(
    const unsigned short* __restrict__ recv, const unsigned short* __restrict__ sentb,
    const unsigned short* __restrict__ xenc_t, float* __restrict__ h_x,
    unsigned short* __restrict__ hx_bf, const unsigned short* __restrict__ Bp,
    const float* __restrict__ gbias, float* __restrict__ x_sum,
    unsigned short* __restrict__ hid_t, float* __restrict__ timed_t) {
    const int ln = threadIdx.x;
    const int er = ln & 31, hi = ln >> 5;
    const int n0 = blockIdx.x * 32;
    const int n = n0 + er;

    f32x16 acc0, acc1;
    #pragma unroll
    for (int i = 0; i < 16; ++i) { acc0[i] = 0.f; acc1[i] = 0.f; }

    NODE_CHUNK(0, recv + (size_t)64 * n)
    NODE_CHUNK(1, sentb + (size_t)64 * n)
    NODE_CHUNK(2, xenc_t + (size_t)64 * n)
    NODE_CHUNK(3, hx_bf + (size_t)64 * n)

    const float gb0 = gbias[er], gb1 = gbias[er + 32];
    float cs0 = 0.f, cs1 = 0.f;
    #pragma unroll
    for (int r = 0; r < 16; ++r) {
        int row = (r & 3) + 8 * (r >> 2) + 4 * hi;
        size_t o = (size_t)(n0 + row) * 64;
        float x0 = fmaxf(acc0[r] + gb0, 0.f);
        float x1 = fmaxf(acc1[r] + gb1, 0.f);
        cs0 += x0; cs1 += x1;
        float hx0 = h_x[o + er] + x0;
        float hx1 = h_x[o + er + 32] + x1;
        unsigned short hb0 = f2bf(hx0), hb1 = f2bf(hx1);
        h_x[o + er] = hx0;        h_x[o + er + 32] = hx1;
        hx_bf[o + er] = hb0;      hx_bf[o + er + 32] = hb1;
        hid_t[o + er] = hb0;      hid_t[o + er + 32] = hb1;
        timed_t[o + er] = x0;     timed_t[o + er + 32] = x1;
    }
    cs0 += __shfl_xor(cs0, 32, 64);
    cs1 += __shfl_xor(cs1, 32, 64);
    if (hi == 0) {
        atomicAdd(&x_sum[er], cs0);
        atomicAdd(&x_sum[er + 32], cs1);
    }
}

// ---------------- Laplacian: 32 threads per node, bf16 h_x reads ----------------
__global__ __launch_bounds__(256) void k_lap(
    const unsigned short* __restrict__ hx_bf, const int* __restrict__ row_L,
    const uint2* __restrict__ col_L8, const float* __restrict__ coeff,
    float* __restrict__ spat_t) {
    int t = blockIdx.x * 256 + threadIdx.x;
    int sub = t & 31, n = t >> 5;
    int g = sub & 15, half = sub >> 4;
    float a0 = 0.f, a1 = 0.f, a2 = 0.f, a3 = 0.f;
    int b0 = row_L[n], b1 = row_L[n + 1];
    int mid = b0 + ((b1 - b0) >> 1);
    int p0 = half ? mid : b0;
    int p1 = half ? b1 : mid;
    for (int p = p0; p < p1; ++p) {
        uint2 e = col_L8[p];
        float lv = __uint_as_float(e.y);
        uint2 hv = *(const uint2*)&hx_bf[(size_t)64 * e.x + g * 4];
        a0 = fmaf(lv, bf2f((unsigned short)(hv.x & 0xFFFF)), a0);
        a1 = fmaf(lv, bf2f((unsigned short)(hv.x >> 16)), a1);
        a2 = fmaf(lv, bf2f((unsigned short)(hv.y & 0xFFFF)), a2);
        a3 = fmaf(lv, bf2f((unsigned short)(hv.y >> 16)), a3);
    }
    a0 += __shfl_xor(a0, 16, 64);
    a1 += __shfl_xor(a1, 16, 64);
    a2 += __shfl_xor(a2, 16, 64);
    a3 += __shfl_xor(a3, 16, 64);
    if (half == 0) {
        float c = coeff[0];
        float4 outv = {c * a0, c * a1, c * a2, c * a3};
        *(float4*)&spat_t[(size_t)64 * n + g * 4] = outv;
    }
}

// ---------------- decoders: MFMA layer1, LDS transpose, scalar layer2 ----------------
__global__ __launch_bounds__(256) void k_dec(
    const unsigned short* __restrict__ hid_bf, const unsigned short* __restrict__ Bpd,
    const float* __restrict__ b_d1, const float* __restrict__ W_d2,
    const float* __restrict__ b_d2, const float* __restrict__ b_i1,
    const float* __restrict__ W_i2, const float* __restrict__ b_i2,
    float* __restrict__ out_nodes, float* __restrict__ pred_in) {
    __shared__ unsigned short sDec[4][32 * 138];
    const int tid = threadIdx.x;
    const int w = tid >> 6, ln = tid & 63;
    const int er = ln & 31, hi = ln >> 5;
    const int row0 = (blockIdx.x * 4 + w) * 32;

    f32x16 ad0, ad1, ai0, ai1;
    #pragma unroll
    for (int i = 0; i < 16; ++i) { ad0[i] = 0.f; ad1[i] = 0.f; ai0[i] = 0.f; ai1[i] = 0.f; }

    const unsigned short* src = hid_bf + (size_t)(row0 + er) * 64 + hi * 8;
    #pragma unroll
    for (int kb = 0; kb < 4; ++kb) {
        bf16x8 a = *(const bf16x8*)(src + kb * 16);
        bf16x8 bd0 = *(const bf16x8*)&Bpd[((0 * 4 + kb) * 64 + ln) * 8];
        bf16x8 bd1 = *(const bf16x8*)&Bpd[((4 + kb) * 64 + ln) * 8];
        bf16x8 bi0 = *(const bf16x8*)&Bpd[((8 + kb) * 64 + ln) * 8];
        bf16x8 bi1 = *(const bf16x8*)&Bpd[((12 + kb) * 64 + ln) * 8];
        ad0 = __builtin_amdgcn_mfma_f32_32x32x16_bf16(a, bd0, ad0, 0, 0, 0);
        ad1 = __builtin_amdgcn_mfma_f32_32x32x16_bf16(a, bd1, ad1, 0, 0, 0);
        ai0 = __builtin_amdgcn_mfma_f32_32x32x16_bf16(a, bi0, ai0, 0, 0, 0);
        ai1 = __builtin_amdgcn_mfma_f32_32x32x16_bf16(a, bi1, ai1, 0, 0, 0);
    }

    const float bd0v = b_d1[er], bd1v = b_d1[er + 32];
    const float bi0v = b_i1[er], bi1v = b_i1[er + 32];
    unsigned short* sw = &sDec[w][0];
    #pragma unroll
    for (int r = 0; r < 16; ++r) {
        int row = (r & 3) + 8 * (r >> 2) + 4 * hi;
        sw[row * 138 + er]       = f2bf(fmaxf(ad0[r] + bd0v, 0.f));
        sw[row * 138 + er + 32]  = f2bf(fmaxf(ad1[r] + bd1v, 0.f));
        sw[row * 138 + er + 64]  = f2bf(fmaxf(ai0[r] + bi0v, 0.f));
        sw[row * 138 + er + 96]  = f2bf(fmaxf(ai1[r] + bi1v, 0.f));
    }
    __syncthreads();

    const int g_row = row0 + er;
    if (hi == 0) {
        float s = 0.f;
        for (int k = 0; k < 32; ++k) {
            unsigned int u = *(const unsigned int*)&sw[er * 138 + 2 * k];
            s = fmaf(bf2f((unsigned short)(u & 0xFFFF)), W_d2[2 * k], s);
            s = fmaf(bf2f((unsigned short)(u >> 16)), W_d2[2 * k + 1], s);
        }
        out_nodes[g_row] = s + b_d2[0];
    } else {
        float s0 = 0.f, s1 = 0.f, s2 = 0.f, s3 = 0.f;
        for (int k = 0; k < 32; ++k) {
            unsigned int u = *(const unsigned int*)&sw[er * 138 + 64 + 2 * k];
            float vlo = bf2f((unsigned short)(u & 0xFFFF));
            float vhi = bf2f((unsigned short)(u >> 16));
            float4 w0 = *(const float4*)&W_i2[(2 * k) * 4];
            float4 w1 = *(const float4*)&W_i2[(2 * k + 1) * 4];
            s0 = fmaf(vlo, w0.x, fmaf(vhi, w1.x, s0));
            s1 = fmaf(vlo, w0.y, fmaf(vhi, w1.y, s1));
            s2 = fmaf(vlo, w0.z, fmaf(vhi, w1.z, s2));
            s3 = fmaf(vlo, w0.w, fmaf(vhi, w1.w, s3));
        }
        float4 pv = {s0 + b_i2[0], s1 + b_i2[1], s2 + b_i2[2], s3 + b_i2[3]};
        *(float4*)&pred_in[(size_t)4 * g_row] = pv;
    }
}

extern "C" void kernel_launch(void* const* d_in, const int* in_sizes, int n_in,
                              void* d_out, int out_size, void* d_ws, size_t ws_size,
                              hipStream_t stream) {
    (void)in_sizes; (void)n_in; (void)out_size; (void)ws_size;
    const float* node_attr   = (const float*)d_in[0];
    const float* global_attr = (const float*)d_in[1];
    const float* L_values    = (const float*)d_in[2];
    const float* coeff       = (const float*)d_in[3];
    const int*   edge_attr   = (const int*)d_in[4];
    const int*   edge_index  = (const int*)d_in[5];
    const int*   L_index     = (const int*)d_in[6];
    const float* emb  = (const float*)d_in[8];
    const float* W_ne = (const float*)d_in[9];
    const float* b_ne = (const float*)d_in[10];
    const float* W_eb = (const float*)d_in[11];
    const float* b_eb = (const float*)d_in[12];
    const float* W_nb = (const float*)d_in[13];
    const float* b_nb = (const float*)d_in[14];
    const float* W_gb = (const float*)d_in[15];
    const float* b_gb = (const float*)d_in[16];
    const float* W_d1 = (const float*)d_in[17];
    const float* b_d1 = (const float*)d_in[18];
    const float* W_d2 = (const float*)d_in[19];
    const float* b_d2 = (const float*)d_in[20];
    const float* W_i1 = (const float*)d_in[21];
    const float* b_i1 = (const float*)d_in[22];
    const float* W_i2 = (const float*)d_in[23];
    const float* b_i2 = (const float*)d_in[24];

    const int* s_idx = edge_index;
    const int* r_idx = edge_index + EE;
    const int* Li = L_index;
    const int* Lj = L_index + NZ;

    char* ws = (char*)d_ws;
    size_t off = 0;
    auto alloc = [&](size_t bytes) -> void* {
        void* p = ws + off;
        off = (off + bytes + 255) & ~(size_t)255;
        return p;
    };
    unsigned short* xenc   = (unsigned short*)alloc((size_t)TT * NN * 64 * 2);
    unsigned short* hid    = (unsigned short*)alloc((size_t)TT * NN * 64 * 2);
    float*          h_x    = (float*)alloc((size_t)NN * 64 * 4);
    unsigned short* hx_bf  = (unsigned short*)alloc((size_t)NN * 64 * 2);
    unsigned short* h_e    = (unsigned short*)alloc((size_t)EE * 64 * 2);
    unsigned short* recv   = (unsigned short*)alloc((size_t)NN * 64 * 2);
    unsigned short* sentb  = (unsigned short*)alloc((size_t)NN * 64 * 2);
    unsigned int*   usr    = (unsigned int*)alloc((size_t)NN * 64 * 4);
    float* smalls          = (float*)alloc(2048);
    unsigned short* Bpe    = (unsigned short*)alloc((size_t)2 * 8 * 512 * 2);
    unsigned short* Bpu    = (unsigned short*)alloc((size_t)4 * 8 * 512 * 2);
    unsigned short* Bpn    = (unsigned short*)alloc((size_t)2 * 16 * 512 * 2);
    unsigned short* Bpd    = (unsigned short*)alloc((size_t)4 * 4 * 512 * 2);
    unsigned short* emb_bf = (unsigned short*)alloc((size_t)100 * 64 * 2);
    int* cnt    = (int*)alloc((size_t)3 * NN * 4);
    int* rowp   = (int*)alloc((size_t)3 * (NN + 1) * 4);
    int* wp     = (int*)alloc((size_t)3 * NN * 4);
    int* col_r  = (int*)alloc((size_t)EE * 4);
    int* col_s  = (int*)alloc((size_t)EE * 4);
    uint2* col_L8 = (uint2*)alloc((size_t)NZ * 8);

    float* g_cur = smalls;
    float* e_sum = smalls + 64;
    float* x_sum = smalls + 128;
    float* gb_eb = smalls + 192;
    float* gb_nb = smalls + 256;
    int* cnt_r = cnt, *cnt_s = cnt + NN, *cnt_L = cnt + 2 * NN;
    int* row_r = rowp, *row_s = rowp + (NN + 1), *row_L = rowp + 2 * (NN + 1);
    int* wp_r = wp, *wp_s = wp + NN, *wp_L = wp + 2 * NN;

    float* out_nodes = (float*)d_out;                    // [T,N,1]
    float* time_d = out_nodes + (size_t)TT * NN;         // [T,N,64]
    float* spat_d = time_d + (size_t)TT * NN * 64;       // [T,N,64]
    float* pred_in = spat_d + (size_t)TT * NN * 64;      // [T,N,4]

    hipMemsetAsync(h_x, 0, (size_t)NN * 64 * 4, stream);
    hipMemsetAsync(hx_bf, 0, (size_t)NN * 64 * 2, stream);
    hipMemsetAsync(smalls, 0, 2048, stream);
    hipMemsetAsync(cnt, 0, (size_t)3 * NN * 4, stream);
    hipMemcpyAsync(g_cur, global_attr, 64 * 4, hipMemcpyDeviceToDevice, stream);

    k_count<<<(NZ + 255) / 256, 256, 0, stream>>>(r_idx, s_idx, Li, cnt_r, cnt_s, cnt_L);
    k_scan<<<3, 1024, 0, stream>>>(cnt, rowp, wp);
    k_scatter<<<2048, 256, 0, stream>>>(r_idx, s_idx, Li, Lj, L_values,
                                        wp_r, wp_s, wp_L, col_r, col_s, col_L8);
    k_pack<<<96, 256, 0, stream>>>(W_eb, W_nb, W_d1, W_i1, emb,
                                   Bpe, Bpu, Bpn, Bpd, emb_bf);
    k_xenc<<<TT * NN / 4, 256, 0, stream>>>(node_attr, W_ne, b_ne, xenc);

    for (int t = 0; t < TT; ++t) {
        const unsigned short* xenc_t = xenc + (size_t)t * NN * 64;
        k_usr<<<NN / 32, 64, 0, stream>>>(t > 0, xenc_t, hx_bf, Bpu, usr,
                                          W_gb, b_gb, W_eb, b_eb, W_nb, b_nb,
                                          g_cur, e_sum, x_sum, gb_eb, gb_nb);
        k_edge<<<EE / 256, 512, 0, stream>>>(t == 0, h_e, emb_bf, usr,
                                             edge_attr + (size_t)t * EE, s_idx, r_idx,
                                             Bpe, gb_eb, e_sum);
        k_gather<<<NN * 32 / 256, 256, 0, stream>>>(h_e, row_r, col_r, row_s, col_s,
                                                    recv, sentb);
        k_node<<<NN / 32, 64, 0, stream>>>(recv, sentb, xenc_t, h_x, hx_bf,
                                           Bpn, gb_nb, x_sum,
                                           hid + (size_t)t * NN * 64,
                                           time_d + (size_t)t * NN * 64);
        k_lap<<<NN * 32 / 256, 256, 0, stream>>>(hx_bf, row_L, col_L8, coeff,
                                                 spat_d + (size_t)t * NN * 64);
    }
    k_dec<<<TT * NN / 128, 256, 0, stream>>>(hid, Bpd, b_d1, W_d2, b_d2,
                                             b_i1, W_i2, b_i2, out_nodes, pred_in);
}